// Round 2
// baseline (1905.461 us; speedup 1.0000x reference)
//
#include <hip/hip_runtime.h>
#include <cstdint>
#include <cstddef>

#define NTOT 2048
#define BTOT 4

// ---------------- workspace layout (float-element offsets) ----------------
static const size_t WS_IDX20 = 0;                       // int[4*2048*20] = 163840
static const size_t WS_FS    = 163840;                  // float[1474560] surface feat (b,n,k,c,v)
static const size_t WS_X0    = 1638400;                 // float[2064384] (B,42,3,2048)
static const size_t WS_X1    = 3702784;                 // float[2064384]
static const size_t WS_XM2   = 5767168;                 // float[258048]  (B,42,3,512)
static const size_t WS_X2    = 6025216;                 // float[516096]  (B,84,3,512)
static const size_t WS_X3    = 6541312;                 // float[516096]
static const size_t WS_IDX42 = 7057408;                 // int[2048]      (B,128,4)
static const size_t WS_XM4   = 7059456;                 // float[129024]  (B,84,3,128)
static const size_t WS_X4    = 7188480;                 // float[258048]  (B,168,3,128)
static const size_t WS_I1    = 7446528;                 // int[8192]
static const size_t WS_I2    = 7454720;                 // int[8192]
static const size_t WS_MF    = 7462912;                 // float[5040]  mean_feat (b, c*3+v)
static const size_t WS_INVGL = 7467952;                 // float[3360]
static const size_t WS_STATS = 7471312;                 // double[840] vn bn stats (8B aligned; 1680 float slots)
static const size_t WS_CST   = 7472992;                 // float[3912]  conv bn stats
static const size_t WS_INVIN = 7476904;                 // float[10379264] (1267 x 8192)
static const size_t WS_Y2    = WS_INVIN;                // float[4194304]  (reuses invin)
static const size_t WS_Y3    = WS_INVIN + 4194304;      // float[3440640]  (reuses invin)
static const size_t WS_Y1    = WS_INVIN + 10379264;     // float[8388608]
// total = 26,244,776 floats ~= 105 MB

// stats sub-offsets within WS_STATS (double units)
#define ST0_OFF 0
#define ST1_OFF 84
#define ST2_OFF 168
#define ST3_OFF 336
#define ST4_OFF 504
// conv stats sub-offsets within WS_CST (float units)
#define CST1_OFF 0
#define CST2_OFF 2048
#define CST3_OFF 3072

// output offsets
#define OUT_EQV   0
#define OUT_MF    10321920
#define OUT_INV   10326960
#define OUT_INVGL 13767600

// ============================ KNN (top-K of pd) ============================
// pd[n][m] = (2*inner - xx_n) - xx_m ; top-K by value desc, ties -> lower idx
// Bit-exact vs numpy: sequential 3-term dot, no FMA (contract off).
template <int K>
__global__ void knn_kernel(const float* __restrict__ coord, int cand_cnt,
                           int cand_stride, int q_stride, int* __restrict__ out_idx,
                           int q_cnt)
{
#pragma clang fp contract(off)
    __shared__ float pdv[2048];
    __shared__ float rv[4];
    __shared__ int   ri[4];
    int b = blockIdx.y;
    int q = blockIdx.x;
    int nq = q * q_stride;
    float qx = coord[(b * 3 + 0) * NTOT + nq];
    float qy = coord[(b * 3 + 1) * NTOT + nq];
    float qz = coord[(b * 3 + 2) * NTOT + nq];
    float xxq = qx * qx + qy * qy + qz * qz;
    for (int m = threadIdx.x; m < cand_cnt; m += blockDim.x) {
        int mo = m * cand_stride;
        float cx = coord[(b * 3 + 0) * NTOT + mo];
        float cy = coord[(b * 3 + 1) * NTOT + mo];
        float cz = coord[(b * 3 + 2) * NTOT + mo];
        float inner = qx * cx + qy * cy + qz * cz;
        float xxc = cx * cx + cy * cy + cz * cz;
        pdv[m] = (2.0f * inner - xxq) - xxc;
    }
    __syncthreads();
    for (int kk = 0; kk < K; ++kk) {
        float bv = -3.4e38f;
        int bi = 0x7fffffff;
        for (int m = threadIdx.x; m < cand_cnt; m += blockDim.x) {
            float v = pdv[m];
            if (v > bv || (v == bv && m < bi)) { bv = v; bi = m; }
        }
        for (int off = 32; off; off >>= 1) {
            float ov = __shfl_down(bv, off);
            int   oi = __shfl_down(bi, off);
            if (ov > bv || (ov == bv && oi < bi)) { bv = ov; bi = oi; }
        }
        int wid = threadIdx.x >> 6;
        if ((threadIdx.x & 63) == 0) { rv[wid] = bv; ri[wid] = bi; }
        __syncthreads();
        if (threadIdx.x == 0) {
            for (int w = 1; w < (int)(blockDim.x >> 6); ++w)
                if (rv[w] > bv || (rv[w] == bv && ri[w] < bi)) { bv = rv[w]; bi = ri[w]; }
            out_idx[((size_t)(b * q_cnt) + q) * K + kk] = bi;
            pdv[bi] = -3.4e38f;
        }
        __syncthreads();
    }
}

// ============================ nearest index (argmin) ============================
// d = (tt_n - 2*inner) + ss_m ; argmin, ties -> lower idx
__global__ void nearest_kernel(const float* __restrict__ coord, int cand_cnt,
                               int cand_stride, int* __restrict__ out)
{
#pragma clang fp contract(off)
    __shared__ float rv[4];
    __shared__ int   ri[4];
    int b = blockIdx.y;
    int n = blockIdx.x;
    float qx = coord[(b * 3 + 0) * NTOT + n];
    float qy = coord[(b * 3 + 1) * NTOT + n];
    float qz = coord[(b * 3 + 2) * NTOT + n];
    float tt = qx * qx + qy * qy + qz * qz;
    float bv = 3.4e38f;
    int bi = 0x7fffffff;
    for (int m = threadIdx.x; m < cand_cnt; m += blockDim.x) {
        int mo = m * cand_stride;
        float cx = coord[(b * 3 + 0) * NTOT + mo];
        float cy = coord[(b * 3 + 1) * NTOT + mo];
        float cz = coord[(b * 3 + 2) * NTOT + mo];
        float inner = qx * cx + qy * cy + qz * cz;
        float ss = cx * cx + cy * cy + cz * cz;
        float d = (tt - 2.0f * inner) + ss;
        if (d < bv || (d == bv && m < bi)) { bv = d; bi = m; }
    }
    for (int off = 32; off; off >>= 1) {
        float ov = __shfl_down(bv, off);
        int   oi = __shfl_down(bi, off);
        if (ov < bv || (ov == bv && oi < bi)) { bv = ov; bi = oi; }
    }
    int wid = threadIdx.x >> 6;
    if ((threadIdx.x & 63) == 0) { rv[wid] = bv; ri[wid] = bi; }
    __syncthreads();
    if (threadIdx.x == 0) {
        for (int w = 1; w < 4; ++w)
            if (rv[w] < bv || (rv[w] == bv && ri[w] < bi)) { bv = rv[w]; bi = ri[w]; }
        out[b * NTOT + n] = bi;
    }
}

// ============================ surface feature build ============================
// fs layout: (b, n, k, c, v) contiguous; c: 0 diff, 1 ctr, 2 cross(nb,ctr)
__global__ void surf_build_kernel(const float* __restrict__ coord,
                                  const int* __restrict__ idx20,
                                  float* __restrict__ fs)
{
#pragma clang fp contract(off)
    int t = blockIdx.x * 256 + threadIdx.x;
    if (t >= BTOT * NTOT * 20) return;
    int n = (t / 20) & (NTOT - 1);
    int b = t / (20 * NTOT);
    int m = idx20[t];
    float cx = coord[(b * 3 + 0) * NTOT + n];
    float cy = coord[(b * 3 + 1) * NTOT + n];
    float cz = coord[(b * 3 + 2) * NTOT + n];
    float nx = coord[(b * 3 + 0) * NTOT + m];
    float ny = coord[(b * 3 + 1) * NTOT + m];
    float nz = coord[(b * 3 + 2) * NTOT + m];
    float* f9 = fs + (size_t)t * 9;
    f9[0] = nx - cx; f9[1] = ny - cy; f9[2] = nz - cz;
    f9[3] = cx;      f9[4] = cy;      f9[5] = cz;
    f9[6] = ny * cz - nz * cy;
    f9[7] = nz * cx - nx * cz;
    f9[8] = nx * cy - ny * cx;
}

// ============================ stage-0 stats / apply ============================
__global__ void stats0_kernel(const float* __restrict__ fs,
                              const float* __restrict__ wf0,
                              double* __restrict__ stats)
{
#pragma clang fp contract(off)
    __shared__ float fl[720];
    int blk = blockIdx.x;
    int b = blk / 512;
    int n0 = (blk % 512) * 4;
    for (int t = threadIdx.x; t < 720; t += 64)
        fl[t] = fs[((size_t)(b * NTOT + n0) * 20) * 9 + t];
    __syncthreads();
    int o = threadIdx.x;
    if (o < 42) {
        float w0 = wf0[o * 3], w1 = wf0[o * 3 + 1], w2 = wf0[o * 3 + 2];
        double s = 0.0, s2 = 0.0;
        for (int i = 0; i < 80; ++i) {
            const float* f9 = &fl[i * 9];
            float p0 = w0 * f9[0] + w1 * f9[3] + w2 * f9[6];
            float p1 = w0 * f9[1] + w1 * f9[4] + w2 * f9[7];
            float p2 = w0 * f9[2] + w1 * f9[5] + w2 * f9[8];
            float nrm = sqrtf(p0 * p0 + p1 * p1 + p2 * p2) + 1e-6f;
            s += (double)nrm; s2 += (double)nrm * (double)nrm;
        }
        atomicAdd(&stats[o], s);
        atomicAdd(&stats[42 + o], s2);
    }
}

__global__ void apply0_kernel(const float* __restrict__ fs,
                              const float* __restrict__ wf0,
                              const float* __restrict__ wd0,
                              const float* __restrict__ g0,
                              const float* __restrict__ b0,
                              const double* __restrict__ stats,
                              float* __restrict__ x0)
{
#pragma clang fp contract(off)
    __shared__ float fl[720];
    int blk = blockIdx.x;
    int b = blk / 512;
    int n0 = (blk % 512) * 4;
    for (int t = threadIdx.x; t < 720; t += 64)
        fl[t] = fs[((size_t)(b * NTOT + n0) * 20) * 9 + t];
    __syncthreads();
    int o = threadIdx.x;
    if (o >= 42) return;
    double S1 = stats[o], S2 = stats[42 + o];
    double md = S1 / 163840.0;
    float m = (float)md;
    float var = (float)(S2 / 163840.0 - md * md);
    float sqv = sqrtf(var + 1e-5f);
    float gg = g0[o], bb = b0[o];
    float wa0 = wf0[o * 3], wa1 = wf0[o * 3 + 1], wa2 = wf0[o * 3 + 2];
    float wb0 = wd0[o * 3], wb1 = wd0[o * 3 + 1], wb2 = wd0[o * 3 + 2];
    for (int pp = 0; pp < 4; ++pp) {
        // numpy pairwise_sum tree for k=20: r[0..7]=a[0..7]; r[j]+=a[8+j];
        // combine ((r0+r1)+(r2+r3))+((r4+r5)+(r6+r7)); then += a16..a19.
        float r8[3][8];
        float tl[3][4];
        for (int k = 0; k < 20; ++k) {
            const float* f9 = &fl[(pp * 20 + k) * 9];
            float p0 = wa0 * f9[0] + wa1 * f9[3] + wa2 * f9[6];
            float p1 = wa0 * f9[1] + wa1 * f9[4] + wa2 * f9[7];
            float p2 = wa0 * f9[2] + wa1 * f9[5] + wa2 * f9[8];
            float d0 = wb0 * f9[0] + wb1 * f9[3] + wb2 * f9[6];
            float d1 = wb0 * f9[1] + wb1 * f9[4] + wb2 * f9[7];
            float d2 = wb0 * f9[2] + wb1 * f9[5] + wb2 * f9[8];
            float nrm = sqrtf(p0 * p0 + p1 * p1 + p2 * p2) + 1e-6f;
            float nb = gg * (nrm - m) / sqv + bb;
            p0 = p0 / nrm * nb;
            p1 = p1 / nrm * nb;
            p2 = p2 / nrm * nb;
            float dot = p0 * d0 + p1 * d1 + p2 * d2;
            float r0, r1, r2;
            if (dot >= 0.f) { r0 = p0; r1 = p1; r2 = p2; }
            else {
                float tq = dot / (d0 * d0 + d1 * d1 + d2 * d2 + 1e-6f);
                r0 = p0 - tq * d0; r1 = p1 - tq * d1; r2 = p2 - tq * d2;
            }
            float o0 = 0.2f * p0 + 0.8f * r0;
            float o1 = 0.2f * p1 + 0.8f * r1;
            float o2 = 0.2f * p2 + 0.8f * r2;
            if (k < 8)       { r8[0][k] = o0;       r8[1][k] = o1;       r8[2][k] = o2; }
            else if (k < 16) { r8[0][k-8] += o0;    r8[1][k-8] += o1;    r8[2][k-8] += o2; }
            else             { tl[0][k-16] = o0;    tl[1][k-16] = o1;    tl[2][k-16] = o2; }
        }
        int n = n0 + pp;
        for (int v = 0; v < 3; ++v) {
            float res = ((r8[v][0] + r8[v][1]) + (r8[v][2] + r8[v][3])) +
                        ((r8[v][4] + r8[v][5]) + (r8[v][6] + r8[v][7]));
            res += tl[v][0]; res += tl[v][1]; res += tl[v][2]; res += tl[v][3];
            x0[((size_t)(b * 42 + o) * 3 + v) * NTOT + n] = res / 20.0f;
        }
    }
}

// ============================ generic VN stats / apply ============================
__global__ void vn_stats_kernel(const float* __restrict__ xin,
                                const float* __restrict__ wf,
                                double* __restrict__ stats,
                                int Ci, int Co, int Npts)
{
#pragma clang fp contract(off)
    __shared__ float col[252];
    int b = blockIdx.y;
    int o = threadIdx.x;
    double s = 0.0, s2 = 0.0;
    for (int it = 0; it < 16; ++it) {
        int pt = blockIdx.x * 16 + it;
        __syncthreads();
        for (int t = threadIdx.x; t < Ci * 3; t += blockDim.x)
            col[t] = xin[(size_t)(b * 3 * Ci + t) * Npts + pt];
        __syncthreads();
        if (o < Co) {
            const float* wr = wf + o * Ci;
            float p0 = 0.f, p1 = 0.f, p2 = 0.f;
            for (int c = 0; c < Ci; ++c) {
                float w = wr[c];
                p0 += w * col[3 * c]; p1 += w * col[3 * c + 1]; p2 += w * col[3 * c + 2];
            }
            float nrm = sqrtf(p0 * p0 + p1 * p1 + p2 * p2) + 1e-6f;
            s += (double)nrm; s2 += (double)nrm * (double)nrm;
        }
    }
    if (o < Co) { atomicAdd(&stats[o], s); atomicAdd(&stats[Co + o], s2); }
}

__global__ void vn_apply_kernel(const float* __restrict__ xin,
                                const float* __restrict__ wf,
                                const float* __restrict__ wd,
                                const float* __restrict__ g,
                                const float* __restrict__ bbp,
                                const double* __restrict__ stats,
                                double count, int Ci, int Co, int Npts,
                                float* __restrict__ xout)
{
#pragma clang fp contract(off)
    __shared__ float col[252];
    int b = blockIdx.y;
    int o = threadIdx.x;
    float m = 0.f, sqv = 1.f, gg = 0.f, bb = 0.f;
    if (o < Co) {
        double S1 = stats[o], S2 = stats[Co + o];
        double md = S1 / count;
        m = (float)md;
        float var = (float)(S2 / count - md * md);
        sqv = sqrtf(var + 1e-5f);
        gg = g[o]; bb = bbp[o];
    }
    for (int it = 0; it < 8; ++it) {
        int pt = blockIdx.x * 8 + it;
        __syncthreads();
        for (int t = threadIdx.x; t < Ci * 3; t += blockDim.x)
            col[t] = xin[(size_t)(b * 3 * Ci + t) * Npts + pt];
        __syncthreads();
        if (o < Co) {
            const float* wr = wf + o * Ci;
            const float* wdr = wd + o * Ci;
            float p0 = 0.f, p1 = 0.f, p2 = 0.f, d0 = 0.f, d1 = 0.f, d2 = 0.f;
            for (int c = 0; c < Ci; ++c) {
                float c0 = col[3 * c], c1 = col[3 * c + 1], c2 = col[3 * c + 2];
                float w = wr[c];
                p0 += w * c0; p1 += w * c1; p2 += w * c2;
                float w2 = wdr[c];
                d0 += w2 * c0; d1 += w2 * c1; d2 += w2 * c2;
            }
            float nrm = sqrtf(p0 * p0 + p1 * p1 + p2 * p2) + 1e-6f;
            float nb = gg * (nrm - m) / sqv + bb;
            p0 = p0 / nrm * nb;
            p1 = p1 / nrm * nb;
            p2 = p2 / nrm * nb;
            float dot = p0 * d0 + p1 * d1 + p2 * d2;
            float r0, r1, r2;
            if (dot >= 0.f) { r0 = p0; r1 = p1; r2 = p2; }
            else {
                float tq = dot / (d0 * d0 + d1 * d1 + d2 * d2 + 1e-6f);
                r0 = p0 - tq * d0; r1 = p1 - tq * d1; r2 = p2 - tq * d2;
            }
            xout[((size_t)(b * Co + o) * 3 + 0) * Npts + pt] = 0.2f * p0 + 0.8f * r0;
            xout[((size_t)(b * Co + o) * 3 + 1) * Npts + pt] = 0.2f * p1 + 0.8f * r1;
            xout[((size_t)(b * Co + o) * 3 + 2) * Npts + pt] = 0.2f * p2 + 0.8f * r2;
        }
    }
}

// ============================ VN max-pool-down ============================
__global__ void vn_pool_kernel(const float* __restrict__ xin,
                               const int* __restrict__ idx, long long sb, int sq,
                               const float* __restrict__ wp,
                               float* __restrict__ xout,
                               int C, int Np, int Nq)
{
#pragma clang fp contract(off)
    __shared__ float nb[4 * 84 * 3];
    int b = blockIdx.y;
    int q = blockIdx.x;
    const int* ir = idx + b * sb + (long long)q * sq;
    for (int kk = 0; kk < 4; ++kk) {
        int mm = ir[kk];
        for (int t = threadIdx.x; t < C * 3; t += blockDim.x)
            nb[kk * C * 3 + t] = xin[(size_t)(b * 3 * C + t) * Np + mm];
    }
    __syncthreads();
    int o = threadIdx.x;
    if (o >= C) return;
    const float* wr = wp + o * C;
    float best = -3.4e38f;
    int bk = 0;
    for (int kk = 0; kk < 4; ++kk) {
        const float* cl = &nb[kk * C * 3];
        float d0 = 0.f, d1 = 0.f, d2 = 0.f;
        for (int c = 0; c < C; ++c) {
            float w = wr[c];
            d0 += w * cl[3 * c]; d1 += w * cl[3 * c + 1]; d2 += w * cl[3 * c + 2];
        }
        float dot = cl[o * 3] * d0 + cl[o * 3 + 1] * d1 + cl[o * 3 + 2] * d2;
        if (dot > best) { best = dot; bk = kk; }
    }
    const float* cb = &nb[bk * C * 3];
    xout[((size_t)(b * C + o) * 3 + 0) * Nq + q] = cb[o * 3];
    xout[((size_t)(b * C + o) * 3 + 1) * Nq + q] = cb[o * 3 + 1];
    xout[((size_t)(b * C + o) * 3 + 2) * Nq + q] = cb[o * 3 + 2];
}

// ============================ eqv assembly ============================
__global__ void eqv_kernel(const float* __restrict__ x0, const float* __restrict__ x1,
                           const float* __restrict__ x2, const float* __restrict__ x3,
                           const float* __restrict__ x4,
                           const int* __restrict__ i1, const int* __restrict__ i2,
                           float* __restrict__ out_eqv)
{
    int n = blockIdx.x * 256 + threadIdx.x;
    int cv = blockIdx.y;       // 0..1259
    int b = blockIdx.z;
    int cc = cv / 3, v = cv % 3;
    float val;
    if (cc < 42)
        val = x0[((size_t)(b * 42 + cc) * 3 + v) * NTOT + n];
    else if (cc < 84)
        val = x1[((size_t)(b * 42 + (cc - 42)) * 3 + v) * NTOT + n];
    else if (cc < 168) {
        int m = i1[b * NTOT + n];
        val = x2[((size_t)(b * 84 + (cc - 84)) * 3 + v) * 512 + m];
    } else if (cc < 252) {
        int m = i1[b * NTOT + n];
        val = x3[((size_t)(b * 84 + (cc - 168)) * 3 + v) * 512 + m];
    } else {
        int m = i2[b * NTOT + n];
        val = x4[((size_t)(b * 168 + (cc - 252)) * 3 + v) * 128 + m];
    }
    out_eqv[((size_t)(b * 1260 + cv)) * NTOT + n] = val;
}

// ============================ mean_feat ============================
__global__ void meanfeat_kernel(const float* __restrict__ eqv,
                                float* __restrict__ out_mf,
                                float* __restrict__ ws_mf)
{
    __shared__ float r1[256];
    int cv = blockIdx.x, b = blockIdx.y;
    const float* row = eqv + ((size_t)(b * 1260 + cv)) * NTOT;
    float s = 0.f;
    for (int n = threadIdx.x; n < NTOT; n += 256) s += row[n];
    r1[threadIdx.x] = s;
    __syncthreads();
    for (int off = 128; off; off >>= 1) {
        if ((int)threadIdx.x < off) r1[threadIdx.x] += r1[threadIdx.x + off];
        __syncthreads();
    }
    if (threadIdx.x == 0) {
        float m = r1[0] / 2048.0f;
        out_mf[b * 1260 + cv] = m;
        ws_mf[b * 1260 + cv] = m;
    }
}

// ============================ z-chain + inv_gl ============================
__global__ void z_kernel(const float* __restrict__ mfw,
                         const float* __restrict__ wv1f, const float* __restrict__ wv1d,
                         const float* __restrict__ wv2f, const float* __restrict__ wv2d,
                         const float* __restrict__ w3,
                         float* __restrict__ invgl_ws, float* __restrict__ out_invgl)
{
#pragma clang fp contract(off)
    __shared__ float mf[1260];
    __shared__ float z1[630];
    __shared__ float z2[252];
    __shared__ float z3[6];
    int b = blockIdx.x;
    int t = threadIdx.x;
    for (int i = t; i < 1260; i += 256) mf[i] = mfw[b * 1260 + i];
    __syncthreads();
    if (t < 210) {
        float p0 = 0.f, p1 = 0.f, p2 = 0.f, d0 = 0.f, d1 = 0.f, d2 = 0.f;
        for (int c = 0; c < 420; ++c) {
            float m0 = mf[3 * c], m1 = mf[3 * c + 1], m2 = mf[3 * c + 2];
            float w = wv1f[t * 420 + c];
            p0 += w * m0; p1 += w * m1; p2 += w * m2;
            float w2 = wv1d[t * 420 + c];
            d0 += w2 * m0; d1 += w2 * m1; d2 += w2 * m2;
        }
        float dot = p0 * d0 + p1 * d1 + p2 * d2;
        float r0, r1, r2;
        if (dot >= 0.f) { r0 = p0; r1 = p1; r2 = p2; }
        else {
            float tq = dot / (d0 * d0 + d1 * d1 + d2 * d2 + 1e-6f);
            r0 = p0 - tq * d0; r1 = p1 - tq * d1; r2 = p2 - tq * d2;
        }
        z1[t * 3]     = 0.2f * p0 + 0.8f * r0;
        z1[t * 3 + 1] = 0.2f * p1 + 0.8f * r1;
        z1[t * 3 + 2] = 0.2f * p2 + 0.8f * r2;
    }
    __syncthreads();
    if (t < 84) {
        float p0 = 0.f, p1 = 0.f, p2 = 0.f, d0 = 0.f, d1 = 0.f, d2 = 0.f;
        for (int c = 0; c < 210; ++c) {
            float m0 = z1[3 * c], m1 = z1[3 * c + 1], m2 = z1[3 * c + 2];
            float w = wv2f[t * 210 + c];
            p0 += w * m0; p1 += w * m1; p2 += w * m2;
            float w2 = wv2d[t * 210 + c];
            d0 += w2 * m0; d1 += w2 * m1; d2 += w2 * m2;
        }
        float dot = p0 * d0 + p1 * d1 + p2 * d2;
        float r0, r1, r2;
        if (dot >= 0.f) { r0 = p0; r1 = p1; r2 = p2; }
        else {
            float tq = dot / (d0 * d0 + d1 * d1 + d2 * d2 + 1e-6f);
            r0 = p0 - tq * d0; r1 = p1 - tq * d1; r2 = p2 - tq * d2;
        }
        z2[t * 3]     = 0.2f * p0 + 0.8f * r0;
        z2[t * 3 + 1] = 0.2f * p1 + 0.8f * r1;
        z2[t * 3 + 2] = 0.2f * p2 + 0.8f * r2;
    }
    __syncthreads();
    if (t < 6) {
        int v = t / 2, kt = t % 2;
        float s = 0.f;
        for (int c = 0; c < 84; ++c) s += z2[c * 3 + v] * w3[kt * 84 + c];
        z3[v * 2 + kt] = s;
    }
    __syncthreads();
    for (int i = t; i < 840; i += 256) {
        int ii = i / 2, kt = i % 2;
        float s = mf[ii * 3] * z3[0 + kt] + mf[ii * 3 + 1] * z3[2 + kt] +
                  mf[ii * 3 + 2] * z3[4 + kt];
        invgl_ws[b * 840 + i] = s;
        out_invgl[b * 840 + i] = s;
    }
}

// ============================ invin build ============================
__global__ void invin_kernel(const float* __restrict__ normv,
                             const int* __restrict__ cat,
                             const float* __restrict__ mfw,
                             const float* __restrict__ invglw,
                             const float* __restrict__ coord,
                             float* __restrict__ invin)
{
#pragma clang fp contract(off)
    int col = blockIdx.x * 256 + threadIdx.x;   // 0..8191
    int c = blockIdx.y;                          // 0..1266
    int b = col >> 11, n = col & 2047;
    float val;
    if (c == 0) val = normv[b * NTOT + n];
    else if (c < 841) val = invglw[b * 840 + (c - 1)];
    else if (c < 1261) {
        int i = c - 841;
        val = mfw[b * 1260 + i * 3]     * coord[(b * 3 + 0) * NTOT + n]
            + mfw[b * 1260 + i * 3 + 1] * coord[(b * 3 + 1) * NTOT + n]
            + mfw[b * 1260 + i * 3 + 2] * coord[(b * 3 + 2) * NTOT + n];
    } else val = (cat[b] == c - 1261) ? 1.f : 0.f;
    invin[(size_t)c * 8192 + col] = val;
}

// ============================ GEMM + bias (f32, 64x64x16) ============================
__global__ void gemm_bias_kernel(const float* __restrict__ A,
                                 const float* __restrict__ Bm,
                                 const float* __restrict__ bias,
                                 float* __restrict__ C, int M, int K)
{
    __shared__ float As[16][68];
    __shared__ float Bs[16][68];
    int bn = blockIdx.x * 64;
    int bm = blockIdx.y * 64;
    int tid = threadIdx.x;
    int tx = tid % 16, ty = tid / 16;
    float acc[4][4];
#pragma unroll
    for (int i = 0; i < 4; ++i)
#pragma unroll
        for (int j = 0; j < 4; ++j) acc[i][j] = 0.f;
    for (int k0 = 0; k0 < K; k0 += 16) {
        for (int e = tid; e < 1024; e += 256) {
            int mm = e >> 4, kk = e & 15;
            int gm = bm + mm, gk = k0 + kk;
            As[kk][mm] = (gm < M && gk < K) ? A[(size_t)gm * K + gk] : 0.f;
        }
        for (int e = tid; e < 1024; e += 256) {
            int kk = e >> 6, nn = e & 63;
            int gk = k0 + kk;
            Bs[kk][nn] = (gk < K) ? Bm[(size_t)gk * 8192 + bn + nn] : 0.f;
        }
        __syncthreads();
#pragma unroll
        for (int kk = 0; kk < 16; ++kk) {
            float a[4], bv[4];
#pragma unroll
            for (int i = 0; i < 4; ++i) a[i] = As[kk][ty * 4 + i];
#pragma unroll
            for (int j = 0; j < 4; ++j) bv[j] = Bs[kk][tx * 4 + j];
#pragma unroll
            for (int i = 0; i < 4; ++i)
#pragma unroll
                for (int j = 0; j < 4; ++j) acc[i][j] += a[i] * bv[j];
        }
        __syncthreads();
    }
#pragma unroll
    for (int i = 0; i < 4; ++i) {
        int gm = bm + ty * 4 + i;
        if (gm < M) {
            float bs = bias[gm];
#pragma unroll
            for (int j = 0; j < 4; ++j)
                C[(size_t)gm * 8192 + bn + tx * 4 + j] = acc[i][j] + bs;
        }
    }
}

// ============================ conv BN stats / apply ============================
__global__ void cstats_kernel(const float* __restrict__ y, float* __restrict__ st, int M)
{
    __shared__ float r1[256], r2[256];
    int o = blockIdx.x;
    const float* row = y + (size_t)o * 8192;
    float s = 0.f, s2 = 0.f;
    for (int c = threadIdx.x; c < 8192; c += 256) {
        float v = row[c];
        s += v; s2 += v * v;
    }
    r1[threadIdx.x] = s; r2[threadIdx.x] = s2;
    __syncthreads();
    for (int off = 128; off; off >>= 1) {
        if ((int)threadIdx.x < off) {
            r1[threadIdx.x] += r1[threadIdx.x + off];
            r2[threadIdx.x] += r2[threadIdx.x + off];
        }
        __syncthreads();
    }
    if (threadIdx.x == 0) {
        float m = r1[0] / 8192.0f;
        float var = r2[0] / 8192.0f - m * m;
        st[o] = m;
        st[M + o] = sqrtf(var + 1e-5f);
    }
}

__global__ void bnrelu_kernel(float* __restrict__ y, const float* __restrict__ st,
                              const float* __restrict__ g, const float* __restrict__ be,
                              int M)
{
#pragma clang fp contract(off)
    int o = blockIdx.y;
    int col = blockIdx.x * 256 + threadIdx.x;
    float m = st[o], sqv = st[M + o];
    size_t i = (size_t)o * 8192 + col;
    float v = g[o] * (y[i] - m) / sqv + be[o];
    y[i] = v > 0.f ? v : 0.f;
}

__global__ void bnrelu_out_kernel(const float* __restrict__ y, const float* __restrict__ st,
                                  const float* __restrict__ g, const float* __restrict__ be,
                                  float* __restrict__ outinv)
{
#pragma clang fp contract(off)
    int o = blockIdx.y;
    int col = blockIdx.x * 256 + threadIdx.x;
    int b = col >> 11, n = col & 2047;
    float m = st[o], sqv = st[420 + o];
    float v = g[o] * (y[(size_t)o * 8192 + col] - m) / sqv + be[o];
    outinv[((size_t)(b * 420 + o)) * 2048 + n] = v > 0.f ? v : 0.f;
}

// ============================ launch ============================
extern "C" void kernel_launch(void* const* d_in, const int* in_sizes, int n_in,
                              void* d_out, int out_size, void* d_ws, size_t ws_size,
                              hipStream_t stream)
{
    (void)in_sizes; (void)n_in; (void)out_size; (void)ws_size;
    const float* xc   = (const float*)d_in[0];
    const float* normv= (const float*)d_in[1];
    const int*   cat  = (const int*)d_in[2];
    const float* wf0  = (const float*)d_in[3];
    const float* wd0  = (const float*)d_in[4];
    const float* g0   = (const float*)d_in[5];
    const float* b0   = (const float*)d_in[6];
    const float* wf1  = (const float*)d_in[7];
    const float* wd1  = (const float*)d_in[8];
    const float* g1   = (const float*)d_in[9];
    const float* b1   = (const float*)d_in[10];
    const float* wp1  = (const float*)d_in[11];
    const float* wf2  = (const float*)d_in[12];
    const float* wd2  = (const float*)d_in[13];
    const float* g2   = (const float*)d_in[14];
    const float* b2   = (const float*)d_in[15];
    const float* wf3  = (const float*)d_in[16];
    const float* wd3  = (const float*)d_in[17];
    const float* g3   = (const float*)d_in[18];
    const float* b3   = (const float*)d_in[19];
    const float* wp2  = (const float*)d_in[20];
    const float* wf4  = (const float*)d_in[21];
    const float* wd4  = (const float*)d_in[22];
    const float* g4   = (const float*)d_in[23];
    const float* b4   = (const float*)d_in[24];
    const float* wv1f = (const float*)d_in[25];
    const float* wv1d = (const float*)d_in[26];
    const float* wv2f = (const float*)d_in[27];
    const float* wv2d = (const float*)d_in[28];
    const float* w3   = (const float*)d_in[29];
    const float* ws1  = (const float*)d_in[30];
    const float* cb1  = (const float*)d_in[31];
    const float* sg1  = (const float*)d_in[32];
    const float* sb1  = (const float*)d_in[33];
    const float* ws2  = (const float*)d_in[34];
    const float* cb2  = (const float*)d_in[35];
    const float* sg2  = (const float*)d_in[36];
    const float* sb2  = (const float*)d_in[37];
    const float* ws3  = (const float*)d_in[38];
    const float* cb3  = (const float*)d_in[39];
    const float* sg3  = (const float*)d_in[40];
    const float* sb3  = (const float*)d_in[41];

    float* ws = (float*)d_ws;
    float* out = (float*)d_out;

    int*    idx20 = (int*)(ws + WS_IDX20);
    float*  fs    = ws + WS_FS;
    float*  x0    = ws + WS_X0;
    float*  x1    = ws + WS_X1;
    float*  xm2   = ws + WS_XM2;
    float*  x2    = ws + WS_X2;
    float*  x3    = ws + WS_X3;
    int*    idx42 = (int*)(ws + WS_IDX42);
    float*  xm4   = ws + WS_XM4;
    float*  x4    = ws + WS_X4;
    int*    i1p   = (int*)(ws + WS_I1);
    int*    i2p   = (int*)(ws + WS_I2);
    float*  mfw   = ws + WS_MF;
    float*  invgl = ws + WS_INVGL;
    double* st    = (double*)(ws + WS_STATS);
    float*  cst   = ws + WS_CST;
    float*  invin = ws + WS_INVIN;
    float*  y1    = ws + WS_Y1;
    float*  y2    = ws + WS_Y2;
    float*  y3    = ws + WS_Y3;

    hipMemsetAsync((void*)st, 0, 840 * sizeof(double), stream);

    // KNN-20 over all points (also serves as knn-4 prefix for pool stage 1)
    knn_kernel<20><<<dim3(2048, 4), 256, 0, stream>>>(xc, 2048, 1, 1, idx20, 2048);
    surf_build_kernel<<<640, 256, 0, stream>>>(xc, idx20, fs);

    // stage 0
    stats0_kernel<<<2048, 64, 0, stream>>>(fs, wf0, st + ST0_OFF);
    apply0_kernel<<<2048, 64, 0, stream>>>(fs, wf0, wd0, g0, b0, st + ST0_OFF, x0);

    // stage 1: x1 = vn_block(x0)
    vn_stats_kernel<<<dim3(128, 4), 256, 0, stream>>>(x0, wf1, st + ST1_OFF, 42, 42, 2048);
    vn_apply_kernel<<<dim3(256, 4), 256, 0, stream>>>(x0, wf1, wd1, g1, b1, st + ST1_OFF,
                                                      8192.0, 42, 42, 2048, x1);

    // pool 1: neighbors = first 4 of idx20 rows at n=4q
    vn_pool_kernel<<<dim3(512, 4), 256, 0, stream>>>(x1, idx20, 40960LL, 80, wp1, xm2,
                                                     42, 2048, 512);
    // stage 2
    vn_stats_kernel<<<dim3(32, 4), 256, 0, stream>>>(xm2, wf2, st + ST2_OFF, 42, 84, 512);
    vn_apply_kernel<<<dim3(64, 4), 256, 0, stream>>>(xm2, wf2, wd2, g2, b2, st + ST2_OFF,
                                                     2048.0, 42, 84, 512, x2);
    // stage 3
    vn_stats_kernel<<<dim3(32, 4), 256, 0, stream>>>(x2, wf3, st + ST3_OFF, 84, 84, 512);
    vn_apply_kernel<<<dim3(64, 4), 256, 0, stream>>>(x2, wf3, wd3, g3, b3, st + ST3_OFF,
                                                     2048.0, 84, 84, 512, x3);

    // knn-4 on coord2 (cands stride 4), queries stride 16 (coord2 ::4)
    knn_kernel<4><<<dim3(128, 4), 256, 0, stream>>>(xc, 512, 4, 16, idx42, 128);
    vn_pool_kernel<<<dim3(128, 4), 256, 0, stream>>>(x3, idx42, 512LL, 4, wp2, xm4,
                                                     84, 512, 128);
    // stage 4
    vn_stats_kernel<<<dim3(8, 4), 256, 0, stream>>>(xm4, wf4, st + ST4_OFF, 84, 168, 128);
    vn_apply_kernel<<<dim3(16, 4), 256, 0, stream>>>(xm4, wf4, wd4, g4, b4, st + ST4_OFF,
                                                     512.0, 84, 168, 128, x4);

    // nearest-neighbor upsample indices
    nearest_kernel<<<dim3(2048, 4), 256, 0, stream>>>(xc, 512, 4, i1p);
    nearest_kernel<<<dim3(2048, 4), 256, 0, stream>>>(xc, 128, 16, i2p);

    // eqv assembly (output 0) and mean_feat (output 1)
    eqv_kernel<<<dim3(8, 1260, 4), 256, 0, stream>>>(x0, x1, x2, x3, x4, i1p, i2p,
                                                     out + OUT_EQV);
    meanfeat_kernel<<<dim3(1260, 4), 256, 0, stream>>>(out + OUT_EQV, out + OUT_MF, mfw);

    // z chain + inv_gl (output 3)
    z_kernel<<<4, 256, 0, stream>>>(mfw, wv1f, wv1d, wv2f, wv2d, w3, invgl,
                                    out + OUT_INVGL);

    // invariant branch
    invin_kernel<<<dim3(32, 1267), 256, 0, stream>>>(normv, cat, mfw, invgl, xc, invin);

    gemm_bias_kernel<<<dim3(128, 16), 256, 0, stream>>>(ws1, invin, cb1, y1, 1024, 1267);
    cstats_kernel<<<1024, 256, 0, stream>>>(y1, cst + CST1_OFF, 1024);
    bnrelu_kernel<<<dim3(32, 1024), 256, 0, stream>>>(y1, cst + CST1_OFF, sg1, sb1, 1024);

    gemm_bias_kernel<<<dim3(128, 8), 256, 0, stream>>>(ws2, y1, cb2, y2, 512, 1024);
    cstats_kernel<<<512, 256, 0, stream>>>(y2, cst + CST2_OFF, 512);
    bnrelu_kernel<<<dim3(32, 512), 256, 0, stream>>>(y2, cst + CST2_OFF, sg2, sb2, 512);

    gemm_bias_kernel<<<dim3(128, 7), 256, 0, stream>>>(ws3, y2, cb3, y3, 420, 512);
    cstats_kernel<<<420, 256, 0, stream>>>(y3, cst + CST3_OFF, 420);
    bnrelu_out_kernel<<<dim3(32, 420), 256, 0, stream>>>(y3, cst + CST3_OFF, sg3, sb3,
                                                         out + OUT_INV);
}

// Round 3
// 1347.223 us; speedup vs baseline: 1.4144x; 1.4144x over previous
//
#include <hip/hip_runtime.h>
#include <hip/hip_bf16.h>
#include <cstdint>
#include <cstddef>

#define NTOT 2048
#define BTOT 4

typedef short bf16x8 __attribute__((ext_vector_type(8)));
typedef float f32x4 __attribute__((ext_vector_type(4)));

__device__ inline unsigned short f2b(float v) {
    __hip_bfloat16 h = __float2bfloat16(v);
    return *reinterpret_cast<unsigned short*>(&h);
}

// ---------------- workspace layout (float-element offsets) ----------------
// Front-end (live until invinT built):
static const size_t WS_IDX20 = 0;                       // int[163840]
static const size_t WS_FS    = 163840;                  // float[1474560]
static const size_t WS_X0    = 1638400;                 // float[2064384] (B,42,3,2048)
static const size_t WS_X1    = 3702784;                 // float[2064384]
static const size_t WS_XM2   = 5767168;                 // float[258048]
static const size_t WS_X2    = 6025216;                 // float[516096]
static const size_t WS_X3    = 6541312;                 // float[516096]
static const size_t WS_IDX42 = 7057408;                 // int[2048]
static const size_t WS_XM4   = 7059456;                 // float[129024]
static const size_t WS_X4    = 7188480;                 // float[258048]
static const size_t WS_I1    = 7446528;                 // int[8192]
static const size_t WS_I2    = 7454720;                 // int[8192]
static const size_t WS_MF    = 7462912;                 // float[5040]
static const size_t WS_INVGL = 7467952;                 // float[3360]
static const size_t WS_STATS = 7471312;                 // double[840] (1680 fl slots)
static const size_t WS_CST   = 7472992;                 // float[3912] conv bn sums
// Conv stack:
static const size_t WS_INVT  = 7480320;                 // ushort[8192*1280]  (5,242,880 fl)
static const size_t WS_W1B   = 12723200;                // ushort[1024*1280]  (655,360 fl)
static const size_t WS_W2B   = 13378560;                // ushort[512*1024]   (262,144 fl)
static const size_t WS_W3B   = 13640704;                // ushort[512*512]    (131,072 fl)
static const size_t WS_Y1T   = 13771776;                // float[8192*1024]   (8,388,608 fl)
// Overlays (front-end dead by the time these are written):
static const size_t WS_Y1B   = 0;                       // ushort[8192*1024] (4,194,304 fl)
static const size_t WS_Y2T   = WS_INVT;                 // float[8192*512]   (invinT dead)
static const size_t WS_Y2B   = 4194304;                 // ushort[8192*512]  (2,097,152 fl)
static const size_t WS_Y3T   = WS_Y1T;                  // float[8192*420]   (y1t dead)
// peak = 22,160,384 floats = 88.6 MB (< known-good 105 MB)

#define ST0_OFF 0
#define ST1_OFF 84
#define ST2_OFF 168
#define ST3_OFF 336
#define ST4_OFF 504
#define CST1_OFF 0
#define CST2_OFF 2048
#define CST3_OFF 3072

#define OUT_EQV   0
#define OUT_MF    10321920
#define OUT_INV   10326960
#define OUT_INVGL 13767600

// ============================ KNN (wave-per-query) ============================
template <int K>
__global__ void knn64_kernel(const float* __restrict__ coord, int cand_cnt,
                             int cand_stride, int q_stride, int* __restrict__ out_idx,
                             int q_cnt)
{
#pragma clang fp contract(off)
    __shared__ float pdv[2048];
    int b = blockIdx.y;
    int q = blockIdx.x;
    int lane = threadIdx.x;
    int nq = q * q_stride;
    float qx = coord[(b * 3 + 0) * NTOT + nq];
    float qy = coord[(b * 3 + 1) * NTOT + nq];
    float qz = coord[(b * 3 + 2) * NTOT + nq];
    float xxq = qx * qx + qy * qy + qz * qz;
    for (int m = lane; m < cand_cnt; m += 64) {
        int mo = m * cand_stride;
        float cx = coord[(b * 3 + 0) * NTOT + mo];
        float cy = coord[(b * 3 + 1) * NTOT + mo];
        float cz = coord[(b * 3 + 2) * NTOT + mo];
        float inner = qx * cx + qy * cy + qz * cz;
        float xxc = cx * cx + cy * cy + cz * cz;
        pdv[m] = (2.0f * inner - xxq) - xxc;
    }
    __syncthreads();
    for (int kk = 0; kk < K; ++kk) {
        float bv = -3.4e38f;
        int bi = 0x7fffffff;
        for (int m = lane; m < cand_cnt; m += 64) {
            float v = pdv[m];
            if (v > bv || (v == bv && m < bi)) { bv = v; bi = m; }
        }
        for (int off = 32; off; off >>= 1) {
            float ov = __shfl_down(bv, off);
            int   oi = __shfl_down(bi, off);
            if (ov > bv || (ov == bv && oi < bi)) { bv = ov; bi = oi; }
        }
        int bi0 = __shfl(bi, 0);
        if (lane == 0) {
            out_idx[((size_t)(b * q_cnt) + q) * K + kk] = bi0;
            pdv[bi0] = -3.4e38f;
        }
        __syncthreads();
    }
}

// ============================ nearest index (argmin) ============================
__global__ void nearest_kernel(const float* __restrict__ coord, int cand_cnt,
                               int cand_stride, int* __restrict__ out)
{
#pragma clang fp contract(off)
    __shared__ float rv[4];
    __shared__ int   ri[4];
    int b = blockIdx.y;
    int n = blockIdx.x;
    float qx = coord[(b * 3 + 0) * NTOT + n];
    float qy = coord[(b * 3 + 1) * NTOT + n];
    float qz = coord[(b * 3 + 2) * NTOT + n];
    float tt = qx * qx + qy * qy + qz * qz;
    float bv = 3.4e38f;
    int bi = 0x7fffffff;
    for (int m = threadIdx.x; m < cand_cnt; m += blockDim.x) {
        int mo = m * cand_stride;
        float cx = coord[(b * 3 + 0) * NTOT + mo];
        float cy = coord[(b * 3 + 1) * NTOT + mo];
        float cz = coord[(b * 3 + 2) * NTOT + mo];
        float inner = qx * cx + qy * cy + qz * cz;
        float ss = cx * cx + cy * cy + cz * cz;
        float d = (tt - 2.0f * inner) + ss;
        if (d < bv || (d == bv && m < bi)) { bv = d; bi = m; }
    }
    for (int off = 32; off; off >>= 1) {
        float ov = __shfl_down(bv, off);
        int   oi = __shfl_down(bi, off);
        if (ov < bv || (ov == bv && oi < bi)) { bv = ov; bi = oi; }
    }
    int wid = threadIdx.x >> 6;
    if ((threadIdx.x & 63) == 0) { rv[wid] = bv; ri[wid] = bi; }
    __syncthreads();
    if (threadIdx.x == 0) {
        for (int w = 1; w < 4; ++w)
            if (rv[w] < bv || (rv[w] == bv && ri[w] < bi)) { bv = rv[w]; bi = ri[w]; }
        out[b * NTOT + n] = bi;
    }
}

// ============================ surface feature build ============================
__global__ void surf_build_kernel(const float* __restrict__ coord,
                                  const int* __restrict__ idx20,
                                  float* __restrict__ fs)
{
#pragma clang fp contract(off)
    int t = blockIdx.x * 256 + threadIdx.x;
    if (t >= BTOT * NTOT * 20) return;
    int n = (t / 20) & (NTOT - 1);
    int b = t / (20 * NTOT);
    int m = idx20[t];
    float cx = coord[(b * 3 + 0) * NTOT + n];
    float cy = coord[(b * 3 + 1) * NTOT + n];
    float cz = coord[(b * 3 + 2) * NTOT + n];
    float nx = coord[(b * 3 + 0) * NTOT + m];
    float ny = coord[(b * 3 + 1) * NTOT + m];
    float nz = coord[(b * 3 + 2) * NTOT + m];
    float* f9 = fs + (size_t)t * 9;
    f9[0] = nx - cx; f9[1] = ny - cy; f9[2] = nz - cz;
    f9[3] = cx;      f9[4] = cy;      f9[5] = cz;
    f9[6] = ny * cz - nz * cy;
    f9[7] = nz * cx - nx * cz;
    f9[8] = nx * cy - ny * cx;
}

// ============================ stage-0 stats / apply ============================
__global__ void stats0_kernel(const float* __restrict__ fs,
                              const float* __restrict__ wf0,
                              double* __restrict__ stats)
{
#pragma clang fp contract(off)
    __shared__ float fl[720];
    int blk = blockIdx.x;
    int b = blk / 512;
    int n0 = (blk % 512) * 4;
    for (int t = threadIdx.x; t < 720; t += 64)
        fl[t] = fs[((size_t)(b * NTOT + n0) * 20) * 9 + t];
    __syncthreads();
    int o = threadIdx.x;
    if (o < 42) {
        float w0 = wf0[o * 3], w1 = wf0[o * 3 + 1], w2 = wf0[o * 3 + 2];
        double s = 0.0, s2 = 0.0;
        for (int i = 0; i < 80; ++i) {
            const float* f9 = &fl[i * 9];
            float p0 = w0 * f9[0] + w1 * f9[3] + w2 * f9[6];
            float p1 = w0 * f9[1] + w1 * f9[4] + w2 * f9[7];
            float p2 = w0 * f9[2] + w1 * f9[5] + w2 * f9[8];
            float nrm = sqrtf(p0 * p0 + p1 * p1 + p2 * p2) + 1e-6f;
            s += (double)nrm; s2 += (double)nrm * (double)nrm;
        }
        atomicAdd(&stats[o], s);
        atomicAdd(&stats[42 + o], s2);
    }
}

__global__ void apply0_kernel(const float* __restrict__ fs,
                              const float* __restrict__ wf0,
                              const float* __restrict__ wd0,
                              const float* __restrict__ g0,
                              const float* __restrict__ b0,
                              const double* __restrict__ stats,
                              float* __restrict__ x0)
{
#pragma clang fp contract(off)
    __shared__ float fl[720];
    int blk = blockIdx.x;
    int b = blk / 512;
    int n0 = (blk % 512) * 4;
    for (int t = threadIdx.x; t < 720; t += 64)
        fl[t] = fs[((size_t)(b * NTOT + n0) * 20) * 9 + t];
    __syncthreads();
    int o = threadIdx.x;
    if (o >= 42) return;
    double S1 = stats[o], S2 = stats[42 + o];
    double md = S1 / 163840.0;
    float m = (float)md;
    float var = (float)(S2 / 163840.0 - md * md);
    float sqv = sqrtf(var + 1e-5f);
    float gg = g0[o], bb = b0[o];
    float wa0 = wf0[o * 3], wa1 = wf0[o * 3 + 1], wa2 = wf0[o * 3 + 2];
    float wb0 = wd0[o * 3], wb1 = wd0[o * 3 + 1], wb2 = wd0[o * 3 + 2];
    for (int pp = 0; pp < 4; ++pp) {
        float r8[3][8];
        float tl[3][4];
        for (int k = 0; k < 20; ++k) {
            const float* f9 = &fl[(pp * 20 + k) * 9];
            float p0 = wa0 * f9[0] + wa1 * f9[3] + wa2 * f9[6];
            float p1 = wa0 * f9[1] + wa1 * f9[4] + wa2 * f9[7];
            float p2 = wa0 * f9[2] + wa1 * f9[5] + wa2 * f9[8];
            float d0 = wb0 * f9[0] + wb1 * f9[3] + wb2 * f9[6];
            float d1 = wb0 * f9[1] + wb1 * f9[4] + wb2 * f9[7];
            float d2 = wb0 * f9[2] + wb1 * f9[5] + wb2 * f9[8];
            float nrm = sqrtf(p0 * p0 + p1 * p1 + p2 * p2) + 1e-6f;
            float nb = gg * (nrm - m) / sqv + bb;
            p0 = p0 / nrm * nb;
            p1 = p1 / nrm * nb;
            p2 = p2 / nrm * nb;
            float dot = p0 * d0 + p1 * d1 + p2 * d2;
            float r0, r1, r2;
            if (dot >= 0.f) { r0 = p0; r1 = p1; r2 = p2; }
            else {
                float tq = dot / (d0 * d0 + d1 * d1 + d2 * d2 + 1e-6f);
                r0 = p0 - tq * d0; r1 = p1 - tq * d1; r2 = p2 - tq * d2;
            }
            float o0 = 0.2f * p0 + 0.8f * r0;
            float o1 = 0.2f * p1 + 0.8f * r1;
            float o2 = 0.2f * p2 + 0.8f * r2;
            if (k < 8)       { r8[0][k] = o0;       r8[1][k] = o1;       r8[2][k] = o2; }
            else if (k < 16) { r8[0][k-8] += o0;    r8[1][k-8] += o1;    r8[2][k-8] += o2; }
            else             { tl[0][k-16] = o0;    tl[1][k-16] = o1;    tl[2][k-16] = o2; }
        }
        int n = n0 + pp;
        for (int v = 0; v < 3; ++v) {
            float res = ((r8[v][0] + r8[v][1]) + (r8[v][2] + r8[v][3])) +
                        ((r8[v][4] + r8[v][5]) + (r8[v][6] + r8[v][7]));
            res += tl[v][0]; res += tl[v][1]; res += tl[v][2]; res += tl[v][3];
            x0[((size_t)(b * 42 + o) * 3 + v) * NTOT + n] = res / 20.0f;
        }
    }
}

// ============================ generic VN stats / apply ============================
__global__ void vn_stats_kernel(const float* __restrict__ xin,
                                const float* __restrict__ wf,
                                double* __restrict__ stats,
                                int Ci, int Co, int Npts)
{
#pragma clang fp contract(off)
    __shared__ float col[252];
    int b = blockIdx.y;
    int o = threadIdx.x;
    double s = 0.0, s2 = 0.0;
    for (int it = 0; it < 16; ++it) {
        int pt = blockIdx.x * 16 + it;
        __syncthreads();
        for (int t = threadIdx.x; t < Ci * 3; t += blockDim.x)
            col[t] = xin[(size_t)(b * 3 * Ci + t) * Npts + pt];
        __syncthreads();
        if (o < Co) {
            const float* wr = wf + o * Ci;
            float p0 = 0.f, p1 = 0.f, p2 = 0.f;
            for (int c = 0; c < Ci; ++c) {
                float w = wr[c];
                p0 += w * col[3 * c]; p1 += w * col[3 * c + 1]; p2 += w * col[3 * c + 2];
            }
            float nrm = sqrtf(p0 * p0 + p1 * p1 + p2 * p2) + 1e-6f;
            s += (double)nrm; s2 += (double)nrm * (double)nrm;
        }
    }
    if (o < Co) { atomicAdd(&stats[o], s); atomicAdd(&stats[Co + o], s2); }
}

__global__ void vn_apply_kernel(const float* __restrict__ xin,
                                const float* __restrict__ wf,
                                const float* __restrict__ wd,
                                const float* __restrict__ g,
                                const float* __restrict__ bbp,
                                const double* __restrict__ stats,
                                double count, int Ci, int Co, int Npts,
                                float* __restrict__ xout)
{
#pragma clang fp contract(off)
    __shared__ float col[252];
    int b = blockIdx.y;
    int o = threadIdx.x;
    float m = 0.f, sqv = 1.f, gg = 0.f, bb = 0.f;
    if (o < Co) {
        double S1 = stats[o], S2 = stats[Co + o];
        double md = S1 / count;
        m = (float)md;
        float var = (float)(S2 / count - md * md);
        sqv = sqrtf(var + 1e-5f);
        gg = g[o]; bb = bbp[o];
    }
    for (int it = 0; it < 8; ++it) {
        int pt = blockIdx.x * 8 + it;
        __syncthreads();
        for (int t = threadIdx.x; t < Ci * 3; t += blockDim.x)
            col[t] = xin[(size_t)(b * 3 * Ci + t) * Npts + pt];
        __syncthreads();
        if (o < Co) {
            const float* wr = wf + o * Ci;
            const float* wdr = wd + o * Ci;
            float p0 = 0.f, p1 = 0.f, p2 = 0.f, d0 = 0.f, d1 = 0.f, d2 = 0.f;
            for (int c = 0; c < Ci; ++c) {
                float c0 = col[3 * c], c1 = col[3 * c + 1], c2 = col[3 * c + 2];
                float w = wr[c];
                p0 += w * c0; p1 += w * c1; p2 += w * c2;
                float w2 = wdr[c];
                d0 += w2 * c0; d1 += w2 * c1; d2 += w2 * c2;
            }
            float nrm = sqrtf(p0 * p0 + p1 * p1 + p2 * p2) + 1e-6f;
            float nb = gg * (nrm - m) / sqv + bb;
            p0 = p0 / nrm * nb;
            p1 = p1 / nrm * nb;
            p2 = p2 / nrm * nb;
            float dot = p0 * d0 + p1 * d1 + p2 * d2;
            float r0, r1, r2;
            if (dot >= 0.f) { r0 = p0; r1 = p1; r2 = p2; }
            else {
                float tq = dot / (d0 * d0 + d1 * d1 + d2 * d2 + 1e-6f);
                r0 = p0 - tq * d0; r1 = p1 - tq * d1; r2 = p2 - tq * d2;
            }
            xout[((size_t)(b * Co + o) * 3 + 0) * Npts + pt] = 0.2f * p0 + 0.8f * r0;
            xout[((size_t)(b * Co + o) * 3 + 1) * Npts + pt] = 0.2f * p1 + 0.8f * r1;
            xout[((size_t)(b * Co + o) * 3 + 2) * Npts + pt] = 0.2f * p2 + 0.8f * r2;
        }
    }
}

// ============================ VN max-pool-down ============================
__global__ void vn_pool_kernel(const float* __restrict__ xin,
                               const int* __restrict__ idx, long long sb, int sq,
                               const float* __restrict__ wp,
                               float* __restrict__ xout,
                               int C, int Np, int Nq)
{
#pragma clang fp contract(off)
    __shared__ float nb[4 * 84 * 3];
    int b = blockIdx.y;
    int q = blockIdx.x;
    const int* ir = idx + b * sb + (long long)q * sq;
    for (int kk = 0; kk < 4; ++kk) {
        int mm = ir[kk];
        for (int t = threadIdx.x; t < C * 3; t += blockDim.x)
            nb[kk * C * 3 + t] = xin[(size_t)(b * 3 * C + t) * Np + mm];
    }
    __syncthreads();
    int o = threadIdx.x;
    if (o >= C) return;
    const float* wr = wp + o * C;
    float best = -3.4e38f;
    int bk = 0;
    for (int kk = 0; kk < 4; ++kk) {
        const float* cl = &nb[kk * C * 3];
        float d0 = 0.f, d1 = 0.f, d2 = 0.f;
        for (int c = 0; c < C; ++c) {
            float w = wr[c];
            d0 += w * cl[3 * c]; d1 += w * cl[3 * c + 1]; d2 += w * cl[3 * c + 2];
        }
        float dot = cl[o * 3] * d0 + cl[o * 3 + 1] * d1 + cl[o * 3 + 2] * d2;
        if (dot > best) { best = dot; bk = kk; }
    }
    const float* cb = &nb[bk * C * 3];
    xout[((size_t)(b * C + o) * 3 + 0) * Nq + q] = cb[o * 3];
    xout[((size_t)(b * C + o) * 3 + 1) * Nq + q] = cb[o * 3 + 1];
    xout[((size_t)(b * C + o) * 3 + 2) * Nq + q] = cb[o * 3 + 2];
}

// ============================ eqv assembly ============================
__global__ void eqv_kernel(const float* __restrict__ x0, const float* __restrict__ x1,
                           const float* __restrict__ x2, const float* __restrict__ x3,
                           const float* __restrict__ x4,
                           const int* __restrict__ i1, const int* __restrict__ i2,
                           float* __restrict__ out_eqv)
{
    int n = blockIdx.x * 256 + threadIdx.x;
    int cv = blockIdx.y;
    int b = blockIdx.z;
    int cc = cv / 3, v = cv % 3;
    float val;
    if (cc < 42)
        val = x0[((size_t)(b * 42 + cc) * 3 + v) * NTOT + n];
    else if (cc < 84)
        val = x1[((size_t)(b * 42 + (cc - 42)) * 3 + v) * NTOT + n];
    else if (cc < 168) {
        int m = i1[b * NTOT + n];
        val = x2[((size_t)(b * 84 + (cc - 84)) * 3 + v) * 512 + m];
    } else if (cc < 252) {
        int m = i1[b * NTOT + n];
        val = x3[((size_t)(b * 84 + (cc - 168)) * 3 + v) * 512 + m];
    } else {
        int m = i2[b * NTOT + n];
        val = x4[((size_t)(b * 168 + (cc - 252)) * 3 + v) * 128 + m];
    }
    out_eqv[((size_t)(b * 1260 + cv)) * NTOT + n] = val;
}

// ============================ mean_feat ============================
__global__ void meanfeat_kernel(const float* __restrict__ eqv,
                                float* __restrict__ out_mf,
                                float* __restrict__ ws_mf)
{
    __shared__ float r1[256];
    int cv = blockIdx.x, b = blockIdx.y;
    const float* row = eqv + ((size_t)(b * 1260 + cv)) * NTOT;
    float s = 0.f;
    for (int n = threadIdx.x; n < NTOT; n += 256) s += row[n];
    r1[threadIdx.x] = s;
    __syncthreads();
    for (int off = 128; off; off >>= 1) {
        if ((int)threadIdx.x < off) r1[threadIdx.x] += r1[threadIdx.x + off];
        __syncthreads();
    }
    if (threadIdx.x == 0) {
        float m = r1[0] / 2048.0f;
        out_mf[b * 1260 + cv] = m;
        ws_mf[b * 1260 + cv] = m;
    }
}

// ============================ z-chain + inv_gl ============================
__global__ void z_kernel(const float* __restrict__ mfw,
                         const float* __restrict__ wv1f, const float* __restrict__ wv1d,
                         const float* __restrict__ wv2f, const float* __restrict__ wv2d,
                         const float* __restrict__ w3,
                         float* __restrict__ invgl_ws, float* __restrict__ out_invgl)
{
#pragma clang fp contract(off)
    __shared__ float mf[1260];
    __shared__ float z1[630];
    __shared__ float z2[252];
    __shared__ float z3[6];
    int b = blockIdx.x;
    int t = threadIdx.x;
    for (int i = t; i < 1260; i += 256) mf[i] = mfw[b * 1260 + i];
    __syncthreads();
    if (t < 210) {
        float p0 = 0.f, p1 = 0.f, p2 = 0.f, d0 = 0.f, d1 = 0.f, d2 = 0.f;
        for (int c = 0; c < 420; ++c) {
            float m0 = mf[3 * c], m1 = mf[3 * c + 1], m2 = mf[3 * c + 2];
            float w = wv1f[t * 420 + c];
            p0 += w * m0; p1 += w * m1; p2 += w * m2;
            float w2 = wv1d[t * 420 + c];
            d0 += w2 * m0; d1 += w2 * m1; d2 += w2 * m2;
        }
        float dot = p0 * d0 + p1 * d1 + p2 * d2;
        float r0, r1, r2;
        if (dot >= 0.f) { r0 = p0; r1 = p1; r2 = p2; }
        else {
            float tq = dot / (d0 * d0 + d1 * d1 + d2 * d2 + 1e-6f);
            r0 = p0 - tq * d0; r1 = p1 - tq * d1; r2 = p2 - tq * d2;
        }
        z1[t * 3]     = 0.2f * p0 + 0.8f * r0;
        z1[t * 3 + 1] = 0.2f * p1 + 0.8f * r1;
        z1[t * 3 + 2] = 0.2f * p2 + 0.8f * r2;
    }
    __syncthreads();
    if (t < 84) {
        float p0 = 0.f, p1 = 0.f, p2 = 0.f, d0 = 0.f, d1 = 0.f, d2 = 0.f;
        for (int c = 0; c < 210; ++c) {
            float m0 = z1[3 * c], m1 = z1[3 * c + 1], m2 = z1[3 * c + 2];
            float w = wv2f[t * 210 + c];
            p0 += w * m0; p1 += w * m1; p2 += w * m2;
            float w2 = wv2d[t * 210 + c];
            d0 += w2 * m0; d1 += w2 * m1; d2 += w2 * m2;
        }
        float dot = p0 * d0 + p1 * d1 + p2 * d2;
        float r0, r1, r2;
        if (dot >= 0.f) { r0 = p0; r1 = p1; r2 = p2; }
        else {
            float tq = dot / (d0 * d0 + d1 * d1 + d2 * d2 + 1e-6f);
            r0 = p0 - tq * d0; r1 = p1 - tq * d1; r2 = p2 - tq * d2;
        }
        z2[t * 3]     = 0.2f * p0 + 0.8f * r0;
        z2[t * 3 + 1] = 0.2f * p1 + 0.8f * r1;
        z2[t * 3 + 2] = 0.2f * p2 + 0.8f * r2;
    }
    __syncthreads();
    if (t < 6) {
        int v = t / 2, kt = t % 2;
        float s = 0.f;
        for (int c = 0; c < 84; ++c) s += z2[c * 3 + v] * w3[kt * 84 + c];
        z3[v * 2 + kt] = s;
    }
    __syncthreads();
    for (int i = t; i < 840; i += 256) {
        int ii = i / 2, kt = i % 2;
        float s = mf[ii * 3] * z3[0 + kt] + mf[ii * 3 + 1] * z3[2 + kt] +
                  mf[ii * 3 + 2] * z3[4 + kt];
        invgl_ws[b * 840 + i] = s;
        out_invgl[b * 840 + i] = s;
    }
}

// ============================ invinT build (bf16, transposed) ============================
// invT[col][c], col = b*2048+n in [0,8192), c in [0,1280) (pad >=1267 -> 0)
__global__ void invinT_kernel(const float* __restrict__ normv,
                              const int* __restrict__ cat,
                              const float* __restrict__ mfw,
                              const float* __restrict__ invglw,
                              const float* __restrict__ coord,
                              unsigned short* __restrict__ invT)
{
#pragma clang fp contract(off)
    int t = threadIdx.x;
    int cc = blockIdx.y * 64 + (t & 63);
    int col = blockIdx.x * 4 + (t >> 6);
    int b = col >> 11, n = col & 2047;
    float val = 0.f;
    if (cc == 0) val = normv[b * NTOT + n];
    else if (cc < 841) val = invglw[b * 840 + (cc - 1)];
    else if (cc < 1261) {
        int i = cc - 841;
        val = mfw[b * 1260 + i * 3]     * coord[(b * 3 + 0) * NTOT + n]
            + mfw[b * 1260 + i * 3 + 1] * coord[(b * 3 + 1) * NTOT + n]
            + mfw[b * 1260 + i * 3 + 2] * coord[(b * 3 + 2) * NTOT + n];
    } else if (cc < 1267) val = (cat[b] == cc - 1261) ? 1.f : 0.f;
    invT[(size_t)col * 1280 + cc] = f2b(val);
}

// ============================ weight convert f32 -> bf16 (padded) ============================
__global__ void wconv_kernel(const float* __restrict__ src, unsigned short* __restrict__ dst,
                             int Msrc, int Ksrc, int Kpad)
{
    int k = blockIdx.x * 256 + threadIdx.x;
    int o = blockIdx.y;
    float v = (o < Msrc && k < Ksrc) ? src[(size_t)o * Ksrc + k] : 0.f;
    dst[(size_t)o * Kpad + k] = f2b(v);
}

// ============================ MFMA GEMM: Ct(8192 x M) = A(8192 x K) * W(M x K)^T ======
// A, W bf16 row-major (K contiguous, K % 32 == 0). C f32 row-major ld=Mreal.
__global__ __launch_bounds__(256)
void gemm_mfma_kernel(const unsigned short* __restrict__ A,
                      const unsigned short* __restrict__ Bw,
                      float* __restrict__ C, int K, int Mreal)
{
    __shared__ __align__(16) unsigned short Al[128 * 40];
    __shared__ __align__(16) unsigned short Bl[128 * 40];
    int t = threadIdx.x;
    int r0 = blockIdx.x * 128;
    int c0 = blockIdx.y * 128;
    int w = t >> 6, l = t & 63;
    int wm = w & 1, wn = w >> 1;
    int lm = l & 15, lq = l >> 4;
    f32x4 acc[4][4] = {};
    for (int k0 = 0; k0 < K; k0 += 32) {
        for (int half = 0; half < 2; ++half) {
            int ch = t + half * 256;
            int row = ch >> 2, kc = ch & 3;
            *(uint4*)&Al[row * 40 + kc * 8] =
                *(const uint4*)&A[(size_t)(r0 + row) * K + k0 + kc * 8];
            *(uint4*)&Bl[row * 40 + kc * 8] =
                *(const uint4*)&Bw[(size_t)(c0 + row) * K + k0 + kc * 8];
        }
        __syncthreads();
        bf16x8 af[4], bfr[4];
#pragma unroll
        for (int i = 0; i < 4; ++i)
            af[i] = *(const bf16x8*)&Al[(wm * 64 + i * 16 + lm) * 40 + lq * 8];
#pragma unroll
        for (int j = 0; j < 4; ++j)
            bfr[j] = *(const bf16x8*)&Bl[(wn * 64 + j * 16 + lm) * 40 + lq * 8];
#pragma unroll
        for (int i = 0; i < 4; ++i)
#pragma unroll
            for (int j = 0; j < 4; ++j)
                acc[i][j] = __builtin_amdgcn_mfma_f32_16x16x32_bf16(af[i], bfr[j],
                                                                    acc[i][j], 0, 0, 0);
        __syncthreads();
    }
#pragma unroll
    for (int i = 0; i < 4; ++i) {
#pragma unroll
        for (int j = 0; j < 4; ++j) {
            int col = c0 + wn * 64 + j * 16 + lm;
            if (col < Mreal) {
                int rbase = r0 + wm * 64 + i * 16 + lq * 4;
#pragma unroll
                for (int r = 0; r < 4; ++r)
                    C[(size_t)(rbase + r) * Mreal + col] = acc[i][j][r];
            }
        }
    }
}

// ============================ conv BN stats (transposed, atomic) ============================
__global__ void cstatsT_kernel(const float* __restrict__ Ct, float* __restrict__ st,
                               int Mreal)
{
    __shared__ float l1[256], l2[256];
    int t = threadIdx.x;
    int o = blockIdx.x * 64 + (t & 63);
    int r0 = blockIdx.y * 128 + (t >> 6) * 32;
    float s = 0.f, s2 = 0.f;
    if (o < Mreal) {
        for (int rr = 0; rr < 32; ++rr) {
            float v = Ct[(size_t)(r0 + rr) * Mreal + o];
            s += v; s2 += v * v;
        }
    }
    l1[t] = s; l2[t] = s2;
    __syncthreads();
    if (t < 64 && o < Mreal) {
        s  = l1[t] + l1[t + 64] + l1[t + 128] + l1[t + 192];
        s2 = l2[t] + l2[t + 64] + l2[t + 128] + l2[t + 192];
        atomicAdd(&st[o], s);
        atomicAdd(&st[Mreal + o], s2);
    }
}

// ============================ BN+ReLU -> bf16 (same layout, next GEMM's A) ======
__global__ void bnreluT_kernel(const float* __restrict__ Ct, const float* __restrict__ st,
                               const float* __restrict__ g, const float* __restrict__ be,
                               unsigned short* __restrict__ outb, int M, int maskM)
{
#pragma clang fp contract(off)
    size_t idx = (size_t)blockIdx.x * 256 + threadIdx.x;
    int o = (int)(idx & (size_t)maskM);
    float m = st[o] * (1.f / 8192.f);
    float var = st[M + o] * (1.f / 8192.f) - m * m;
    float sqv = sqrtf(var + 1e-5f);
    float v = g[o] * (Ct[idx] - m) / sqv + be[o];
    outb[idx] = f2b(v > 0.f ? v : 0.f);
}

// ============================ final BN+ReLU + transpose to output ============================
__global__ void bnrelu_outT_kernel(const float* __restrict__ Ct, const float* __restrict__ st,
                                   const float* __restrict__ g, const float* __restrict__ be,
                                   float* __restrict__ outinv)
{
#pragma clang fp contract(off)
    __shared__ float tile[64][65];
    int t = threadIdx.x;
    int r0 = blockIdx.x * 64;
    int o0 = blockIdx.y * 64;
    int b = r0 >> 11, n0 = r0 & 2047;
    int oi = t & 63;
    int o = o0 + oi;
    float m = 0.f, sqv = 1.f, gg = 0.f, bb = 0.f;
    if (o < 420) {
        m = st[o] * (1.f / 8192.f);
        float var = st[420 + o] * (1.f / 8192.f) - m * m;
        sqv = sqrtf(var + 1e-5f);
        gg = g[o]; bb = be[o];
    }
    for (int it = 0; it < 16; ++it) {
        int rr = it * 4 + (t >> 6);
        float v = 0.f;
        if (o < 420) {
            v = gg * (Ct[(size_t)(r0 + rr) * 420 + o] - m) / sqv + bb;
            v = v > 0.f ? v : 0.f;
        }
        tile[rr][oi] = v;
    }
    __syncthreads();
    for (int it = 0; it < 16; ++it) {
        int oc = it * 4 + (t >> 6);
        int oo = o0 + oc;
        if (oo < 420)
            outinv[((size_t)(b * 420 + oo)) * 2048 + n0 + (t & 63)] = tile[t & 63][oc];
    }
}

// ============================ launch ============================
extern "C" void kernel_launch(void* const* d_in, const int* in_sizes, int n_in,
                              void* d_out, int out_size, void* d_ws, size_t ws_size,
                              hipStream_t stream)
{
    (void)in_sizes; (void)n_in; (void)out_size; (void)ws_size;
    const float* xc   = (const float*)d_in[0];
    const float* normv= (const float*)d_in[1];
    const int*   cat  = (const int*)d_in[2];
    const float* wf0  = (const float*)d_in[3];
    const float* wd0  = (const float*)d_in[4];
    const float* g0   = (const float*)d_in[5];
    const float* b0   = (const float*)d_in[6];
    const float* wf1  = (const float*)d_in[7];
    const float* wd1  = (const float*)d_in[8];
    const float* g1   = (const float*)d_in[9];
    const float* b1   = (const float*)d_in[10];
    const float* wp1  = (const float*)d_in[11];
    const float* wf2  = (const float*)d_in[12];
    const float* wd2  = (const float*)d_in[13];
    const float* g2   = (const float*)d_in[14];
    const float* b2   = (const float*)d_in[15];
    const float* wf3  = (const float*)d_in[16];
    const float* wd3  = (const float*)d_in[17];
    const float* g3   = (const float*)d_in[18];
    const float* b3   = (const float*)d_in[19];
    const float* wp2  = (const float*)d_in[20];
    const float* wf4  = (const float*)d_in[21];
    const float* wd4  = (const float*)d_in[22];
    const float* g4   = (const float*)d_in[23];
    const float* b4   = (const float*)d_in[24];
    const float* wv1f = (const float*)d_in[25];
    const float* wv1d = (const float*)d_in[26];
    const float* wv2f = (const float*)d_in[27];
    const float* wv2d = (const float*)d_in[28];
    const float* w3   = (const float*)d_in[29];
    const float* ws1  = (const float*)d_in[30];
    const float* cb1  = (const float*)d_in[31]; (void)cb1;   // bias cancels in BN
    const float* sg1  = (const float*)d_in[32];
    const float* sb1  = (const float*)d_in[33];
    const float* ws2  = (const float*)d_in[34];
    const float* cb2  = (const float*)d_in[35]; (void)cb2;
    const float* sg2  = (const float*)d_in[36];
    const float* sb2  = (const float*)d_in[37];
    const float* ws3  = (const float*)d_in[38];
    const float* cb3  = (const float*)d_in[39]; (void)cb3;
    const float* sg3  = (const float*)d_in[40];
    const float* sb3  = (const float*)d_in[41];

    float* ws = (float*)d_ws;
    float* out = (float*)d_out;

    int*    idx20 = (int*)(ws + WS_IDX20);
    float*  fs    = ws + WS_FS;
    float*  x0    = ws + WS_X0;
    float*  x1    = ws + WS_X1;
    float*  xm2   = ws + WS_XM2;
    float*  x2    = ws + WS_X2;
    float*  x3    = ws + WS_X3;
    int*    idx42 = (int*)(ws + WS_IDX42);
    float*  xm4   = ws + WS_XM4;
    float*  x4    = ws + WS_X4;
    int*    i1p   = (int*)(ws + WS_I1);
    int*    i2p   = (int*)(ws + WS_I2);
    float*  mfw   = ws + WS_MF;
    float*  invgl = ws + WS_INVGL;
    double* st    = (double*)(ws + WS_STATS);
    float*  cst   = ws + WS_CST;
    unsigned short* invT = (unsigned short*)(ws + WS_INVT);
    unsigned short* w1b  = (unsigned short*)(ws + WS_W1B);
    unsigned short* w2b  = (unsigned short*)(ws + WS_W2B);
    unsigned short* w3b  = (unsigned short*)(ws + WS_W3B);
    float*  y1t   = ws + WS_Y1T;
    unsigned short* y1b  = (unsigned short*)(ws + WS_Y1B);
    float*  y2t   = ws + WS_Y2T;
    unsigned short* y2b  = (unsigned short*)(ws + WS_Y2B);
    float*  y3t   = ws + WS_Y3T;

    hipMemsetAsync((void*)st, 0, 840 * sizeof(double), stream);
    hipMemsetAsync((void*)cst, 0, 3912 * sizeof(float), stream);

    // weight conversions (independent; schedule early)
    wconv_kernel<<<dim3(5, 1024), 256, 0, stream>>>(ws1, w1b, 1024, 1267, 1280);
    wconv_kernel<<<dim3(4, 512), 256, 0, stream>>>(ws2, w2b, 512, 1024, 1024);
    wconv_kernel<<<dim3(2, 512), 256, 0, stream>>>(ws3, w3b, 420, 512, 512);

    // KNN-20 (also the knn-4 prefix for pool stage 1)
    knn64_kernel<20><<<dim3(2048, 4), 64, 0, stream>>>(xc, 2048, 1, 1, idx20, 2048);
    surf_build_kernel<<<640, 256, 0, stream>>>(xc, idx20, fs);

    // stage 0
    stats0_kernel<<<2048, 64, 0, stream>>>(fs, wf0, st + ST0_OFF);
    apply0_kernel<<<2048, 64, 0, stream>>>(fs, wf0, wd0, g0, b0, st + ST0_OFF, x0);

    // stage 1
    vn_stats_kernel<<<dim3(128, 4), 256, 0, stream>>>(x0, wf1, st + ST1_OFF, 42, 42, 2048);
    vn_apply_kernel<<<dim3(256, 4), 256, 0, stream>>>(x0, wf1, wd1, g1, b1, st + ST1_OFF,
                                                      8192.0, 42, 42, 2048, x1);

    // pool 1
    vn_pool_kernel<<<dim3(512, 4), 256, 0, stream>>>(x1, idx20, 40960LL, 80, wp1, xm2,
                                                     42, 2048, 512);
    // stage 2
    vn_stats_kernel<<<dim3(32, 4), 256, 0, stream>>>(xm2, wf2, st + ST2_OFF, 42, 84, 512);
    vn_apply_kernel<<<dim3(64, 4), 256, 0, stream>>>(xm2, wf2, wd2, g2, b2, st + ST2_OFF,
                                                     2048.0, 42, 84, 512, x2);
    // stage 3
    vn_stats_kernel<<<dim3(32, 4), 256, 0, stream>>>(x2, wf3, st + ST3_OFF, 84, 84, 512);
    vn_apply_kernel<<<dim3(64, 4), 256, 0, stream>>>(x2, wf3, wd3, g3, b3, st + ST3_OFF,
                                                     2048.0, 84, 84, 512, x3);

    // knn-4 on coord2
    knn64_kernel<4><<<dim3(128, 4), 64, 0, stream>>>(xc, 512, 4, 16, idx42, 128);
    vn_pool_kernel<<<dim3(128, 4), 256, 0, stream>>>(x3, idx42, 512LL, 4, wp2, xm4,
                                                     84, 512, 128);
    // stage 4
    vn_stats_kernel<<<dim3(8, 4), 256, 0, stream>>>(xm4, wf4, st + ST4_OFF, 84, 168, 128);
    vn_apply_kernel<<<dim3(16, 4), 256, 0, stream>>>(xm4, wf4, wd4, g4, b4, st + ST4_OFF,
                                                     512.0, 84, 168, 128, x4);

    // nearest-neighbor upsample indices
    nearest_kernel<<<dim3(2048, 4), 256, 0, stream>>>(xc, 512, 4, i1p);
    nearest_kernel<<<dim3(2048, 4), 256, 0, stream>>>(xc, 128, 16, i2p);

    // eqv (output 0), mean_feat (output 1)
    eqv_kernel<<<dim3(8, 1260, 4), 256, 0, stream>>>(x0, x1, x2, x3, x4, i1p, i2p,
                                                     out + OUT_EQV);
    meanfeat_kernel<<<dim3(1260, 4), 256, 0, stream>>>(out + OUT_EQV, out + OUT_MF, mfw);

    // z chain + inv_gl (output 3)
    z_kernel<<<4, 256, 0, stream>>>(mfw, wv1f, wv1d, wv2f, wv2d, w3, invgl,
                                    out + OUT_INVGL);

    // invariant branch (bf16 MFMA stack)
    invinT_kernel<<<dim3(2048, 20), 256, 0, stream>>>(normv, cat, mfw, invgl, xc, invT);

    gemm_mfma_kernel<<<dim3(64, 8), 256, 0, stream>>>(invT, w1b, y1t, 1280, 1024);
    cstatsT_kernel<<<dim3(16, 64), 256, 0, stream>>>(y1t, cst + CST1_OFF, 1024);
    bnreluT_kernel<<<32768, 256, 0, stream>>>(y1t, cst + CST1_OFF, sg1, sb1, y1b,
                                              1024, 1023);

    gemm_mfma_kernel<<<dim3(64, 4), 256, 0, stream>>>(y1b, w2b, y2t, 1024, 512);
    cstatsT_kernel<<<dim3(8, 64), 256, 0, stream>>>(y2t, cst + CST2_OFF, 512);
    bnreluT_kernel<<<16384, 256, 0, stream>>>(y2t, cst + CST2_OFF, sg2, sb2, y2b,
                                              512, 511);

    gemm_mfma_kernel<<<dim3(64, 4), 256, 0, stream>>>(y2b, w3b, y3t, 512, 420);
    cstatsT_kernel<<<dim3(7, 64), 256, 0, stream>>>(y3t, cst + CST3_OFF, 420);
    bnrelu_outT_kernel<<<dim3(128, 7), 256, 0, stream>>>(y3t, cst + CST3_OFF, sg3, sb3,
                                                         out + OUT_INV);
}

// Round 4
// 930.979 us; speedup vs baseline: 2.0467x; 1.4471x over previous
//
#include <hip/hip_runtime.h>
#include <hip/hip_bf16.h>
#include <cstdint>
#include <cstddef>

#define NTOT 2048
#define BTOT 4

typedef short bf16x8 __attribute__((ext_vector_type(8)));
typedef float f32x4 __attribute__((ext_vector_type(4)));

__device__ inline unsigned short f2b(float v) {
    __hip_bfloat16 h = __float2bfloat16(v);
    return *reinterpret_cast<unsigned short*>(&h);
}

// ---------------- workspace layout (float-element offsets) ----------------
static const size_t WS_IDX20 = 0;                       // int[163840]
static const size_t WS_FS    = 163840;                  // float[1474560]
static const size_t WS_X0    = 1638400;                 // float[2064384] (B,42,3,2048)
static const size_t WS_X1    = 3702784;                 // float[2064384]
static const size_t WS_XM2   = 5767168;                 // float[258048]
static const size_t WS_X2    = 6025216;                 // float[516096]
static const size_t WS_X3    = 6541312;                 // float[516096]
static const size_t WS_IDX42 = 7057408;                 // int[2048]
static const size_t WS_XM4   = 7059456;                 // float[129024]
static const size_t WS_X4    = 7188480;                 // float[258048]
static const size_t WS_I1    = 7446528;                 // int[8192]
static const size_t WS_I2    = 7454720;                 // int[8192]
static const size_t WS_MF    = 7462912;                 // float[5040]
static const size_t WS_INVGL = 7467952;                 // float[3360]
static const size_t WS_STATS = 7471312;                 // double[840] (1680 fl slots)
static const size_t WS_CST   = 7472992;                 // float[3912] conv bn sums
static const size_t WS_INVT  = 7480320;                 // ushort[8192*1280]
static const size_t WS_W1B   = 12723200;                // ushort[1024*1280]
static const size_t WS_W2B   = 13378560;                // ushort[512*1024]
static const size_t WS_W3B   = 13640704;                // ushort[512*512]
static const size_t WS_Y1T   = 13771776;                // float[8192*1024]
static const size_t WS_Y1B   = 0;                       // ushort overlay
static const size_t WS_Y2T   = WS_INVT;                 // float overlay
static const size_t WS_Y2B   = 4194304;                 // ushort overlay
static const size_t WS_Y3T   = WS_Y1T;                  // float overlay

#define ST0_OFF 0
#define ST1_OFF 84
#define ST2_OFF 168
#define ST3_OFF 336
#define ST4_OFF 504
#define CST1_OFF 0
#define CST2_OFF 2048
#define CST3_OFF 3072

#define OUT_EQV   0
#define OUT_MF    10321920
#define OUT_INV   10326960
#define OUT_INVGL 13767600

// ============================ KNN (register-resident, wave-per-query) ========
// pd[m] = (2*inner - xx_q) - xx_m ; top-K desc, ties -> lower m (numpy top_k).
// Slot j of lane holds candidate m = lane + 64*j. No LDS, no barriers.
template <int SLOTS, int K>
__global__ __launch_bounds__(256)
void knn_reg_kernel(const float* __restrict__ coord, int cand_stride, int q_stride,
                    int* __restrict__ out_idx, int q_cnt)
{
#pragma clang fp contract(off)
    int b = blockIdx.y;
    int wave = threadIdx.x >> 6, lane = threadIdx.x & 63;
    int q = blockIdx.x * 4 + wave;
    if (q >= q_cnt) return;
    int nq = q * q_stride;
    float qx = coord[(b * 3 + 0) * NTOT + nq];
    float qy = coord[(b * 3 + 1) * NTOT + nq];
    float qz = coord[(b * 3 + 2) * NTOT + nq];
    float xxq = qx * qx + qy * qy + qz * qz;
    float v[SLOTS];
#pragma unroll
    for (int j = 0; j < SLOTS; ++j) {
        int mo = (lane + 64 * j) * cand_stride;
        float cx = coord[(b * 3 + 0) * NTOT + mo];
        float cy = coord[(b * 3 + 1) * NTOT + mo];
        float cz = coord[(b * 3 + 2) * NTOT + mo];
        float inner = qx * cx + qy * cy + qz * cz;
        float xxc = cx * cx + cy * cy + cz * cz;
        v[j] = (2.0f * inner - xxq) - xxc;
    }
#pragma clang loop unroll(disable)
    for (int kk = 0; kk < K; ++kk) {
        // in-lane max tree; first level folds v directly (halves reg use)
        float tv[SLOTS > 1 ? SLOTS / 2 : 1];
        int   tj[SLOTS > 1 ? SLOTS / 2 : 1];
        if (SLOTS == 1) { tv[0] = v[0]; tj[0] = 0; }
        else {
#pragma unroll
            for (int j = 0; j < SLOTS / 2; ++j) {
                bool c = v[j + SLOTS / 2] > v[j];   // tie keeps lower j
                tv[j] = c ? v[j + SLOTS / 2] : v[j];
                tj[j] = c ? j + SLOTS / 2 : j;
            }
#pragma unroll
            for (int s = SLOTS / 4; s >= 1; s >>= 1) {
#pragma unroll
                for (int j = 0; j < s; ++j) {
                    if (tv[j + s] > tv[j] ||
                        (tv[j + s] == tv[j] && tj[j + s] < tj[j])) {
                        tv[j] = tv[j + s]; tj[j] = tj[j + s];
                    }
                }
            }
        }
        float bv = tv[0];
        int bm = lane + 64 * tj[0];
        for (int off = 32; off; off >>= 1) {
            float ov = __shfl_down(bv, off);
            int   om = __shfl_down(bm, off);
            if (ov > bv || (ov == bv && om < bm)) { bv = ov; bm = om; }
        }
        int m_win = __shfl(bm, 0);
        if (lane == 0)
            out_idx[((size_t)(b * q_cnt) + q) * K + kk] = m_win;
#pragma unroll
        for (int j = 0; j < SLOTS; ++j)
            if (m_win == lane + 64 * j) v[j] = -3.4e38f;
    }
}

// ============================ nearest (register argmin, wave-per-query) ======
// d = (tt - 2*inner) + ss ; argmin, ties -> lower m.
template <int SLOTS>
__global__ __launch_bounds__(256)
void nearest_reg_kernel(const float* __restrict__ coord, int cand_stride,
                        int* __restrict__ out)
{
#pragma clang fp contract(off)
    int b = blockIdx.y;
    int wave = threadIdx.x >> 6, lane = threadIdx.x & 63;
    int n = blockIdx.x * 4 + wave;
    float qx = coord[(b * 3 + 0) * NTOT + n];
    float qy = coord[(b * 3 + 1) * NTOT + n];
    float qz = coord[(b * 3 + 2) * NTOT + n];
    float tt = qx * qx + qy * qy + qz * qz;
    float v[SLOTS];
#pragma unroll
    for (int j = 0; j < SLOTS; ++j) {
        int mo = (lane + 64 * j) * cand_stride;
        float cx = coord[(b * 3 + 0) * NTOT + mo];
        float cy = coord[(b * 3 + 1) * NTOT + mo];
        float cz = coord[(b * 3 + 2) * NTOT + mo];
        float inner = qx * cx + qy * cy + qz * cz;
        float ss = cx * cx + cy * cy + cz * cz;
        v[j] = (tt - 2.0f * inner) + ss;
    }
    float bv = v[0];
    int bj = 0;
#pragma unroll
    for (int j = 1; j < SLOTS; ++j)
        if (v[j] < bv) { bv = v[j]; bj = j; }   // tie keeps lower j (scan order)
    int bm = lane + 64 * bj;
    for (int off = 32; off; off >>= 1) {
        float ov = __shfl_down(bv, off);
        int   om = __shfl_down(bm, off);
        if (ov < bv || (ov == bv && om < bm)) { bv = ov; bm = om; }
    }
    if (lane == 0) out[b * NTOT + n] = bm;
}

// ============================ surface feature build ============================
__global__ void surf_build_kernel(const float* __restrict__ coord,
                                  const int* __restrict__ idx20,
                                  float* __restrict__ fs)
{
#pragma clang fp contract(off)
    int t = blockIdx.x * 256 + threadIdx.x;
    if (t >= BTOT * NTOT * 20) return;
    int n = (t / 20) & (NTOT - 1);
    int b = t / (20 * NTOT);
    int m = idx20[t];
    float cx = coord[(b * 3 + 0) * NTOT + n];
    float cy = coord[(b * 3 + 1) * NTOT + n];
    float cz = coord[(b * 3 + 2) * NTOT + n];
    float nx = coord[(b * 3 + 0) * NTOT + m];
    float ny = coord[(b * 3 + 1) * NTOT + m];
    float nz = coord[(b * 3 + 2) * NTOT + m];
    float* f9 = fs + (size_t)t * 9;
    f9[0] = nx - cx; f9[1] = ny - cy; f9[2] = nz - cz;
    f9[3] = cx;      f9[4] = cy;      f9[5] = cz;
    f9[6] = ny * cz - nz * cy;
    f9[7] = nz * cx - nx * cz;
    f9[8] = nx * cy - ny * cx;
}

// ============================ stage-0 stats / apply (4 waves x 4 pts) ========
__global__ __launch_bounds__(256)
void stats0_kernel(const float* __restrict__ fs,
                   const float* __restrict__ wf0,
                   double* __restrict__ stats)
{
#pragma clang fp contract(off)
    __shared__ float fl[4][720];
    __shared__ double red[4][84];
    int wave = threadIdx.x >> 6, lane = threadIdx.x & 63;
    int b = blockIdx.y;
    int n0 = (blockIdx.x * 4 + wave) * 4;
    const float* src = fs + ((size_t)(b * NTOT + n0) * 20) * 9;
    for (int t = lane; t < 720; t += 64) fl[wave][t] = src[t];
    __syncthreads();
    int o = lane;
    if (o < 42) {
        float w0 = wf0[o * 3], w1 = wf0[o * 3 + 1], w2 = wf0[o * 3 + 2];
        double s = 0.0, s2 = 0.0;
        for (int i = 0; i < 80; ++i) {
            const float* f9 = &fl[wave][i * 9];
            float p0 = w0 * f9[0] + w1 * f9[3] + w2 * f9[6];
            float p1 = w0 * f9[1] + w1 * f9[4] + w2 * f9[7];
            float p2 = w0 * f9[2] + w1 * f9[5] + w2 * f9[8];
            float nrm = sqrtf(p0 * p0 + p1 * p1 + p2 * p2) + 1e-6f;
            s += (double)nrm; s2 += (double)nrm * (double)nrm;
        }
        red[wave][o] = s;
        red[wave][42 + o] = s2;
    }
    __syncthreads();
    int t = threadIdx.x;
    if (t < 84)
        atomicAdd(&stats[t], red[0][t] + red[1][t] + red[2][t] + red[3][t]);
}

__global__ __launch_bounds__(256)
void apply0_kernel(const float* __restrict__ fs,
                   const float* __restrict__ wf0,
                   const float* __restrict__ wd0,
                   const float* __restrict__ g0,
                   const float* __restrict__ b0,
                   const double* __restrict__ stats,
                   float* __restrict__ x0)
{
#pragma clang fp contract(off)
    __shared__ float fl[4][720];
    int wave = threadIdx.x >> 6, lane = threadIdx.x & 63;
    int b = blockIdx.y;
    int n0 = (blockIdx.x * 4 + wave) * 4;
    const float* src = fs + ((size_t)(b * NTOT + n0) * 20) * 9;
    for (int t = lane; t < 720; t += 64) fl[wave][t] = src[t];
    __syncthreads();
    int o = lane;
    if (o >= 42) return;
    double S1 = stats[o], S2 = stats[42 + o];
    double md = S1 / 163840.0;
    float m = (float)md;
    float var = (float)(S2 / 163840.0 - md * md);
    float sqv = sqrtf(var + 1e-5f);
    float gg = g0[o], bb = b0[o];
    float wa0 = wf0[o * 3], wa1 = wf0[o * 3 + 1], wa2 = wf0[o * 3 + 2];
    float wb0 = wd0[o * 3], wb1 = wd0[o * 3 + 1], wb2 = wd0[o * 3 + 2];
    for (int pp = 0; pp < 4; ++pp) {
        float r8[3][8];
        float tl[3][4];
        for (int k = 0; k < 20; ++k) {
            const float* f9 = &fl[wave][(pp * 20 + k) * 9];
            float p0 = wa0 * f9[0] + wa1 * f9[3] + wa2 * f9[6];
            float p1 = wa0 * f9[1] + wa1 * f9[4] + wa2 * f9[7];
            float p2 = wa0 * f9[2] + wa1 * f9[5] + wa2 * f9[8];
            float d0 = wb0 * f9[0] + wb1 * f9[3] + wb2 * f9[6];
            float d1 = wb0 * f9[1] + wb1 * f9[4] + wb2 * f9[7];
            float d2 = wb0 * f9[2] + wb1 * f9[5] + wb2 * f9[8];
            float nrm = sqrtf(p0 * p0 + p1 * p1 + p2 * p2) + 1e-6f;
            float nb = gg * (nrm - m) / sqv + bb;
            p0 = p0 / nrm * nb;
            p1 = p1 / nrm * nb;
            p2 = p2 / nrm * nb;
            float dot = p0 * d0 + p1 * d1 + p2 * d2;
            float r0, r1, r2;
            if (dot >= 0.f) { r0 = p0; r1 = p1; r2 = p2; }
            else {
                float tq = dot / (d0 * d0 + d1 * d1 + d2 * d2 + 1e-6f);
                r0 = p0 - tq * d0; r1 = p1 - tq * d1; r2 = p2 - tq * d2;
            }
            float o0 = 0.2f * p0 + 0.8f * r0;
            float o1 = 0.2f * p1 + 0.8f * r1;
            float o2 = 0.2f * p2 + 0.8f * r2;
            if (k < 8)       { r8[0][k] = o0;       r8[1][k] = o1;       r8[2][k] = o2; }
            else if (k < 16) { r8[0][k-8] += o0;    r8[1][k-8] += o1;    r8[2][k-8] += o2; }
            else             { tl[0][k-16] = o0;    tl[1][k-16] = o1;    tl[2][k-16] = o2; }
        }
        int n = n0 + pp;
        for (int v = 0; v < 3; ++v) {
            float res = ((r8[v][0] + r8[v][1]) + (r8[v][2] + r8[v][3])) +
                        ((r8[v][4] + r8[v][5]) + (r8[v][6] + r8[v][7]));
            res += tl[v][0]; res += tl[v][1]; res += tl[v][2]; res += tl[v][3];
            x0[((size_t)(b * 42 + o) * 3 + v) * NTOT + n] = res / 20.0f;
        }
    }
}

// ============================ generic VN stats (unchanged) ============================
__global__ void vn_stats_kernel(const float* __restrict__ xin,
                                const float* __restrict__ wf,
                                double* __restrict__ stats,
                                int Ci, int Co, int Npts)
{
#pragma clang fp contract(off)
    __shared__ float col[252];
    int b = blockIdx.y;
    int o = threadIdx.x;
    double s = 0.0, s2 = 0.0;
    for (int it = 0; it < 16; ++it) {
        int pt = blockIdx.x * 16 + it;
        __syncthreads();
        for (int t = threadIdx.x; t < Ci * 3; t += blockDim.x)
            col[t] = xin[(size_t)(b * 3 * Ci + t) * Npts + pt];
        __syncthreads();
        if (o < Co) {
            const float* wr = wf + o * Ci;
            float p0 = 0.f, p1 = 0.f, p2 = 0.f;
            for (int c = 0; c < Ci; ++c) {
                float w = wr[c];
                p0 += w * col[3 * c]; p1 += w * col[3 * c + 1]; p2 += w * col[3 * c + 2];
            }
            float nrm = sqrtf(p0 * p0 + p1 * p1 + p2 * p2) + 1e-6f;
            s += (double)nrm; s2 += (double)nrm * (double)nrm;
        }
    }
    if (o < Co) { atomicAdd(&stats[o], s); atomicAdd(&stats[Co + o], s2); }
}

// ============================ VN apply (OPAD thread mapping) ==================
// o = t & (OPAD-1), point-slot = t >> oshift; PTS = 256/OPAD points per iter.
__global__ __launch_bounds__(256)
void vn_apply_kernel(const float* __restrict__ xin,
                     const float* __restrict__ wf,
                     const float* __restrict__ wd,
                     const float* __restrict__ g,
                     const float* __restrict__ bbp,
                     const double* __restrict__ stats,
                     double count, int Ci, int Co, int Npts,
                     int oshift, int nit,
                     float* __restrict__ xout)
{
#pragma clang fp contract(off)
    __shared__ float col[520];
    int t = threadIdx.x;
    int b = blockIdx.y;
    int OPAD = 1 << oshift;
    int PTS = 256 >> oshift;
    int o = t & (OPAD - 1);
    int ps = t >> oshift;
    int Ci3 = Ci * 3;
    int stride = Ci3 + 1;
    float m = 0.f, sqv = 1.f, gg = 0.f, bb = 0.f;
    if (o < Co) {
        double S1 = stats[o], S2 = stats[Co + o];
        double md = S1 / count;
        m = (float)md;
        float var = (float)(S2 / count - md * md);
        sqv = sqrtf(var + 1e-5f);
        gg = g[o]; bb = bbp[o];
    }
    int pt0 = blockIdx.x * (PTS * nit);
    for (int it = 0; it < nit; ++it) {
        int ptbase = pt0 + it * PTS;
        __syncthreads();
        for (int i = t; i < PTS * Ci3; i += 256) {
            int pl = i / Ci3, off = i - pl * Ci3;
            col[pl * stride + off] =
                xin[(size_t)(b * 3 * Ci + off) * Npts + (ptbase + pl)];
        }
        __syncthreads();
        if (o < Co) {
            const float* cl = &col[ps * stride];
            const float* wr = wf + o * Ci;
            const float* wdr = wd + o * Ci;
            float p0 = 0.f, p1 = 0.f, p2 = 0.f, d0 = 0.f, d1 = 0.f, d2 = 0.f;
            for (int c = 0; c < Ci; ++c) {
                float c0 = cl[3 * c], c1 = cl[3 * c + 1], c2 = cl[3 * c + 2];
                float w = wr[c];
                p0 += w * c0; p1 += w * c1; p2 += w * c2;
                float w2 = wdr[c];
                d0 += w2 * c0; d1 += w2 * c1; d2 += w2 * c2;
            }
            float nrm = sqrtf(p0 * p0 + p1 * p1 + p2 * p2) + 1e-6f;
            float nb = gg * (nrm - m) / sqv + bb;
            p0 = p0 / nrm * nb;
            p1 = p1 / nrm * nb;
            p2 = p2 / nrm * nb;
            float dot = p0 * d0 + p1 * d1 + p2 * d2;
            float r0, r1, r2;
            if (dot >= 0.f) { r0 = p0; r1 = p1; r2 = p2; }
            else {
                float tq = dot / (d0 * d0 + d1 * d1 + d2 * d2 + 1e-6f);
                r0 = p0 - tq * d0; r1 = p1 - tq * d1; r2 = p2 - tq * d2;
            }
            int pt = ptbase + ps;
            xout[((size_t)(b * Co + o) * 3 + 0) * Npts + pt] = 0.2f * p0 + 0.8f * r0;
            xout[((size_t)(b * Co + o) * 3 + 1) * Npts + pt] = 0.2f * p1 + 0.8f * r1;
            xout[((size_t)(b * Co + o) * 3 + 2) * Npts + pt] = 0.2f * p2 + 0.8f * r2;
        }
    }
}

// ============================ VN max-pool-down ============================
__global__ void vn_pool_kernel(const float* __restrict__ xin,
                               const int* __restrict__ idx, long long sb, int sq,
                               const float* __restrict__ wp,
                               float* __restrict__ xout,
                               int C, int Np, int Nq)
{
#pragma clang fp contract(off)
    __shared__ float nb[4 * 84 * 3];
    int b = blockIdx.y;
    int q = blockIdx.x;
    const int* ir = idx + b * sb + (long long)q * sq;
    for (int kk = 0; kk < 4; ++kk) {
        int mm = ir[kk];
        for (int t = threadIdx.x; t < C * 3; t += blockDim.x)
            nb[kk * C * 3 + t] = xin[(size_t)(b * 3 * C + t) * Np + mm];
    }
    __syncthreads();
    int o = threadIdx.x;
    if (o >= C) return;
    const float* wr = wp + o * C;
    float best = -3.4e38f;
    int bk = 0;
    for (int kk = 0; kk < 4; ++kk) {
        const float* cl = &nb[kk * C * 3];
        float d0 = 0.f, d1 = 0.f, d2 = 0.f;
        for (int c = 0; c < C; ++c) {
            float w = wr[c];
            d0 += w * cl[3 * c]; d1 += w * cl[3 * c + 1]; d2 += w * cl[3 * c + 2];
        }
        float dot = cl[o * 3] * d0 + cl[o * 3 + 1] * d1 + cl[o * 3 + 2] * d2;
        if (dot > best) { best = dot; bk = kk; }
    }
    const float* cb = &nb[bk * C * 3];
    xout[((size_t)(b * C + o) * 3 + 0) * Nq + q] = cb[o * 3];
    xout[((size_t)(b * C + o) * 3 + 1) * Nq + q] = cb[o * 3 + 1];
    xout[((size_t)(b * C + o) * 3 + 2) * Nq + q] = cb[o * 3 + 2];
}

// ============================ eqv assembly ============================
__global__ void eqv_kernel(const float* __restrict__ x0, const float* __restrict__ x1,
                           const float* __restrict__ x2, const float* __restrict__ x3,
                           const float* __restrict__ x4,
                           const int* __restrict__ i1, const int* __restrict__ i2,
                           float* __restrict__ out_eqv)
{
    int n = blockIdx.x * 256 + threadIdx.x;
    int cv = blockIdx.y;
    int b = blockIdx.z;
    int cc = cv / 3, v = cv % 3;
    float val;
    if (cc < 42)
        val = x0[((size_t)(b * 42 + cc) * 3 + v) * NTOT + n];
    else if (cc < 84)
        val = x1[((size_t)(b * 42 + (cc - 42)) * 3 + v) * NTOT + n];
    else if (cc < 168) {
        int m = i1[b * NTOT + n];
        val = x2[((size_t)(b * 84 + (cc - 84)) * 3 + v) * 512 + m];
    } else if (cc < 252) {
        int m = i1[b * NTOT + n];
        val = x3[((size_t)(b * 84 + (cc - 168)) * 3 + v) * 512 + m];
    } else {
        int m = i2[b * NTOT + n];
        val = x4[((size_t)(b * 168 + (cc - 252)) * 3 + v) * 128 + m];
    }
    out_eqv[((size_t)(b * 1260 + cv)) * NTOT + n] = val;
}

// ============================ mean_feat ============================
__global__ void meanfeat_kernel(const float* __restrict__ eqv,
                                float* __restrict__ out_mf,
                                float* __restrict__ ws_mf)
{
    __shared__ float r1[256];
    int cv = blockIdx.x, b = blockIdx.y;
    const float* row = eqv + ((size_t)(b * 1260 + cv)) * NTOT;
    float s = 0.f;
    for (int n = threadIdx.x; n < NTOT; n += 256) s += row[n];
    r1[threadIdx.x] = s;
    __syncthreads();
    for (int off = 128; off; off >>= 1) {
        if ((int)threadIdx.x < off) r1[threadIdx.x] += r1[threadIdx.x + off];
        __syncthreads();
    }
    if (threadIdx.x == 0) {
        float m = r1[0] / 2048.0f;
        out_mf[b * 1260 + cv] = m;
        ws_mf[b * 1260 + cv] = m;
    }
}

// ============================ z-chain + inv_gl ============================
__global__ void z_kernel(const float* __restrict__ mfw,
                         const float* __restrict__ wv1f, const float* __restrict__ wv1d,
                         const float* __restrict__ wv2f, const float* __restrict__ wv2d,
                         const float* __restrict__ w3,
                         float* __restrict__ invgl_ws, float* __restrict__ out_invgl)
{
#pragma clang fp contract(off)
    __shared__ float mf[1260];
    __shared__ float z1[630];
    __shared__ float z2[252];
    __shared__ float z3[6];
    int b = blockIdx.x;
    int t = threadIdx.x;
    for (int i = t; i < 1260; i += 256) mf[i] = mfw[b * 1260 + i];
    __syncthreads();
    if (t < 210) {
        float p0 = 0.f, p1 = 0.f, p2 = 0.f, d0 = 0.f, d1 = 0.f, d2 = 0.f;
        for (int c = 0; c < 420; ++c) {
            float m0 = mf[3 * c], m1 = mf[3 * c + 1], m2 = mf[3 * c + 2];
            float w = wv1f[t * 420 + c];
            p0 += w * m0; p1 += w * m1; p2 += w * m2;
            float w2 = wv1d[t * 420 + c];
            d0 += w2 * m0; d1 += w2 * m1; d2 += w2 * m2;
        }
        float dot = p0 * d0 + p1 * d1 + p2 * d2;
        float r0, r1, r2;
        if (dot >= 0.f) { r0 = p0; r1 = p1; r2 = p2; }
        else {
            float tq = dot / (d0 * d0 + d1 * d1 + d2 * d2 + 1e-6f);
            r0 = p0 - tq * d0; r1 = p1 - tq * d1; r2 = p2 - tq * d2;
        }
        z1[t * 3]     = 0.2f * p0 + 0.8f * r0;
        z1[t * 3 + 1] = 0.2f * p1 + 0.8f * r1;
        z1[t * 3 + 2] = 0.2f * p2 + 0.8f * r2;
    }
    __syncthreads();
    if (t < 84) {
        float p0 = 0.f, p1 = 0.f, p2 = 0.f, d0 = 0.f, d1 = 0.f, d2 = 0.f;
        for (int c = 0; c < 210; ++c) {
            float m0 = z1[3 * c], m1 = z1[3 * c + 1], m2 = z1[3 * c + 2];
            float w = wv2f[t * 210 + c];
            p0 += w * m0; p1 += w * m1; p2 += w * m2;
            float w2 = wv2d[t * 210 + c];
            d0 += w2 * m0; d1 += w2 * m1; d2 += w2 * m2;
        }
        float dot = p0 * d0 + p1 * d1 + p2 * d2;
        float r0, r1, r2;
        if (dot >= 0.f) { r0 = p0; r1 = p1; r2 = p2; }
        else {
            float tq = dot / (d0 * d0 + d1 * d1 + d2 * d2 + 1e-6f);
            r0 = p0 - tq * d0; r1 = p1 - tq * d1; r2 = p2 - tq * d2;
        }
        z2[t * 3]     = 0.2f * p0 + 0.8f * r0;
        z2[t * 3 + 1] = 0.2f * p1 + 0.8f * r1;
        z2[t * 3 + 2] = 0.2f * p2 + 0.8f * r2;
    }
    __syncthreads();
    if (t < 6) {
        int v = t / 2, kt = t % 2;
        float s = 0.f;
        for (int c = 0; c < 84; ++c) s += z2[c * 3 + v] * w3[kt * 84 + c];
        z3[v * 2 + kt] = s;
    }
    __syncthreads();
    for (int i = t; i < 840; i += 256) {
        int ii = i / 2, kt = i % 2;
        float s = mf[ii * 3] * z3[0 + kt] + mf[ii * 3 + 1] * z3[2 + kt] +
                  mf[ii * 3 + 2] * z3[4 + kt];
        invgl_ws[b * 840 + i] = s;
        out_invgl[b * 840 + i] = s;
    }
}

// ============================ invinT build (bf16, transposed) ============================
__global__ void invinT_kernel(const float* __restrict__ normv,
                              const int* __restrict__ cat,
                              const float* __restrict__ mfw,
                              const float* __restrict__ invglw,
                              const float* __restrict__ coord,
                              unsigned short* __restrict__ invT)
{
#pragma clang fp contract(off)
    int t = threadIdx.x;
    int cc = blockIdx.y * 64 + (t & 63);
    int col = blockIdx.x * 4 + (t >> 6);
    int b = col >> 11, n = col & 2047;
    float val = 0.f;
    if (cc == 0) val = normv[b * NTOT + n];
    else if (cc < 841) val = invglw[b * 840 + (cc - 1)];
    else if (cc < 1261) {
        int i = cc - 841;
        val = mfw[b * 1260 + i * 3]     * coord[(b * 3 + 0) * NTOT + n]
            + mfw[b * 1260 + i * 3 + 1] * coord[(b * 3 + 1) * NTOT + n]
            + mfw[b * 1260 + i * 3 + 2] * coord[(b * 3 + 2) * NTOT + n];
    } else if (cc < 1267) val = (cat[b] == cc - 1261) ? 1.f : 0.f;
    invT[(size_t)col * 1280 + cc] = f2b(val);
}

// ============================ weight convert f32 -> bf16 (padded) ============================
__global__ void wconv_kernel(const float* __restrict__ src, unsigned short* __restrict__ dst,
                             int Msrc, int Ksrc, int Kpad)
{
    int k = blockIdx.x * 256 + threadIdx.x;
    int o = blockIdx.y;
    float v = (o < Msrc && k < Ksrc) ? src[(size_t)o * Ksrc + k] : 0.f;
    dst[(size_t)o * Kpad + k] = f2b(v);
}

// ============================ MFMA GEMM ============================
__global__ __launch_bounds__(256)
void gemm_mfma_kernel(const unsigned short* __restrict__ A,
                      const unsigned short* __restrict__ Bw,
                      float* __restrict__ C, int K, int Mreal)
{
    __shared__ __align__(16) unsigned short Al[128 * 40];
    __shared__ __align__(16) unsigned short Bl[128 * 40];
    int t = threadIdx.x;
    int r0 = blockIdx.x * 128;
    int c0 = blockIdx.y * 128;
    int w = t >> 6, l = t & 63;
    int wm = w & 1, wn = w >> 1;
    int lm = l & 15, lq = l >> 4;
    f32x4 acc[4][4] = {};
    for (int k0 = 0; k0 < K; k0 += 32) {
        for (int half = 0; half < 2; ++half) {
            int ch = t + half * 256;
            int row = ch >> 2, kc = ch & 3;
            *(uint4*)&Al[row * 40 + kc * 8] =
                *(const uint4*)&A[(size_t)(r0 + row) * K + k0 + kc * 8];
            *(uint4*)&Bl[row * 40 + kc * 8] =
                *(const uint4*)&Bw[(size_t)(c0 + row) * K + k0 + kc * 8];
        }
        __syncthreads();
        bf16x8 af[4], bfr[4];
#pragma unroll
        for (int i = 0; i < 4; ++i)
            af[i] = *(const bf16x8*)&Al[(wm * 64 + i * 16 + lm) * 40 + lq * 8];
#pragma unroll
        for (int j = 0; j < 4; ++j)
            bfr[j] = *(const bf16x8*)&Bl[(wn * 64 + j * 16 + lm) * 40 + lq * 8];
#pragma unroll
        for (int i = 0; i < 4; ++i)
#pragma unroll
            for (int j = 0; j < 4; ++j)
                acc[i][j] = __builtin_amdgcn_mfma_f32_16x16x32_bf16(af[i], bfr[j],
                                                                    acc[i][j], 0, 0, 0);
        __syncthreads();
    }
#pragma unroll
    for (int i = 0; i < 4; ++i) {
#pragma unroll
        for (int j = 0; j < 4; ++j) {
            int col = c0 + wn * 64 + j * 16 + lm;
            if (col < Mreal) {
                int rbase = r0 + wm * 64 + i * 16 + lq * 4;
#pragma unroll
                for (int r = 0; r < 4; ++r)
                    C[(size_t)(rbase + r) * Mreal + col] = acc[i][j][r];
            }
        }
    }
}

// ============================ conv BN stats ============================
__global__ void cstatsT_kernel(const float* __restrict__ Ct, float* __restrict__ st,
                               int Mreal)
{
    __shared__ float l1[256], l2[256];
    int t = threadIdx.x;
    int o = blockIdx.x * 64 + (t & 63);
    int r0 = blockIdx.y * 128 + (t >> 6) * 32;
    float s = 0.f, s2 = 0.f;
    if (o < Mreal) {
        for (int rr = 0; rr < 32; ++rr) {
            float v = Ct[(size_t)(r0 + rr) * Mreal + o];
            s += v; s2 += v * v;
        }
    }
    l1[t] = s; l2[t] = s2;
    __syncthreads();
    if (t < 64 && o < Mreal) {
        s  = l1[t] + l1[t + 64] + l1[t + 128] + l1[t + 192];
        s2 = l2[t] + l2[t + 64] + l2[t + 128] + l2[t + 192];
        atomicAdd(&st[o], s);
        atomicAdd(&st[Mreal + o], s2);
    }
}

// ============================ BN+ReLU -> bf16 ============================
__global__ void bnreluT_kernel(const float* __restrict__ Ct, const float* __restrict__ st,
                               const float* __restrict__ g, const float* __restrict__ be,
                               unsigned short* __restrict__ outb, int M, int maskM)
{
#pragma clang fp contract(off)
    size_t idx = (size_t)blockIdx.x * 256 + threadIdx.x;
    int o = (int)(idx & (size_t)maskM);
    float m = st[o] * (1.f / 8192.f);
    float var = st[M + o] * (1.f / 8192.f) - m * m;
    float sqv = sqrtf(var + 1e-5f);
    float v = g[o] * (Ct[idx] - m) / sqv + be[o];
    outb[idx] = f2b(v > 0.f ? v : 0.f);
}

// ============================ final BN+ReLU + transpose ============================
__global__ void bnrelu_outT_kernel(const float* __restrict__ Ct, const float* __restrict__ st,
                                   const float* __restrict__ g, const float* __restrict__ be,
                                   float* __restrict__ outinv)
{
#pragma clang fp contract(off)
    __shared__ float tile[64][65];
    int t = threadIdx.x;
    int r0 = blockIdx.x * 64;
    int o0 = blockIdx.y * 64;
    int b = r0 >> 11, n0 = r0 & 2047;
    int oi = t & 63;
    int o = o0 + oi;
    float m = 0.f, sqv = 1.f, gg = 0.f, bb = 0.f;
    if (o < 420) {
        m = st[o] * (1.f / 8192.f);
        float var = st[420 + o] * (1.f / 8192.f) - m * m;
        sqv = sqrtf(var + 1e-5f);
        gg = g[o]; bb = be[o];
    }
    for (int it = 0; it < 16; ++it) {
        int rr = it * 4 + (t >> 6);
        float v = 0.f;
        if (o < 420) {
            v = gg * (Ct[(size_t)(r0 + rr) * 420 + o] - m) / sqv + bb;
            v = v > 0.f ? v : 0.f;
        }
        tile[rr][oi] = v;
    }
    __syncthreads();
    for (int it = 0; it < 16; ++it) {
        int oc = it * 4 + (t >> 6);
        int oo = o0 + oc;
        if (oo < 420)
            outinv[((size_t)(b * 420 + oo)) * 2048 + n0 + (t & 63)] = tile[t & 63][oc];
    }
}

// ============================ launch ============================
extern "C" void kernel_launch(void* const* d_in, const int* in_sizes, int n_in,
                              void* d_out, int out_size, void* d_ws, size_t ws_size,
                              hipStream_t stream)
{
    (void)in_sizes; (void)n_in; (void)out_size; (void)ws_size;
    const float* xc   = (const float*)d_in[0];
    const float* normv= (const float*)d_in[1];
    const int*   cat  = (const int*)d_in[2];
    const float* wf0  = (const float*)d_in[3];
    const float* wd0  = (const float*)d_in[4];
    const float* g0   = (const float*)d_in[5];
    const float* b0   = (const float*)d_in[6];
    const float* wf1  = (const float*)d_in[7];
    const float* wd1  = (const float*)d_in[8];
    const float* g1   = (const float*)d_in[9];
    const float* b1   = (const float*)d_in[10];
    const float* wp1  = (const float*)d_in[11];
    const float* wf2  = (const float*)d_in[12];
    const float* wd2  = (const float*)d_in[13];
    const float* g2   = (const float*)d_in[14];
    const float* b2   = (const float*)d_in[15];
    const float* wf3  = (const float*)d_in[16];
    const float* wd3  = (const float*)d_in[17];
    const float* g3   = (const float*)d_in[18];
    const float* b3   = (const float*)d_in[19];
    const float* wp2  = (const float*)d_in[20];
    const float* wf4  = (const float*)d_in[21];
    const float* wd4  = (const float*)d_in[22];
    const float* g4   = (const float*)d_in[23];
    const float* b4   = (const float*)d_in[24];
    const float* wv1f = (const float*)d_in[25];
    const float* wv1d = (const float*)d_in[26];
    const float* wv2f = (const float*)d_in[27];
    const float* wv2d = (const float*)d_in[28];
    const float* w3   = (const float*)d_in[29];
    const float* ws1  = (const float*)d_in[30];
    const float* sg1  = (const float*)d_in[32];
    const float* sb1  = (const float*)d_in[33];
    const float* ws2  = (const float*)d_in[34];
    const float* sg2  = (const float*)d_in[36];
    const float* sb2  = (const float*)d_in[37];
    const float* ws3  = (const float*)d_in[38];
    const float* sg3  = (const float*)d_in[40];
    const float* sb3  = (const float*)d_in[41];

    float* ws = (float*)d_ws;
    float* out = (float*)d_out;

    int*    idx20 = (int*)(ws + WS_IDX20);
    float*  fs    = ws + WS_FS;
    float*  x0    = ws + WS_X0;
    float*  x1    = ws + WS_X1;
    float*  xm2   = ws + WS_XM2;
    float*  x2    = ws + WS_X2;
    float*  x3    = ws + WS_X3;
    int*    idx42 = (int*)(ws + WS_IDX42);
    float*  xm4   = ws + WS_XM4;
    float*  x4    = ws + WS_X4;
    int*    i1p   = (int*)(ws + WS_I1);
    int*    i2p   = (int*)(ws + WS_I2);
    float*  mfw   = ws + WS_MF;
    float*  invgl = ws + WS_INVGL;
    double* st    = (double*)(ws + WS_STATS);
    float*  cst   = ws + WS_CST;
    unsigned short* invT = (unsigned short*)(ws + WS_INVT);
    unsigned short* w1b  = (unsigned short*)(ws + WS_W1B);
    unsigned short* w2b  = (unsigned short*)(ws + WS_W2B);
    unsigned short* w3b  = (unsigned short*)(ws + WS_W3B);
    float*  y1t   = ws + WS_Y1T;
    unsigned short* y1b  = (unsigned short*)(ws + WS_Y1B);
    float*  y2t   = ws + WS_Y2T;
    unsigned short* y2b  = (unsigned short*)(ws + WS_Y2B);
    float*  y3t   = ws + WS_Y3T;

    hipMemsetAsync((void*)st, 0, 840 * sizeof(double), stream);
    hipMemsetAsync((void*)cst, 0, 3912 * sizeof(float), stream);

    // weight conversions (independent)
    wconv_kernel<<<dim3(5, 1024), 256, 0, stream>>>(ws1, w1b, 1024, 1267, 1280);
    wconv_kernel<<<dim3(4, 512), 256, 0, stream>>>(ws2, w2b, 512, 1024, 1024);
    wconv_kernel<<<dim3(2, 512), 256, 0, stream>>>(ws3, w3b, 420, 512, 512);

    // KNN-20 (register-resident; also the knn-4 prefix for pool stage 1)
    knn_reg_kernel<32, 20><<<dim3(512, 4), 256, 0, stream>>>(xc, 1, 1, idx20, 2048);
    surf_build_kernel<<<640, 256, 0, stream>>>(xc, idx20, fs);

    // stage 0
    stats0_kernel<<<dim3(128, 4), 256, 0, stream>>>(fs, wf0, st + ST0_OFF);
    apply0_kernel<<<dim3(128, 4), 256, 0, stream>>>(fs, wf0, wd0, g0, b0,
                                                    st + ST0_OFF, x0);

    // stage 1
    vn_stats_kernel<<<dim3(128, 4), 256, 0, stream>>>(x0, wf1, st + ST1_OFF, 42, 42, 2048);
    vn_apply_kernel<<<dim3(256, 4), 256, 0, stream>>>(x0, wf1, wd1, g1, b1, st + ST1_OFF,
                                                      8192.0, 42, 42, 2048, 6, 2, x1);

    // pool 1
    vn_pool_kernel<<<dim3(512, 4), 256, 0, stream>>>(x1, idx20, 40960LL, 80, wp1, xm2,
                                                     42, 2048, 512);
    // stage 2
    vn_stats_kernel<<<dim3(32, 4), 256, 0, stream>>>(xm2, wf2, st + ST2_OFF, 42, 84, 512);
    vn_apply_kernel<<<dim3(128, 4), 256, 0, stream>>>(xm2, wf2, wd2, g2, b2, st + ST2_OFF,
                                                      2048.0, 42, 84, 512, 7, 2, x2);
    // stage 3
    vn_stats_kernel<<<dim3(32, 4), 256, 0, stream>>>(x2, wf3, st + ST3_OFF, 84, 84, 512);
    vn_apply_kernel<<<dim3(128, 4), 256, 0, stream>>>(x2, wf3, wd3, g3, b3, st + ST3_OFF,
                                                      2048.0, 84, 84, 512, 7, 2, x3);

    // knn-4 on coord2 (cands stride 4, queries stride 16)
    knn_reg_kernel<8, 4><<<dim3(32, 4), 256, 0, stream>>>(xc, 4, 16, idx42, 128);
    vn_pool_kernel<<<dim3(128, 4), 256, 0, stream>>>(x3, idx42, 512LL, 4, wp2, xm4,
                                                     84, 512, 128);
    // stage 4
    vn_stats_kernel<<<dim3(8, 4), 256, 0, stream>>>(xm4, wf4, st + ST4_OFF, 84, 168, 128);
    vn_apply_kernel<<<dim3(64, 4), 256, 0, stream>>>(xm4, wf4, wd4, g4, b4, st + ST4_OFF,
                                                     512.0, 84, 168, 128, 8, 2, x4);

    // nearest-neighbor upsample indices (register argmin, wave-per-query)
    nearest_reg_kernel<8><<<dim3(512, 4), 256, 0, stream>>>(xc, 4, i1p);
    nearest_reg_kernel<2><<<dim3(512, 4), 256, 0, stream>>>(xc, 16, i2p);

    // eqv (output 0), mean_feat (output 1)
    eqv_kernel<<<dim3(8, 1260, 4), 256, 0, stream>>>(x0, x1, x2, x3, x4, i1p, i2p,
                                                     out + OUT_EQV);
    meanfeat_kernel<<<dim3(1260, 4), 256, 0, stream>>>(out + OUT_EQV, out + OUT_MF, mfw);

    // z chain + inv_gl (output 3)
    z_kernel<<<4, 256, 0, stream>>>(mfw, wv1f, wv1d, wv2f, wv2d, w3, invgl,
                                    out + OUT_INVGL);

    // invariant branch (bf16 MFMA stack)
    invinT_kernel<<<dim3(2048, 20), 256, 0, stream>>>(normv, cat, mfw, invgl, xc, invT);

    gemm_mfma_kernel<<<dim3(64, 8), 256, 0, stream>>>(invT, w1b, y1t, 1280, 1024);
    cstatsT_kernel<<<dim3(16, 64), 256, 0, stream>>>(y1t, cst + CST1_OFF, 1024);
    bnreluT_kernel<<<32768, 256, 0, stream>>>(y1t, cst + CST1_OFF, sg1, sb1, y1b,
                                              1024, 1023);

    gemm_mfma_kernel<<<dim3(64, 4), 256, 0, stream>>>(y1b, w2b, y2t, 1024, 512);
    cstatsT_kernel<<<dim3(8, 64), 256, 0, stream>>>(y2t, cst + CST2_OFF, 512);
    bnreluT_kernel<<<16384, 256, 0, stream>>>(y2t, cst + CST2_OFF, sg2, sb2, y2b,
                                              512, 511);

    gemm_mfma_kernel<<<dim3(64, 4), 256, 0, stream>>>(y2b, w3b, y3t, 512, 420);
    cstatsT_kernel<<<dim3(7, 64), 256, 0, stream>>>(y3t, cst + CST3_OFF, 420);
    bnrelu_outT_kernel<<<dim3(128, 7), 256, 0, stream>>>(y3t, cst + CST3_OFF, sg3, sb3,
                                                         out + OUT_INV);
}

// Round 5
// 892.743 us; speedup vs baseline: 2.1344x; 1.0428x over previous
//
#include <hip/hip_runtime.h>
#include <hip/hip_bf16.h>
#include <cstdint>
#include <cstddef>

#define NTOT 2048
#define BTOT 4

typedef short bf16x8 __attribute__((ext_vector_type(8)));
typedef float f32x4 __attribute__((ext_vector_type(4)));

__device__ inline unsigned short f2b(float v) {
    __hip_bfloat16 h = __float2bfloat16(v);
    return *reinterpret_cast<unsigned short*>(&h);
}

// ---------------- workspace layout (float-element offsets) ----------------
static const size_t WS_IDX20 = 0;                       // int[163840]
static const size_t WS_FS    = 163840;                  // float[1474560]
static const size_t WS_X0    = 1638400;                 // float[2064384] (B,42,3,2048)
static const size_t WS_X1    = 3702784;                 // float[2064384]
static const size_t WS_XM2   = 5767168;                 // float[258048]
static const size_t WS_X2    = 6025216;                 // float[516096]
static const size_t WS_X3    = 6541312;                 // float[516096]
static const size_t WS_IDX42 = 7057408;                 // int[2048]
static const size_t WS_XM4   = 7059456;                 // float[129024]
static const size_t WS_X4    = 7188480;                 // float[258048]
static const size_t WS_I1    = 7446528;                 // int[8192]
static const size_t WS_I2    = 7454720;                 // int[8192]
static const size_t WS_MF    = 7462912;                 // float[5040]
static const size_t WS_INVGL = 7467952;                 // float[3360]
static const size_t WS_STATS = 7471312;                 // double[840] (1680 fl slots)
static const size_t WS_CST   = 7472992;                 // float[3912] conv bn sums
// conv1 factored coefficients (in old invT region; dead before y2t overlay use)
static const size_t WS_CB    = 7480320;                 // float[4096]   cb[b][o]
static const size_t WS_AB    = 7484416;                 // float[12288]  ab[b][o][3]
static const size_t WS_W0    = 7496704;                 // float[1024]   ws1[:,0]
static const size_t WS_W2B   = 13378560;                // ushort[512*1024]
static const size_t WS_W3B   = 13640704;                // ushort[512*512]
static const size_t WS_Y1T   = 13771776;                // float[8192*1024]
static const size_t WS_Y1B   = 0;                       // ushort overlay
static const size_t WS_Y2T   = 7480320;                 // float overlay (CB/AB dead)
static const size_t WS_Y2B   = 4194304;                 // ushort overlay
static const size_t WS_Y3T   = WS_Y1T;                  // float overlay

#define ST0_OFF 0
#define ST1_OFF 84
#define ST2_OFF 168
#define ST3_OFF 336
#define ST4_OFF 504
#define CST1_OFF 0
#define CST2_OFF 2048
#define CST3_OFF 3072

#define OUT_EQV   0
#define OUT_MF    10321920
#define OUT_INV   10326960
#define OUT_INVGL 13767600

// ============================ KNN v3 (cached quarter maxima) ==================
// pd[m] = (2*inner - xx_q) - xx_m ; top-K desc, ties -> lower m (numpy top_k).
// Lane slot j holds m = lane + 64*j. Per-lane quarters of 8 slots keep cached
// (max, argmax); per round only the winner's quarter (wave-uniform) rescans.
// Linear strict-> scans give exact tie->lower-m semantics.
template <int SLOTS, int K>
__global__ __launch_bounds__(256)
void knn_reg_kernel(const float* __restrict__ coord, int cand_stride, int q_stride,
                    int* __restrict__ out_idx, int q_cnt)
{
#pragma clang fp contract(off)
    constexpr int Q = SLOTS / 8;
    int b = blockIdx.y;
    int wave = threadIdx.x >> 6, lane = threadIdx.x & 63;
    int q = blockIdx.x * 4 + wave;
    if (q >= q_cnt) return;
    int nq = q * q_stride;
    float qx = coord[(b * 3 + 0) * NTOT + nq];
    float qy = coord[(b * 3 + 1) * NTOT + nq];
    float qz = coord[(b * 3 + 2) * NTOT + nq];
    float xxq = qx * qx + qy * qy + qz * qz;
    float v[SLOTS];
#pragma unroll
    for (int j = 0; j < SLOTS; ++j) {
        int mo = (lane + 64 * j) * cand_stride;
        float cx = coord[(b * 3 + 0) * NTOT + mo];
        float cy = coord[(b * 3 + 1) * NTOT + mo];
        float cz = coord[(b * 3 + 2) * NTOT + mo];
        float inner = qx * cx + qy * cy + qz * cz;
        float xxc = cx * cx + cy * cy + cz * cz;
        v[j] = (2.0f * inner - xxq) - xxc;
    }
    float qv[Q]; int qj[Q];
#pragma unroll
    for (int qq = 0; qq < Q; ++qq) {
        float nv = v[qq * 8]; int nj = qq * 8;
#pragma unroll
        for (int j = 1; j < 8; ++j)
            if (v[qq * 8 + j] > nv) { nv = v[qq * 8 + j]; nj = qq * 8 + j; }
        qv[qq] = nv; qj[qq] = nj;
    }
#pragma clang loop unroll(disable)
    for (int kk = 0; kk < K; ++kk) {
        float bv = qv[0]; int bj = qj[0];
#pragma unroll
        for (int qq = 1; qq < Q; ++qq)
            if (qv[qq] > bv) { bv = qv[qq]; bj = qj[qq]; }   // quarters ascend in j
        int bm = lane + 64 * bj;
        for (int off = 32; off; off >>= 1) {
            float ov = __shfl_down(bv, off);
            int   om = __shfl_down(bm, off);
            if (ov > bv || (ov == bv && om < bm)) { bv = ov; bm = om; }
        }
        int m_win = __builtin_amdgcn_readfirstlane(bm);   // wave-uniform
        if (lane == 0)
            out_idx[((size_t)(b * q_cnt) + q) * K + kk] = m_win;
        int w_slot = m_win >> 6;                 // uniform
        bool isw = (lane == (m_win & 63));       // per-lane
#pragma unroll
        for (int qq = 0; qq < Q; ++qq) {
            if (qq == (w_slot >> 3)) {           // uniform branch: 1 of Q quarters
#pragma unroll
                for (int j = 0; j < 8; ++j)
                    if (qq * 8 + j == w_slot)    // uniform: 1 of 8 slots
                        v[qq * 8 + j] = isw ? -3.4e38f : v[qq * 8 + j];
                float nv = v[qq * 8]; int nj = qq * 8;
#pragma unroll
                for (int j = 1; j < 8; ++j)
                    if (v[qq * 8 + j] > nv) { nv = v[qq * 8 + j]; nj = qq * 8 + j; }
                qv[qq] = nv; qj[qq] = nj;
            }
        }
    }
}

// ============================ nearest (register argmin, wave-per-query) ======
template <int SLOTS>
__global__ __launch_bounds__(256)
void nearest_reg_kernel(const float* __restrict__ coord, int cand_stride,
                        int* __restrict__ out)
{
#pragma clang fp contract(off)
    int b = blockIdx.y;
    int wave = threadIdx.x >> 6, lane = threadIdx.x & 63;
    int n = blockIdx.x * 4 + wave;
    float qx = coord[(b * 3 + 0) * NTOT + n];
    float qy = coord[(b * 3 + 1) * NTOT + n];
    float qz = coord[(b * 3 + 2) * NTOT + n];
    float tt = qx * qx + qy * qy + qz * qz;
    float v[SLOTS];
#pragma unroll
    for (int j = 0; j < SLOTS; ++j) {
        int mo = (lane + 64 * j) * cand_stride;
        float cx = coord[(b * 3 + 0) * NTOT + mo];
        float cy = coord[(b * 3 + 1) * NTOT + mo];
        float cz = coord[(b * 3 + 2) * NTOT + mo];
        float inner = qx * cx + qy * cy + qz * cz;
        float ss = cx * cx + cy * cy + cz * cz;
        v[j] = (tt - 2.0f * inner) + ss;
    }
    float bv = v[0];
    int bj = 0;
#pragma unroll
    for (int j = 1; j < SLOTS; ++j)
        if (v[j] < bv) { bv = v[j]; bj = j; }
    int bm = lane + 64 * bj;
    for (int off = 32; off; off >>= 1) {
        float ov = __shfl_down(bv, off);
        int   om = __shfl_down(bm, off);
        if (ov < bv || (ov == bv && om < bm)) { bv = ov; bm = om; }
    }
    if (lane == 0) out[b * NTOT + n] = bm;
}

// ============================ surface feature build ============================
__global__ void surf_build_kernel(const float* __restrict__ coord,
                                  const int* __restrict__ idx20,
                                  float* __restrict__ fs)
{
#pragma clang fp contract(off)
    int t = blockIdx.x * 256 + threadIdx.x;
    if (t >= BTOT * NTOT * 20) return;
    int n = (t / 20) & (NTOT - 1);
    int b = t / (20 * NTOT);
    int m = idx20[t];
    float cx = coord[(b * 3 + 0) * NTOT + n];
    float cy = coord[(b * 3 + 1) * NTOT + n];
    float cz = coord[(b * 3 + 2) * NTOT + n];
    float nx = coord[(b * 3 + 0) * NTOT + m];
    float ny = coord[(b * 3 + 1) * NTOT + m];
    float nz = coord[(b * 3 + 2) * NTOT + m];
    float* f9 = fs + (size_t)t * 9;
    f9[0] = nx - cx; f9[1] = ny - cy; f9[2] = nz - cz;
    f9[3] = cx;      f9[4] = cy;      f9[5] = cz;
    f9[6] = ny * cz - nz * cy;
    f9[7] = nz * cx - nx * cz;
    f9[8] = nx * cy - ny * cx;
}

// ============================ stage-0 stats / apply (4 waves x 4 pts) ========
__global__ __launch_bounds__(256)
void stats0_kernel(const float* __restrict__ fs,
                   const float* __restrict__ wf0,
                   double* __restrict__ stats)
{
#pragma clang fp contract(off)
    __shared__ float fl[4][720];
    __shared__ double red[4][84];
    int wave = threadIdx.x >> 6, lane = threadIdx.x & 63;
    int b = blockIdx.y;
    int n0 = (blockIdx.x * 4 + wave) * 4;
    const float* src = fs + ((size_t)(b * NTOT + n0) * 20) * 9;
    for (int t = lane; t < 720; t += 64) fl[wave][t] = src[t];
    __syncthreads();
    int o = lane;
    if (o < 42) {
        float w0 = wf0[o * 3], w1 = wf0[o * 3 + 1], w2 = wf0[o * 3 + 2];
        double s = 0.0, s2 = 0.0;
        for (int i = 0; i < 80; ++i) {
            const float* f9 = &fl[wave][i * 9];
            float p0 = w0 * f9[0] + w1 * f9[3] + w2 * f9[6];
            float p1 = w0 * f9[1] + w1 * f9[4] + w2 * f9[7];
            float p2 = w0 * f9[2] + w1 * f9[5] + w2 * f9[8];
            float nrm = sqrtf(p0 * p0 + p1 * p1 + p2 * p2) + 1e-6f;
            s += (double)nrm; s2 += (double)nrm * (double)nrm;
        }
        red[wave][o] = s;
        red[wave][42 + o] = s2;
    }
    __syncthreads();
    int t = threadIdx.x;
    if (t < 84)
        atomicAdd(&stats[t], red[0][t] + red[1][t] + red[2][t] + red[3][t]);
}

__global__ __launch_bounds__(256)
void apply0_kernel(const float* __restrict__ fs,
                   const float* __restrict__ wf0,
                   const float* __restrict__ wd0,
                   const float* __restrict__ g0,
                   const float* __restrict__ b0,
                   const double* __restrict__ stats,
                   float* __restrict__ x0)
{
#pragma clang fp contract(off)
    __shared__ float fl[4][720];
    int wave = threadIdx.x >> 6, lane = threadIdx.x & 63;
    int b = blockIdx.y;
    int n0 = (blockIdx.x * 4 + wave) * 4;
    const float* src = fs + ((size_t)(b * NTOT + n0) * 20) * 9;
    for (int t = lane; t < 720; t += 64) fl[wave][t] = src[t];
    __syncthreads();
    int o = lane;
    if (o >= 42) return;
    double S1 = stats[o], S2 = stats[42 + o];
    double md = S1 / 163840.0;
    float m = (float)md;
    float var = (float)(S2 / 163840.0 - md * md);
    float sqv = sqrtf(var + 1e-5f);
    float gg = g0[o], bb = b0[o];
    float wa0 = wf0[o * 3], wa1 = wf0[o * 3 + 1], wa2 = wf0[o * 3 + 2];
    float wb0 = wd0[o * 3], wb1 = wd0[o * 3 + 1], wb2 = wd0[o * 3 + 2];
    for (int pp = 0; pp < 4; ++pp) {
        float r8[3][8];
        float tl[3][4];
        for (int k = 0; k < 20; ++k) {
            const float* f9 = &fl[wave][(pp * 20 + k) * 9];
            float p0 = wa0 * f9[0] + wa1 * f9[3] + wa2 * f9[6];
            float p1 = wa0 * f9[1] + wa1 * f9[4] + wa2 * f9[7];
            float p2 = wa0 * f9[2] + wa1 * f9[5] + wa2 * f9[8];
            float d0 = wb0 * f9[0] + wb1 * f9[3] + wb2 * f9[6];
            float d1 = wb0 * f9[1] + wb1 * f9[4] + wb2 * f9[7];
            float d2 = wb0 * f9[2] + wb1 * f9[5] + wb2 * f9[8];
            float nrm = sqrtf(p0 * p0 + p1 * p1 + p2 * p2) + 1e-6f;
            float nb = gg * (nrm - m) / sqv + bb;
            p0 = p0 / nrm * nb;
            p1 = p1 / nrm * nb;
            p2 = p2 / nrm * nb;
            float dot = p0 * d0 + p1 * d1 + p2 * d2;
            float r0, r1, r2;
            if (dot >= 0.f) { r0 = p0; r1 = p1; r2 = p2; }
            else {
                float tq = dot / (d0 * d0 + d1 * d1 + d2 * d2 + 1e-6f);
                r0 = p0 - tq * d0; r1 = p1 - tq * d1; r2 = p2 - tq * d2;
            }
            float o0 = 0.2f * p0 + 0.8f * r0;
            float o1 = 0.2f * p1 + 0.8f * r1;
            float o2 = 0.2f * p2 + 0.8f * r2;
            if (k < 8)       { r8[0][k] = o0;       r8[1][k] = o1;       r8[2][k] = o2; }
            else if (k < 16) { r8[0][k-8] += o0;    r8[1][k-8] += o1;    r8[2][k-8] += o2; }
            else             { tl[0][k-16] = o0;    tl[1][k-16] = o1;    tl[2][k-16] = o2; }
        }
        int n = n0 + pp;
        for (int v = 0; v < 3; ++v) {
            float res = ((r8[v][0] + r8[v][1]) + (r8[v][2] + r8[v][3])) +
                        ((r8[v][4] + r8[v][5]) + (r8[v][6] + r8[v][7]));
            res += tl[v][0]; res += tl[v][1]; res += tl[v][2]; res += tl[v][3];
            x0[((size_t)(b * 42 + o) * 3 + v) * NTOT + n] = res / 20.0f;
        }
    }
}

// ============================ generic VN stats ============================
__global__ void vn_stats_kernel(const float* __restrict__ xin,
                                const float* __restrict__ wf,
                                double* __restrict__ stats,
                                int Ci, int Co, int Npts)
{
#pragma clang fp contract(off)
    __shared__ float col[252];
    int b = blockIdx.y;
    int o = threadIdx.x;
    double s = 0.0, s2 = 0.0;
    for (int it = 0; it < 16; ++it) {
        int pt = blockIdx.x * 16 + it;
        __syncthreads();
        for (int t = threadIdx.x; t < Ci * 3; t += blockDim.x)
            col[t] = xin[(size_t)(b * 3 * Ci + t) * Npts + pt];
        __syncthreads();
        if (o < Co) {
            const float* wr = wf + o * Ci;
            float p0 = 0.f, p1 = 0.f, p2 = 0.f;
            for (int c = 0; c < Ci; ++c) {
                float w = wr[c];
                p0 += w * col[3 * c]; p1 += w * col[3 * c + 1]; p2 += w * col[3 * c + 2];
            }
            float nrm = sqrtf(p0 * p0 + p1 * p1 + p2 * p2) + 1e-6f;
            s += (double)nrm; s2 += (double)nrm * (double)nrm;
        }
    }
    if (o < Co) { atomicAdd(&stats[o], s); atomicAdd(&stats[Co + o], s2); }
}

// ============================ VN apply (OPAD thread mapping) ==================
__global__ __launch_bounds__(256)
void vn_apply_kernel(const float* __restrict__ xin,
                     const float* __restrict__ wf,
                     const float* __restrict__ wd,
                     const float* __restrict__ g,
                     const float* __restrict__ bbp,
                     const double* __restrict__ stats,
                     double count, int Ci, int Co, int Npts,
                     int oshift, int nit,
                     float* __restrict__ xout)
{
#pragma clang fp contract(off)
    __shared__ float col[520];
    int t = threadIdx.x;
    int b = blockIdx.y;
    int OPAD = 1 << oshift;
    int PTS = 256 >> oshift;
    int o = t & (OPAD - 1);
    int ps = t >> oshift;
    int Ci3 = Ci * 3;
    int stride = Ci3 + 1;
    float m = 0.f, sqv = 1.f, gg = 0.f, bb = 0.f;
    if (o < Co) {
        double S1 = stats[o], S2 = stats[Co + o];
        double md = S1 / count;
        m = (float)md;
        float var = (float)(S2 / count - md * md);
        sqv = sqrtf(var + 1e-5f);
        gg = g[o]; bb = bbp[o];
    }
    int pt0 = blockIdx.x * (PTS * nit);
    for (int it = 0; it < nit; ++it) {
        int ptbase = pt0 + it * PTS;
        __syncthreads();
        for (int i = t; i < PTS * Ci3; i += 256) {
            int pl = i / Ci3, off = i - pl * Ci3;
            col[pl * stride + off] =
                xin[(size_t)(b * 3 * Ci + off) * Npts + (ptbase + pl)];
        }
        __syncthreads();
        if (o < Co) {
            const float* cl = &col[ps * stride];
            const float* wr = wf + o * Ci;
            const float* wdr = wd + o * Ci;
            float p0 = 0.f, p1 = 0.f, p2 = 0.f, d0 = 0.f, d1 = 0.f, d2 = 0.f;
            for (int c = 0; c < Ci; ++c) {
                float c0 = cl[3 * c], c1 = cl[3 * c + 1], c2 = cl[3 * c + 2];
                float w = wr[c];
                p0 += w * c0; p1 += w * c1; p2 += w * c2;
                float w2 = wdr[c];
                d0 += w2 * c0; d1 += w2 * c1; d2 += w2 * c2;
            }
            float nrm = sqrtf(p0 * p0 + p1 * p1 + p2 * p2) + 1e-6f;
            float nb = gg * (nrm - m) / sqv + bb;
            p0 = p0 / nrm * nb;
            p1 = p1 / nrm * nb;
            p2 = p2 / nrm * nb;
            float dot = p0 * d0 + p1 * d1 + p2 * d2;
            float r0, r1, r2;
            if (dot >= 0.f) { r0 = p0; r1 = p1; r2 = p2; }
            else {
                float tq = dot / (d0 * d0 + d1 * d1 + d2 * d2 + 1e-6f);
                r0 = p0 - tq * d0; r1 = p1 - tq * d1; r2 = p2 - tq * d2;
            }
            int pt = ptbase + ps;
            xout[((size_t)(b * Co + o) * 3 + 0) * Npts + pt] = 0.2f * p0 + 0.8f * r0;
            xout[((size_t)(b * Co + o) * 3 + 1) * Npts + pt] = 0.2f * p1 + 0.8f * r1;
            xout[((size_t)(b * Co + o) * 3 + 2) * Npts + pt] = 0.2f * p2 + 0.8f * r2;
        }
    }
}

// ============================ VN max-pool-down ============================
__global__ void vn_pool_kernel(const float* __restrict__ xin,
                               const int* __restrict__ idx, long long sb, int sq,
                               const float* __restrict__ wp,
                               float* __restrict__ xout,
                               int C, int Np, int Nq)
{
#pragma clang fp contract(off)
    __shared__ float nb[4 * 84 * 3];
    int b = blockIdx.y;
    int q = blockIdx.x;
    const int* ir = idx + b * sb + (long long)q * sq;
    for (int kk = 0; kk < 4; ++kk) {
        int mm = ir[kk];
        for (int t = threadIdx.x; t < C * 3; t += blockDim.x)
            nb[kk * C * 3 + t] = xin[(size_t)(b * 3 * C + t) * Np + mm];
    }
    __syncthreads();
    int o = threadIdx.x;
    if (o >= C) return;
    const float* wr = wp + o * C;
    float best = -3.4e38f;
    int bk = 0;
    for (int kk = 0; kk < 4; ++kk) {
        const float* cl = &nb[kk * C * 3];
        float d0 = 0.f, d1 = 0.f, d2 = 0.f;
        for (int c = 0; c < C; ++c) {
            float w = wr[c];
            d0 += w * cl[3 * c]; d1 += w * cl[3 * c + 1]; d2 += w * cl[3 * c + 2];
        }
        float dot = cl[o * 3] * d0 + cl[o * 3 + 1] * d1 + cl[o * 3 + 2] * d2;
        if (dot > best) { best = dot; bk = kk; }
    }
    const float* cb = &nb[bk * C * 3];
    xout[((size_t)(b * C + o) * 3 + 0) * Nq + q] = cb[o * 3];
    xout[((size_t)(b * C + o) * 3 + 1) * Nq + q] = cb[o * 3 + 1];
    xout[((size_t)(b * C + o) * 3 + 2) * Nq + q] = cb[o * 3 + 2];
}

// ============================ eqv assembly + fused mean partial ==============
__global__ void eqv_kernel(const float* __restrict__ x0, const float* __restrict__ x1,
                           const float* __restrict__ x2, const float* __restrict__ x3,
                           const float* __restrict__ x4,
                           const int* __restrict__ i1, const int* __restrict__ i2,
                           float* __restrict__ out_eqv, float* __restrict__ mfw)
{
    __shared__ float r1[256];
    int n = blockIdx.x * 256 + threadIdx.x;
    int cv = blockIdx.y;
    int b = blockIdx.z;
    int cc = cv / 3, v = cv % 3;
    float val;
    if (cc < 42)
        val = x0[((size_t)(b * 42 + cc) * 3 + v) * NTOT + n];
    else if (cc < 84)
        val = x1[((size_t)(b * 42 + (cc - 42)) * 3 + v) * NTOT + n];
    else if (cc < 168) {
        int m = i1[b * NTOT + n];
        val = x2[((size_t)(b * 84 + (cc - 84)) * 3 + v) * 512 + m];
    } else if (cc < 252) {
        int m = i1[b * NTOT + n];
        val = x3[((size_t)(b * 84 + (cc - 168)) * 3 + v) * 512 + m];
    } else {
        int m = i2[b * NTOT + n];
        val = x4[((size_t)(b * 168 + (cc - 252)) * 3 + v) * 128 + m];
    }
    out_eqv[((size_t)(b * 1260 + cv)) * NTOT + n] = val;
    r1[threadIdx.x] = val;
    __syncthreads();
    for (int off = 128; off; off >>= 1) {
        if ((int)threadIdx.x < off) r1[threadIdx.x] += r1[threadIdx.x + off];
        __syncthreads();
    }
    if (threadIdx.x == 0) atomicAdd(&mfw[b * 1260 + cv], r1[0]);
}

// ============================ mean_feat finalize ============================
__global__ void mf_finalize_kernel(float* __restrict__ mfw, float* __restrict__ out_mf)
{
    int i = blockIdx.x * 256 + threadIdx.x;
    if (i < 5040) {
        float m = mfw[i] / 2048.0f;
        mfw[i] = m;
        out_mf[i] = m;
    }
}

// ============================ z-chain + inv_gl ============================
__global__ void z_kernel(const float* __restrict__ mfw,
                         const float* __restrict__ wv1f, const float* __restrict__ wv1d,
                         const float* __restrict__ wv2f, const float* __restrict__ wv2d,
                         const float* __restrict__ w3,
                         float* __restrict__ invgl_ws, float* __restrict__ out_invgl)
{
#pragma clang fp contract(off)
    __shared__ float mf[1260];
    __shared__ float z1[630];
    __shared__ float z2[252];
    __shared__ float z3[6];
    int b = blockIdx.x;
    int t = threadIdx.x;
    for (int i = t; i < 1260; i += 256) mf[i] = mfw[b * 1260 + i];
    __syncthreads();
    if (t < 210) {
        float p0 = 0.f, p1 = 0.f, p2 = 0.f, d0 = 0.f, d1 = 0.f, d2 = 0.f;
        for (int c = 0; c < 420; ++c) {
            float m0 = mf[3 * c], m1 = mf[3 * c + 1], m2 = mf[3 * c + 2];
            float w = wv1f[t * 420 + c];
            p0 += w * m0; p1 += w * m1; p2 += w * m2;
            float w2 = wv1d[t * 420 + c];
            d0 += w2 * m0; d1 += w2 * m1; d2 += w2 * m2;
        }
        float dot = p0 * d0 + p1 * d1 + p2 * d2;
        float r0, r1, r2;
        if (dot >= 0.f) { r0 = p0; r1 = p1; r2 = p2; }
        else {
            float tq = dot / (d0 * d0 + d1 * d1 + d2 * d2 + 1e-6f);
            r0 = p0 - tq * d0; r1 = p1 - tq * d1; r2 = p2 - tq * d2;
        }
        z1[t * 3]     = 0.2f * p0 + 0.8f * r0;
        z1[t * 3 + 1] = 0.2f * p1 + 0.8f * r1;
        z1[t * 3 + 2] = 0.2f * p2 + 0.8f * r2;
    }
    __syncthreads();
    if (t < 84) {
        float p0 = 0.f, p1 = 0.f, p2 = 0.f, d0 = 0.f, d1 = 0.f, d2 = 0.f;
        for (int c = 0; c < 210; ++c) {
            float m0 = z1[3 * c], m1 = z1[3 * c + 1], m2 = z1[3 * c + 2];
            float w = wv2f[t * 210 + c];
            p0 += w * m0; p1 += w * m1; p2 += w * m2;
            float w2 = wv2d[t * 210 + c];
            d0 += w2 * m0; d1 += w2 * m1; d2 += w2 * m2;
        }
        float dot = p0 * d0 + p1 * d1 + p2 * d2;
        float r0, r1, r2;
        if (dot >= 0.f) { r0 = p0; r1 = p1; r2 = p2; }
        else {
            float tq = dot / (d0 * d0 + d1 * d1 + d2 * d2 + 1e-6f);
            r0 = p0 - tq * d0; r1 = p1 - tq * d1; r2 = p2 - tq * d2;
        }
        z2[t * 3]     = 0.2f * p0 + 0.8f * r0;
        z2[t * 3 + 1] = 0.2f * p1 + 0.8f * r1;
        z2[t * 3 + 2] = 0.2f * p2 + 0.8f * r2;
    }
    __syncthreads();
    if (t < 6) {
        int v = t / 2, kt = t % 2;
        float s = 0.f;
        for (int c = 0; c < 84; ++c) s += z2[c * 3 + v] * w3[kt * 84 + c];
        z3[v * 2 + kt] = s;
    }
    __syncthreads();
    for (int i = t; i < 840; i += 256) {
        int ii = i / 2, kt = i % 2;
        float s = mf[ii * 3] * z3[0 + kt] + mf[ii * 3 + 1] * z3[2 + kt] +
                  mf[ii * 3 + 2] * z3[4 + kt];
        invgl_ws[b * 840 + i] = s;
        out_invgl[b * 840 + i] = s;
    }
}

// ============================ conv1 factored coefficients ====================
// y1[o,(b,n)] = cb[b,o] + ab[b,o,:]·coord[:,n] + ws1[o,0]*norm[b,n]
__global__ void conv1_coef_kernel(const float* __restrict__ ws1,
                                  const float* __restrict__ invgl,
                                  const float* __restrict__ mfw,
                                  const int* __restrict__ cat,
                                  float* __restrict__ cb, float* __restrict__ ab,
                                  float* __restrict__ w0)
{
#pragma clang fp contract(off)
    int o = blockIdx.x * 256 + threadIdx.x;   // 0..1023
    int b = blockIdx.y;
    const float* wr = ws1 + (size_t)o * 1267;
    float s = 0.f;
    for (int j = 0; j < 840; ++j) s += wr[1 + j] * invgl[b * 840 + j];
    s += wr[1261 + cat[b]];
    cb[b * 1024 + o] = s;
    float a0 = 0.f, a1 = 0.f, a2 = 0.f;
    for (int i = 0; i < 420; ++i) {
        float w = wr[841 + i];
        a0 += w * mfw[b * 1260 + i * 3];
        a1 += w * mfw[b * 1260 + i * 3 + 1];
        a2 += w * mfw[b * 1260 + i * 3 + 2];
    }
    ab[((size_t)(b * 1024 + o)) * 3 + 0] = a0;
    ab[((size_t)(b * 1024 + o)) * 3 + 1] = a1;
    ab[((size_t)(b * 1024 + o)) * 3 + 2] = a2;
    w0[o] = wr[0];
}

// ============================ y1 generator (replaces gemm1) ==================
__global__ __launch_bounds__(256)
void y1_gen_kernel(const float* __restrict__ cb, const float* __restrict__ ab,
                   const float* __restrict__ w0, const float* __restrict__ coord,
                   const float* __restrict__ normv, float* __restrict__ y1t)
{
#pragma clang fp contract(off)
    int pt = blockIdx.x;                // 0..8191
    int b = pt >> 11, n = pt & 2047;
    float cx = coord[(b * 3 + 0) * NTOT + n];
    float cy = coord[(b * 3 + 1) * NTOT + n];
    float cz = coord[(b * 3 + 2) * NTOT + n];
    float nr = normv[b * NTOT + n];
    for (int it = 0; it < 4; ++it) {
        int o = it * 256 + threadIdx.x;
        size_t bo = (size_t)(b * 1024 + o);
        float v = cb[bo] + ab[bo * 3] * cx + ab[bo * 3 + 1] * cy +
                  ab[bo * 3 + 2] * cz + w0[o] * nr;
        y1t[(size_t)pt * 1024 + o] = v;
    }
}

// ============================ weight convert f32 -> bf16 ============================
__global__ void wconv_kernel(const float* __restrict__ src, unsigned short* __restrict__ dst,
                             int Msrc, int Ksrc, int Kpad)
{
    int k = blockIdx.x * 256 + threadIdx.x;
    int o = blockIdx.y;
    float v = (o < Msrc && k < Ksrc) ? src[(size_t)o * Ksrc + k] : 0.f;
    dst[(size_t)o * Kpad + k] = f2b(v);
}

// ============================ MFMA GEMM ============================
__global__ __launch_bounds__(256)
void gemm_mfma_kernel(const unsigned short* __restrict__ A,
                      const unsigned short* __restrict__ Bw,
                      float* __restrict__ C, int K, int Mreal)
{
    __shared__ __align__(16) unsigned short Al[128 * 40];
    __shared__ __align__(16) unsigned short Bl[128 * 40];
    int t = threadIdx.x;
    int r0 = blockIdx.x * 128;
    int c0 = blockIdx.y * 128;
    int w = t >> 6, l = t & 63;
    int wm = w & 1, wn = w >> 1;
    int lm = l & 15, lq = l >> 4;
    f32x4 acc[4][4] = {};
    for (int k0 = 0; k0 < K; k0 += 32) {
        for (int half = 0; half < 2; ++half) {
            int ch = t + half * 256;
            int row = ch >> 2, kc = ch & 3;
            *(uint4*)&Al[row * 40 + kc * 8] =
                *(const uint4*)&A[(size_t)(r0 + row) * K + k0 + kc * 8];
            *(uint4*)&Bl[row * 40 + kc * 8] =
                *(const uint4*)&Bw[(size_t)(c0 + row) * K + k0 + kc * 8];
        }
        __syncthreads();
        bf16x8 af[4], bfr[4];
#pragma unroll
        for (int i = 0; i < 4; ++i)
            af[i] = *(const bf16x8*)&Al[(wm * 64 + i * 16 + lm) * 40 + lq * 8];
#pragma unroll
        for (int j = 0; j < 4; ++j)
            bfr[j] = *(const bf16x8*)&Bl[(wn * 64 + j * 16 + lm) * 40 + lq * 8];
#pragma unroll
        for (int i = 0; i < 4; ++i)
#pragma unroll
            for (int j = 0; j < 4; ++j)
                acc[i][j] = __builtin_amdgcn_mfma_f32_16x16x32_bf16(af[i], bfr[j],
                                                                    acc[i][j], 0, 0, 0);
        __syncthreads();
    }
#pragma unroll
    for (int i = 0; i < 4; ++i) {
#pragma unroll
        for (int j = 0; j < 4; ++j) {
            int col = c0 + wn * 64 + j * 16 + lm;
            if (col < Mreal) {
                int rbase = r0 + wm * 64 + i * 16 + lq * 4;
#pragma unroll
                for (int r = 0; r < 4; ++r)
                    C[(size_t)(rbase + r) * Mreal + col] = acc[i][j][r];
            }
        }
    }
}

// ============================ conv BN stats ============================
__global__ void cstatsT_kernel(const float* __restrict__ Ct, float* __restrict__ st,
                               int Mreal)
{
    __shared__ float l1[256], l2[256];
    int t = threadIdx.x;
    int o = blockIdx.x * 64 + (t & 63);
    int r0 = blockIdx.y * 128 + (t >> 6) * 32;
    float s = 0.f, s2 = 0.f;
    if (o < Mreal) {
        for (int rr = 0; rr < 32; ++rr) {
            float v = Ct[(size_t)(r0 + rr) * Mreal + o];
            s += v; s2 += v * v;
        }
    }
    l1[t] = s; l2[t] = s2;
    __syncthreads();
    if (t < 64 && o < Mreal) {
        s  = l1[t] + l1[t + 64] + l1[t + 128] + l1[t + 192];
        s2 = l2[t] + l2[t + 64] + l2[t + 128] + l2[t + 192];
        atomicAdd(&st[o], s);
        atomicAdd(&st[Mreal + o], s2);
    }
}

// ============================ BN+ReLU -> bf16 ============================
__global__ void bnreluT_kernel(const float* __restrict__ Ct, const float* __restrict__ st,
                               const float* __restrict__ g, const float* __restrict__ be,
                               unsigned short* __restrict__ outb, int M, int maskM)
{
#pragma clang fp contract(off)
    size_t idx = (size_t)blockIdx.x * 256 + threadIdx.x;
    int o = (int)(idx & (size_t)maskM);
    float m = st[o] * (1.f / 8192.f);
    float var = st[M + o] * (1.f / 8192.f) - m * m;
    float sqv = sqrtf(var + 1e-5f);
    float v = g[o] * (Ct[idx] - m) / sqv + be[o];
    outb[idx] = f2b(v > 0.f ? v : 0.f);
}

// ============================ final BN+ReLU + transpose ============================
__global__ void bnrelu_outT_kernel(const float* __restrict__ Ct, const float* __restrict__ st,
                                   const float* __restrict__ g, const float* __restrict__ be,
                                   float* __restrict__ outinv)
{
#pragma clang fp contract(off)
    __shared__ float tile[64][65];
    int t = threadIdx.x;
    int r0 = blockIdx.x * 64;
    int o0 = blockIdx.y * 64;
    int b = r0 >> 11, n0 = r0 & 2047;
    int oi = t & 63;
    int o = o0 + oi;
    float m = 0.f, sqv = 1.f, gg = 0.f, bb = 0.f;
    if (o < 420) {
        m = st[o] * (1.f / 8192.f);
        float var = st[420 + o] * (1.f / 8192.f) - m * m;
        sqv = sqrtf(var + 1e-5f);
        gg = g[o]; bb = be[o];
    }
    for (int it = 0; it < 16; ++it) {
        int rr = it * 4 + (t >> 6);
        float v = 0.f;
        if (o < 420) {
            v = gg * (Ct[(size_t)(r0 + rr) * 420 + o] - m) / sqv + bb;
            v = v > 0.f ? v : 0.f;
        }
        tile[rr][oi] = v;
    }
    __syncthreads();
    for (int it = 0; it < 16; ++it) {
        int oc = it * 4 + (t >> 6);
        int oo = o0 + oc;
        if (oo < 420)
            outinv[((size_t)(b * 420 + oo)) * 2048 + n0 + (t & 63)] = tile[t & 63][oc];
    }
}

// ============================ launch ============================
extern "C" void kernel_launch(void* const* d_in, const int* in_sizes, int n_in,
                              void* d_out, int out_size, void* d_ws, size_t ws_size,
                              hipStream_t stream)
{
    (void)in_sizes; (void)n_in; (void)out_size; (void)ws_size;
    const float* xc   = (const float*)d_in[0];
    const float* normv= (const float*)d_in[1];
    const int*   cat  = (const int*)d_in[2];
    const float* wf0  = (const float*)d_in[3];
    const float* wd0  = (const float*)d_in[4];
    const float* g0   = (const float*)d_in[5];
    const float* b0   = (const float*)d_in[6];
    const float* wf1  = (const float*)d_in[7];
    const float* wd1  = (const float*)d_in[8];
    const float* g1   = (const float*)d_in[9];
    const float* b1   = (const float*)d_in[10];
    const float* wp1  = (const float*)d_in[11];
    const float* wf2  = (const float*)d_in[12];
    const float* wd2  = (const float*)d_in[13];
    const float* g2   = (const float*)d_in[14];
    const float* b2   = (const float*)d_in[15];
    const float* wf3  = (const float*)d_in[16];
    const float* wd3  = (const float*)d_in[17];
    const float* g3   = (const float*)d_in[18];
    const float* b3   = (const float*)d_in[19];
    const float* wp2  = (const float*)d_in[20];
    const float* wf4  = (const float*)d_in[21];
    const float* wd4  = (const float*)d_in[22];
    const float* g4   = (const float*)d_in[23];
    const float* b4   = (const float*)d_in[24];
    const float* wv1f = (const float*)d_in[25];
    const float* wv1d = (const float*)d_in[26];
    const float* wv2f = (const float*)d_in[27];
    const float* wv2d = (const float*)d_in[28];
    const float* w3   = (const float*)d_in[29];
    const float* ws1  = (const float*)d_in[30];
    const float* sg1  = (const float*)d_in[32];
    const float* sb1  = (const float*)d_in[33];
    const float* ws2  = (const float*)d_in[34];
    const float* sg2  = (const float*)d_in[36];
    const float* sb2  = (const float*)d_in[37];
    const float* ws3  = (const float*)d_in[38];
    const float* sg3  = (const float*)d_in[40];
    const float* sb3  = (const float*)d_in[41];

    float* ws = (float*)d_ws;
    float* out = (float*)d_out;

    int*    idx20 = (int*)(ws + WS_IDX20);
    float*  fs    = ws + WS_FS;
    float*  x0    = ws + WS_X0;
    float*  x1    = ws + WS_X1;
    float*  xm2   = ws + WS_XM2;
    float*  x2    = ws + WS_X2;
    float*  x3    = ws + WS_X3;
    int*    idx42 = (int*)(ws + WS_IDX42);
    float*  xm4   = ws + WS_XM4;
    float*  x4    = ws + WS_X4;
    int*    i1p   = (int*)(ws + WS_I1);
    int*    i2p   = (int*)(ws + WS_I2);
    float*  mfw   = ws + WS_MF;
    float*  invgl = ws + WS_INVGL;
    double* st    = (double*)(ws + WS_STATS);
    float*  cst   = ws + WS_CST;
    float*  cb    = ws + WS_CB;
    float*  ab    = ws + WS_AB;
    float*  w0    = ws + WS_W0;
    unsigned short* w2b  = (unsigned short*)(ws + WS_W2B);
    unsigned short* w3b  = (unsigned short*)(ws + WS_W3B);
    float*  y1t   = ws + WS_Y1T;
    unsigned short* y1b  = (unsigned short*)(ws + WS_Y1B);
    float*  y2t   = ws + WS_Y2T;
    unsigned short* y2b  = (unsigned short*)(ws + WS_Y2B);
    float*  y3t   = ws + WS_Y3T;

    hipMemsetAsync((void*)st, 0, 840 * sizeof(double), stream);
    hipMemsetAsync((void*)cst, 0, 3912 * sizeof(float), stream);
    hipMemsetAsync((void*)mfw, 0, 5040 * sizeof(float), stream);

    // weight conversions (independent)
    wconv_kernel<<<dim3(4, 512), 256, 0, stream>>>(ws2, w2b, 512, 1024, 1024);
    wconv_kernel<<<dim3(2, 512), 256, 0, stream>>>(ws3, w3b, 420, 512, 512);

    // KNN-20 (also the knn-4 prefix for pool stage 1)
    knn_reg_kernel<32, 20><<<dim3(512, 4), 256, 0, stream>>>(xc, 1, 1, idx20, 2048);
    surf_build_kernel<<<640, 256, 0, stream>>>(xc, idx20, fs);

    // stage 0
    stats0_kernel<<<dim3(128, 4), 256, 0, stream>>>(fs, wf0, st + ST0_OFF);
    apply0_kernel<<<dim3(128, 4), 256, 0, stream>>>(fs, wf0, wd0, g0, b0,
                                                    st + ST0_OFF, x0);

    // stage 1
    vn_stats_kernel<<<dim3(128, 4), 256, 0, stream>>>(x0, wf1, st + ST1_OFF, 42, 42, 2048);
    vn_apply_kernel<<<dim3(256, 4), 256, 0, stream>>>(x0, wf1, wd1, g1, b1, st + ST1_OFF,
                                                      8192.0, 42, 42, 2048, 6, 2, x1);

    // pool 1
    vn_pool_kernel<<<dim3(512, 4), 256, 0, stream>>>(x1, idx20, 40960LL, 80, wp1, xm2,
                                                     42, 2048, 512);
    // stage 2
    vn_stats_kernel<<<dim3(32, 4), 256, 0, stream>>>(xm2, wf2, st + ST2_OFF, 42, 84, 512);
    vn_apply_kernel<<<dim3(128, 4), 256, 0, stream>>>(xm2, wf2, wd2, g2, b2, st + ST2_OFF,
                                                      2048.0, 42, 84, 512, 7, 2, x2);
    // stage 3
    vn_stats_kernel<<<dim3(32, 4), 256, 0, stream>>>(x2, wf3, st + ST3_OFF, 84, 84, 512);
    vn_apply_kernel<<<dim3(128, 4), 256, 0, stream>>>(x2, wf3, wd3, g3, b3, st + ST3_OFF,
                                                      2048.0, 84, 84, 512, 7, 2, x3);

    // knn-4 on coord2 (cands stride 4, queries stride 16)
    knn_reg_kernel<8, 4><<<dim3(32, 4), 256, 0, stream>>>(xc, 4, 16, idx42, 128);
    vn_pool_kernel<<<dim3(128, 4), 256, 0, stream>>>(x3, idx42, 512LL, 4, wp2, xm4,
                                                     84, 512, 128);
    // stage 4
    vn_stats_kernel<<<dim3(8, 4), 256, 0, stream>>>(xm4, wf4, st + ST4_OFF, 84, 168, 128);
    vn_apply_kernel<<<dim3(64, 4), 256, 0, stream>>>(xm4, wf4, wd4, g4, b4, st + ST4_OFF,
                                                     512.0, 84, 168, 128, 8, 2, x4);

    // nearest-neighbor upsample indices
    nearest_reg_kernel<8><<<dim3(512, 4), 256, 0, stream>>>(xc, 4, i1p);
    nearest_reg_kernel<2><<<dim3(512, 4), 256, 0, stream>>>(xc, 16, i2p);

    // eqv (output 0) with fused mean partials; finalize mean (output 1)
    eqv_kernel<<<dim3(8, 1260, 4), 256, 0, stream>>>(x0, x1, x2, x3, x4, i1p, i2p,
                                                     out + OUT_EQV, mfw);
    mf_finalize_kernel<<<20, 256, 0, stream>>>(mfw, out + OUT_MF);

    // z chain + inv_gl (output 3)
    z_kernel<<<4, 256, 0, stream>>>(mfw, wv1f, wv1d, wv2f, wv2d, w3, invgl,
                                    out + OUT_INVGL);

    // invariant branch: conv1 factored (invin is [const; rank-3; const] per batch)
    conv1_coef_kernel<<<dim3(4, 4), 256, 0, stream>>>(ws1, invgl, mfw, cat, cb, ab, w0);
    y1_gen_kernel<<<8192, 256, 0, stream>>>(cb, ab, w0, xc, normv, y1t);
    cstatsT_kernel<<<dim3(16, 64), 256, 0, stream>>>(y1t, cst + CST1_OFF, 1024);
    bnreluT_kernel<<<32768, 256, 0, stream>>>(y1t, cst + CST1_OFF, sg1, sb1, y1b,
                                              1024, 1023);

    gemm_mfma_kernel<<<dim3(64, 4), 256, 0, stream>>>(y1b, w2b, y2t, 1024, 512);
    cstatsT_kernel<<<dim3(8, 64), 256, 0, stream>>>(y2t, cst + CST2_OFF, 512);
    bnreluT_kernel<<<16384, 256, 0, stream>>>(y2t, cst + CST2_OFF, sg2, sb2, y2b,
                                              512, 511);

    gemm_mfma_kernel<<<dim3(64, 4), 256, 0, stream>>>(y2b, w3b, y3t, 512, 420);
    cstatsT_kernel<<<dim3(7, 64), 256, 0, stream>>>(y3t, cst + CST3_OFF, 420);
    bnrelu_outT_kernel<<<dim3(128, 7), 256, 0, stream>>>(y3t, cst + CST3_OFF, sg3, sb3,
                                                         out + OUT_INV);
}

// Round 6
// 826.835 us; speedup vs baseline: 2.3045x; 1.0797x over previous
//
#include <hip/hip_runtime.h>
#include <hip/hip_bf16.h>
#include <cstdint>
#include <cstddef>

#define NTOT 2048
#define BTOT 4

typedef short bf16x8 __attribute__((ext_vector_type(8)));
typedef float f32x4 __attribute__((ext_vector_type(4)));

__device__ inline unsigned short f2b(float v) {
    __hip_bfloat16 h = __float2bfloat16(v);
    return *reinterpret_cast<unsigned short*>(&h);
}

// ---------------- workspace layout (float-element offsets) ----------------
static const size_t WS_IDX20 = 0;                       // int[163840]
static const size_t WS_FS    = 163840;                  // float[1474560]
static const size_t WS_X0    = 1638400;                 // float[2064384] (B,42,3,2048)
static const size_t WS_X1    = 3702784;                 // float[2064384]
static const size_t WS_XM2   = 5767168;                 // float[258048]
static const size_t WS_X2    = 6025216;                 // float[516096]
static const size_t WS_X3    = 6541312;                 // float[516096]
static const size_t WS_IDX42 = 7057408;                 // int[2048]
static const size_t WS_XM4   = 7059456;                 // float[129024]
static const size_t WS_X4    = 7188480;                 // float[258048]
static const size_t WS_I1    = 7446528;                 // int[8192]
static const size_t WS_I2    = 7454720;                 // int[8192]
static const size_t WS_MF    = 7462912;                 // float[5040]
static const size_t WS_INVGL = 7467952;                 // float[3360]
static const size_t WS_STATS = 7471312;                 // double[840] (1680 fl slots)
static const size_t WS_CST   = 7472992;                 // float[3912] conv bn sums
// conv1 factored coefficients (in old invT region; dead before y2t overlay use)
static const size_t WS_CB    = 7480320;                 // float[4096]   cb[b][o]
static const size_t WS_AB    = 7484416;                 // float[12288]  ab[b][o][3]
static const size_t WS_W0    = 7496704;                 // float[1024]   ws1[:,0]
static const size_t WS_W2B   = 13378560;                // ushort[512*1024]
static const size_t WS_W3B   = 13640704;                // ushort[512*512]
static const size_t WS_Y1T   = 13771776;                // float[8192*1024]
static const size_t WS_Y1B   = 0;                       // ushort overlay
static const size_t WS_Y2T   = 7480320;                 // float overlay (CB/AB dead)
static const size_t WS_Y2B   = 4194304;                 // ushort overlay
static const size_t WS_Y3T   = WS_Y1T;                  // float overlay

#define ST0_OFF 0
#define ST1_OFF 84
#define ST2_OFF 168
#define ST3_OFF 336
#define ST4_OFF 504
#define CST1_OFF 0
#define CST2_OFF 2048
#define CST3_OFF 3072

#define OUT_EQV   0
#define OUT_MF    10321920
#define OUT_INV   10326960
#define OUT_INVGL 13767600

// ============================ KNN v3 (cached quarter maxima) ==================
template <int SLOTS, int K>
__global__ __launch_bounds__(256)
void knn_reg_kernel(const float* __restrict__ coord, int cand_stride, int q_stride,
                    int* __restrict__ out_idx, int q_cnt)
{
#pragma clang fp contract(off)
    constexpr int Q = SLOTS / 8;
    int b = blockIdx.y;
    int wave = threadIdx.x >> 6, lane = threadIdx.x & 63;
    int q = blockIdx.x * 4 + wave;
    if (q >= q_cnt) return;
    int nq = q * q_stride;
    float qx = coord[(b * 3 + 0) * NTOT + nq];
    float qy = coord[(b * 3 + 1) * NTOT + nq];
    float qz = coord[(b * 3 + 2) * NTOT + nq];
    float xxq = qx * qx + qy * qy + qz * qz;
    float v[SLOTS];
#pragma unroll
    for (int j = 0; j < SLOTS; ++j) {
        int mo = (lane + 64 * j) * cand_stride;
        float cx = coord[(b * 3 + 0) * NTOT + mo];
        float cy = coord[(b * 3 + 1) * NTOT + mo];
        float cz = coord[(b * 3 + 2) * NTOT + mo];
        float inner = qx * cx + qy * cy + qz * cz;
        float xxc = cx * cx + cy * cy + cz * cz;
        v[j] = (2.0f * inner - xxq) - xxc;
    }
    float qv[Q]; int qj[Q];
#pragma unroll
    for (int qq = 0; qq < Q; ++qq) {
        float nv = v[qq * 8]; int nj = qq * 8;
#pragma unroll
        for (int j = 1; j < 8; ++j)
            if (v[qq * 8 + j] > nv) { nv = v[qq * 8 + j]; nj = qq * 8 + j; }
        qv[qq] = nv; qj[qq] = nj;
    }
#pragma clang loop unroll(disable)
    for (int kk = 0; kk < K; ++kk) {
        float bv = qv[0]; int bj = qj[0];
#pragma unroll
        for (int qq = 1; qq < Q; ++qq)
            if (qv[qq] > bv) { bv = qv[qq]; bj = qj[qq]; }
        int bm = lane + 64 * bj;
        for (int off = 32; off; off >>= 1) {
            float ov = __shfl_down(bv, off);
            int   om = __shfl_down(bm, off);
            if (ov > bv || (ov == bv && om < bm)) { bv = ov; bm = om; }
        }
        int m_win = __builtin_amdgcn_readfirstlane(bm);
        if (lane == 0)
            out_idx[((size_t)(b * q_cnt) + q) * K + kk] = m_win;
        int w_slot = m_win >> 6;
        bool isw = (lane == (m_win & 63));
#pragma unroll
        for (int qq = 0; qq < Q; ++qq) {
            if (qq == (w_slot >> 3)) {
#pragma unroll
                for (int j = 0; j < 8; ++j)
                    if (qq * 8 + j == w_slot)
                        v[qq * 8 + j] = isw ? -3.4e38f : v[qq * 8 + j];
                float nv = v[qq * 8]; int nj = qq * 8;
#pragma unroll
                for (int j = 1; j < 8; ++j)
                    if (v[qq * 8 + j] > nv) { nv = v[qq * 8 + j]; nj = qq * 8 + j; }
                qv[qq] = nv; qj[qq] = nj;
            }
        }
    }
}

// ============================ nearest (register argmin, wave-per-query) ======
template <int SLOTS>
__global__ __launch_bounds__(256)
void nearest_reg_kernel(const float* __restrict__ coord, int cand_stride,
                        int* __restrict__ out)
{
#pragma clang fp contract(off)
    int b = blockIdx.y;
    int wave = threadIdx.x >> 6, lane = threadIdx.x & 63;
    int n = blockIdx.x * 4 + wave;
    float qx = coord[(b * 3 + 0) * NTOT + n];
    float qy = coord[(b * 3 + 1) * NTOT + n];
    float qz = coord[(b * 3 + 2) * NTOT + n];
    float tt = qx * qx + qy * qy + qz * qz;
    float v[SLOTS];
#pragma unroll
    for (int j = 0; j < SLOTS; ++j) {
        int mo = (lane + 64 * j) * cand_stride;
        float cx = coord[(b * 3 + 0) * NTOT + mo];
        float cy = coord[(b * 3 + 1) * NTOT + mo];
        float cz = coord[(b * 3 + 2) * NTOT + mo];
        float inner = qx * cx + qy * cy + qz * cz;
        float ss = cx * cx + cy * cy + cz * cz;
        v[j] = (tt - 2.0f * inner) + ss;
    }
    float bv = v[0];
    int bj = 0;
#pragma unroll
    for (int j = 1; j < SLOTS; ++j)
        if (v[j] < bv) { bv = v[j]; bj = j; }
    int bm = lane + 64 * bj;
    for (int off = 32; off; off >>= 1) {
        float ov = __shfl_down(bv, off);
        int   om = __shfl_down(bm, off);
        if (ov < bv || (ov == bv && om < bm)) { bv = ov; bm = om; }
    }
    if (lane == 0) out[b * NTOT + n] = bm;
}

// ============================ surface feature build ============================
__global__ void surf_build_kernel(const float* __restrict__ coord,
                                  const int* __restrict__ idx20,
                                  float* __restrict__ fs)
{
#pragma clang fp contract(off)
    int t = blockIdx.x * 256 + threadIdx.x;
    if (t >= BTOT * NTOT * 20) return;
    int n = (t / 20) & (NTOT - 1);
    int b = t / (20 * NTOT);
    int m = idx20[t];
    float cx = coord[(b * 3 + 0) * NTOT + n];
    float cy = coord[(b * 3 + 1) * NTOT + n];
    float cz = coord[(b * 3 + 2) * NTOT + n];
    float nx = coord[(b * 3 + 0) * NTOT + m];
    float ny = coord[(b * 3 + 1) * NTOT + m];
    float nz = coord[(b * 3 + 2) * NTOT + m];
    float* f9 = fs + (size_t)t * 9;
    f9[0] = nx - cx; f9[1] = ny - cy; f9[2] = nz - cz;
    f9[3] = cx;      f9[4] = cy;      f9[5] = cz;
    f9[6] = ny * cz - nz * cy;
    f9[7] = nz * cx - nx * cz;
    f9[8] = nx * cy - ny * cx;
}

// ============================ stage-0 stats / apply (4 waves x 4 pts) ========
__global__ __launch_bounds__(256)
void stats0_kernel(const float* __restrict__ fs,
                   const float* __restrict__ wf0,
                   double* __restrict__ stats)
{
#pragma clang fp contract(off)
    __shared__ float fl[4][720];
    __shared__ double red[4][84];
    int wave = threadIdx.x >> 6, lane = threadIdx.x & 63;
    int b = blockIdx.y;
    int n0 = (blockIdx.x * 4 + wave) * 4;
    const float* src = fs + ((size_t)(b * NTOT + n0) * 20) * 9;
    for (int t = lane; t < 720; t += 64) fl[wave][t] = src[t];
    __syncthreads();
    int o = lane;
    if (o < 42) {
        float w0 = wf0[o * 3], w1 = wf0[o * 3 + 1], w2 = wf0[o * 3 + 2];
        double s = 0.0, s2 = 0.0;
        for (int i = 0; i < 80; ++i) {
            const float* f9 = &fl[wave][i * 9];
            float p0 = w0 * f9[0] + w1 * f9[3] + w2 * f9[6];
            float p1 = w0 * f9[1] + w1 * f9[4] + w2 * f9[7];
            float p2 = w0 * f9[2] + w1 * f9[5] + w2 * f9[8];
            float nrm = sqrtf(p0 * p0 + p1 * p1 + p2 * p2) + 1e-6f;
            s += (double)nrm; s2 += (double)nrm * (double)nrm;
        }
        red[wave][o] = s;
        red[wave][42 + o] = s2;
    }
    __syncthreads();
    int t = threadIdx.x;
    if (t < 84)
        atomicAdd(&stats[t], red[0][t] + red[1][t] + red[2][t] + red[3][t]);
}

__global__ __launch_bounds__(256)
void apply0_kernel(const float* __restrict__ fs,
                   const float* __restrict__ wf0,
                   const float* __restrict__ wd0,
                   const float* __restrict__ g0,
                   const float* __restrict__ b0,
                   const double* __restrict__ stats,
                   float* __restrict__ x0)
{
#pragma clang fp contract(off)
    __shared__ float fl[4][720];
    int wave = threadIdx.x >> 6, lane = threadIdx.x & 63;
    int b = blockIdx.y;
    int n0 = (blockIdx.x * 4 + wave) * 4;
    const float* src = fs + ((size_t)(b * NTOT + n0) * 20) * 9;
    for (int t = lane; t < 720; t += 64) fl[wave][t] = src[t];
    __syncthreads();
    int o = lane;
    if (o >= 42) return;
    double S1 = stats[o], S2 = stats[42 + o];
    double md = S1 / 163840.0;
    float m = (float)md;
    float var = (float)(S2 / 163840.0 - md * md);
    float sqv = sqrtf(var + 1e-5f);
    float gg = g0[o], bb = b0[o];
    float wa0 = wf0[o * 3], wa1 = wf0[o * 3 + 1], wa2 = wf0[o * 3 + 2];
    float wb0 = wd0[o * 3], wb1 = wd0[o * 3 + 1], wb2 = wd0[o * 3 + 2];
    for (int pp = 0; pp < 4; ++pp) {
        float r8[3][8];
        float tl[3][4];
        for (int k = 0; k < 20; ++k) {
            const float* f9 = &fl[wave][(pp * 20 + k) * 9];
            float p0 = wa0 * f9[0] + wa1 * f9[3] + wa2 * f9[6];
            float p1 = wa0 * f9[1] + wa1 * f9[4] + wa2 * f9[7];
            float p2 = wa0 * f9[2] + wa1 * f9[5] + wa2 * f9[8];
            float d0 = wb0 * f9[0] + wb1 * f9[3] + wb2 * f9[6];
            float d1 = wb0 * f9[1] + wb1 * f9[4] + wb2 * f9[7];
            float d2 = wb0 * f9[2] + wb1 * f9[5] + wb2 * f9[8];
            float nrm = sqrtf(p0 * p0 + p1 * p1 + p2 * p2) + 1e-6f;
            float nb = gg * (nrm - m) / sqv + bb;
            p0 = p0 / nrm * nb;
            p1 = p1 / nrm * nb;
            p2 = p2 / nrm * nb;
            float dot = p0 * d0 + p1 * d1 + p2 * d2;
            float r0, r1, r2;
            if (dot >= 0.f) { r0 = p0; r1 = p1; r2 = p2; }
            else {
                float tq = dot / (d0 * d0 + d1 * d1 + d2 * d2 + 1e-6f);
                r0 = p0 - tq * d0; r1 = p1 - tq * d1; r2 = p2 - tq * d2;
            }
            float o0 = 0.2f * p0 + 0.8f * r0;
            float o1 = 0.2f * p1 + 0.8f * r1;
            float o2 = 0.2f * p2 + 0.8f * r2;
            if (k < 8)       { r8[0][k] = o0;       r8[1][k] = o1;       r8[2][k] = o2; }
            else if (k < 16) { r8[0][k-8] += o0;    r8[1][k-8] += o1;    r8[2][k-8] += o2; }
            else             { tl[0][k-16] = o0;    tl[1][k-16] = o1;    tl[2][k-16] = o2; }
        }
        int n = n0 + pp;
        for (int v = 0; v < 3; ++v) {
            float res = ((r8[v][0] + r8[v][1]) + (r8[v][2] + r8[v][3])) +
                        ((r8[v][4] + r8[v][5]) + (r8[v][6] + r8[v][7]));
            res += tl[v][0]; res += tl[v][1]; res += tl[v][2]; res += tl[v][3];
            x0[((size_t)(b * 42 + o) * 3 + v) * NTOT + n] = res / 20.0f;
        }
    }
}

// ============================ generic VN stats ============================
__global__ void vn_stats_kernel(const float* __restrict__ xin,
                                const float* __restrict__ wf,
                                double* __restrict__ stats,
                                int Ci, int Co, int Npts)
{
#pragma clang fp contract(off)
    __shared__ float col[252];
    int b = blockIdx.y;
    int o = threadIdx.x;
    double s = 0.0, s2 = 0.0;
    for (int it = 0; it < 16; ++it) {
        int pt = blockIdx.x * 16 + it;
        __syncthreads();
        for (int t = threadIdx.x; t < Ci * 3; t += blockDim.x)
            col[t] = xin[(size_t)(b * 3 * Ci + t) * Npts + pt];
        __syncthreads();
        if (o < Co) {
            const float* wr = wf + o * Ci;
            float p0 = 0.f, p1 = 0.f, p2 = 0.f;
            for (int c = 0; c < Ci; ++c) {
                float w = wr[c];
                p0 += w * col[3 * c]; p1 += w * col[3 * c + 1]; p2 += w * col[3 * c + 2];
            }
            float nrm = sqrtf(p0 * p0 + p1 * p1 + p2 * p2) + 1e-6f;
            s += (double)nrm; s2 += (double)nrm * (double)nrm;
        }
    }
    if (o < Co) { atomicAdd(&stats[o], s); atomicAdd(&stats[Co + o], s2); }
}

// ============================ VN apply (OPAD thread mapping) ==================
__global__ __launch_bounds__(256)
void vn_apply_kernel(const float* __restrict__ xin,
                     const float* __restrict__ wf,
                     const float* __restrict__ wd,
                     const float* __restrict__ g,
                     const float* __restrict__ bbp,
                     const double* __restrict__ stats,
                     double count, int Ci, int Co, int Npts,
                     int oshift, int nit,
                     float* __restrict__ xout)
{
#pragma clang fp contract(off)
    __shared__ float col[520];
    int t = threadIdx.x;
    int b = blockIdx.y;
    int OPAD = 1 << oshift;
    int PTS = 256 >> oshift;
    int o = t & (OPAD - 1);
    int ps = t >> oshift;
    int Ci3 = Ci * 3;
    int stride = Ci3 + 1;
    float m = 0.f, sqv = 1.f, gg = 0.f, bb = 0.f;
    if (o < Co) {
        double S1 = stats[o], S2 = stats[Co + o];
        double md = S1 / count;
        m = (float)md;
        float var = (float)(S2 / count - md * md);
        sqv = sqrtf(var + 1e-5f);
        gg = g[o]; bb = bbp[o];
    }
    int pt0 = blockIdx.x * (PTS * nit);
    for (int it = 0; it < nit; ++it) {
        int ptbase = pt0 + it * PTS;
        __syncthreads();
        for (int i = t; i < PTS * Ci3; i += 256) {
            int pl = i / Ci3, off = i - pl * Ci3;
            col[pl * stride + off] =
                xin[(size_t)(b * 3 * Ci + off) * Npts + (ptbase + pl)];
        }
        __syncthreads();
        if (o < Co) {
            const float* cl = &col[ps * stride];
            const float* wr = wf + o * Ci;
            const float* wdr = wd + o * Ci;
            float p0 = 0.f, p1 = 0.f, p2 = 0.f, d0 = 0.f, d1 = 0.f, d2 = 0.f;
            for (int c = 0; c < Ci; ++c) {
                float c0 = cl[3 * c], c1 = cl[3 * c + 1], c2 = cl[3 * c + 2];
                float w = wr[c];
                p0 += w * c0; p1 += w * c1; p2 += w * c2;
                float w2 = wdr[c];
                d0 += w2 * c0; d1 += w2 * c1; d2 += w2 * c2;
            }
            float nrm = sqrtf(p0 * p0 + p1 * p1 + p2 * p2) + 1e-6f;
            float nb = gg * (nrm - m) / sqv + bb;
            p0 = p0 / nrm * nb;
            p1 = p1 / nrm * nb;
            p2 = p2 / nrm * nb;
            float dot = p0 * d0 + p1 * d1 + p2 * d2;
            float r0, r1, r2;
            if (dot >= 0.f) { r0 = p0; r1 = p1; r2 = p2; }
            else {
                float tq = dot / (d0 * d0 + d1 * d1 + d2 * d2 + 1e-6f);
                r0 = p0 - tq * d0; r1 = p1 - tq * d1; r2 = p2 - tq * d2;
            }
            int pt = ptbase + ps;
            xout[((size_t)(b * Co + o) * 3 + 0) * Npts + pt] = 0.2f * p0 + 0.8f * r0;
            xout[((size_t)(b * Co + o) * 3 + 1) * Npts + pt] = 0.2f * p1 + 0.8f * r1;
            xout[((size_t)(b * Co + o) * 3 + 2) * Npts + pt] = 0.2f * p2 + 0.8f * r2;
        }
    }
}

// ============================ VN max-pool-down ============================
__global__ void vn_pool_kernel(const float* __restrict__ xin,
                               const int* __restrict__ idx, long long sb, int sq,
                               const float* __restrict__ wp,
                               float* __restrict__ xout,
                               int C, int Np, int Nq)
{
#pragma clang fp contract(off)
    __shared__ float nb[4 * 84 * 3];
    int b = blockIdx.y;
    int q = blockIdx.x;
    const int* ir = idx + b * sb + (long long)q * sq;
    for (int kk = 0; kk < 4; ++kk) {
        int mm = ir[kk];
        for (int t = threadIdx.x; t < C * 3; t += blockDim.x)
            nb[kk * C * 3 + t] = xin[(size_t)(b * 3 * C + t) * Np + mm];
    }
    __syncthreads();
    int o = threadIdx.x;
    if (o >= C) return;
    const float* wr = wp + o * C;
    float best = -3.4e38f;
    int bk = 0;
    for (int kk = 0; kk < 4; ++kk) {
        const float* cl = &nb[kk * C * 3];
        float d0 = 0.f, d1 = 0.f, d2 = 0.f;
        for (int c = 0; c < C; ++c) {
            float w = wr[c];
            d0 += w * cl[3 * c]; d1 += w * cl[3 * c + 1]; d2 += w * cl[3 * c + 2];
        }
        float dot = cl[o * 3] * d0 + cl[o * 3 + 1] * d1 + cl[o * 3 + 2] * d2;
        if (dot > best) { best = dot; bk = kk; }
    }
    const float* cb = &nb[bk * C * 3];
    xout[((size_t)(b * C + o) * 3 + 0) * Nq + q] = cb[o * 3];
    xout[((size_t)(b * C + o) * 3 + 1) * Nq + q] = cb[o * 3 + 1];
    xout[((size_t)(b * C + o) * 3 + 2) * Nq + q] = cb[o * 3 + 2];
}

// ============================ eqv assembly + fused mean partial ==============
__global__ void eqv_kernel(const float* __restrict__ x0, const float* __restrict__ x1,
                           const float* __restrict__ x2, const float* __restrict__ x3,
                           const float* __restrict__ x4,
                           const int* __restrict__ i1, const int* __restrict__ i2,
                           float* __restrict__ out_eqv, float* __restrict__ mfw)
{
    __shared__ float r1[256];
    int n = blockIdx.x * 256 + threadIdx.x;
    int cv = blockIdx.y;
    int b = blockIdx.z;
    int cc = cv / 3, v = cv % 3;
    float val;
    if (cc < 42)
        val = x0[((size_t)(b * 42 + cc) * 3 + v) * NTOT + n];
    else if (cc < 84)
        val = x1[((size_t)(b * 42 + (cc - 42)) * 3 + v) * NTOT + n];
    else if (cc < 168) {
        int m = i1[b * NTOT + n];
        val = x2[((size_t)(b * 84 + (cc - 84)) * 3 + v) * 512 + m];
    } else if (cc < 252) {
        int m = i1[b * NTOT + n];
        val = x3[((size_t)(b * 84 + (cc - 168)) * 3 + v) * 512 + m];
    } else {
        int m = i2[b * NTOT + n];
        val = x4[((size_t)(b * 168 + (cc - 252)) * 3 + v) * 128 + m];
    }
    out_eqv[((size_t)(b * 1260 + cv)) * NTOT + n] = val;
    r1[threadIdx.x] = val;
    __syncthreads();
    for (int off = 128; off; off >>= 1) {
        if ((int)threadIdx.x < off) r1[threadIdx.x] += r1[threadIdx.x + off];
        __syncthreads();
    }
    if (threadIdx.x == 0) atomicAdd(&mfw[b * 1260 + cv], r1[0]);
}

// ============================ mean_feat finalize ============================
__global__ void mf_finalize_kernel(float* __restrict__ mfw, float* __restrict__ out_mf)
{
    int i = blockIdx.x * 256 + threadIdx.x;
    if (i < 5040) {
        float m = mfw[i] / 2048.0f;
        mfw[i] = m;
        out_mf[i] = m;
    }
}

// ============================ z-chain + inv_gl ============================
__global__ void z_kernel(const float* __restrict__ mfw,
                         const float* __restrict__ wv1f, const float* __restrict__ wv1d,
                         const float* __restrict__ wv2f, const float* __restrict__ wv2d,
                         const float* __restrict__ w3,
                         float* __restrict__ invgl_ws, float* __restrict__ out_invgl)
{
#pragma clang fp contract(off)
    __shared__ float mf[1260];
    __shared__ float z1[630];
    __shared__ float z2[252];
    __shared__ float z3[6];
    int b = blockIdx.x;
    int t = threadIdx.x;
    for (int i = t; i < 1260; i += 256) mf[i] = mfw[b * 1260 + i];
    __syncthreads();
    if (t < 210) {
        float p0 = 0.f, p1 = 0.f, p2 = 0.f, d0 = 0.f, d1 = 0.f, d2 = 0.f;
        for (int c = 0; c < 420; ++c) {
            float m0 = mf[3 * c], m1 = mf[3 * c + 1], m2 = mf[3 * c + 2];
            float w = wv1f[t * 420 + c];
            p0 += w * m0; p1 += w * m1; p2 += w * m2;
            float w2 = wv1d[t * 420 + c];
            d0 += w2 * m0; d1 += w2 * m1; d2 += w2 * m2;
        }
        float dot = p0 * d0 + p1 * d1 + p2 * d2;
        float r0, r1, r2;
        if (dot >= 0.f) { r0 = p0; r1 = p1; r2 = p2; }
        else {
            float tq = dot / (d0 * d0 + d1 * d1 + d2 * d2 + 1e-6f);
            r0 = p0 - tq * d0; r1 = p1 - tq * d1; r2 = p2 - tq * d2;
        }
        z1[t * 3]     = 0.2f * p0 + 0.8f * r0;
        z1[t * 3 + 1] = 0.2f * p1 + 0.8f * r1;
        z1[t * 3 + 2] = 0.2f * p2 + 0.8f * r2;
    }
    __syncthreads();
    if (t < 84) {
        float p0 = 0.f, p1 = 0.f, p2 = 0.f, d0 = 0.f, d1 = 0.f, d2 = 0.f;
        for (int c = 0; c < 210; ++c) {
            float m0 = z1[3 * c], m1 = z1[3 * c + 1], m2 = z1[3 * c + 2];
            float w = wv2f[t * 210 + c];
            p0 += w * m0; p1 += w * m1; p2 += w * m2;
            float w2 = wv2d[t * 210 + c];
            d0 += w2 * m0; d1 += w2 * m1; d2 += w2 * m2;
        }
        float dot = p0 * d0 + p1 * d1 + p2 * d2;
        float r0, r1, r2;
        if (dot >= 0.f) { r0 = p0; r1 = p1; r2 = p2; }
        else {
            float tq = dot / (d0 * d0 + d1 * d1 + d2 * d2 + 1e-6f);
            r0 = p0 - tq * d0; r1 = p1 - tq * d1; r2 = p2 - tq * d2;
        }
        z2[t * 3]     = 0.2f * p0 + 0.8f * r0;
        z2[t * 3 + 1] = 0.2f * p1 + 0.8f * r1;
        z2[t * 3 + 2] = 0.2f * p2 + 0.8f * r2;
    }
    __syncthreads();
    if (t < 6) {
        int v = t / 2, kt = t % 2;
        float s = 0.f;
        for (int c = 0; c < 84; ++c) s += z2[c * 3 + v] * w3[kt * 84 + c];
        z3[v * 2 + kt] = s;
    }
    __syncthreads();
    for (int i = t; i < 840; i += 256) {
        int ii = i / 2, kt = i % 2;
        float s = mf[ii * 3] * z3[0 + kt] + mf[ii * 3 + 1] * z3[2 + kt] +
                  mf[ii * 3 + 2] * z3[4 + kt];
        invgl_ws[b * 840 + i] = s;
        out_invgl[b * 840 + i] = s;
    }
}

// ============================ conv1 factored coefficients (wave-per-o) =======
// y1[o,(b,n)] = cb[b,o] + ab[b,o,:]·coord[:,n] + ws1[o,0]*norm[b,n]
// One wave per (b,o): lanes stride K (coalesced ws1 reads), shuffle-reduce.
__global__ __launch_bounds__(256)
void conv1_coef_kernel(const float* __restrict__ ws1,
                       const float* __restrict__ invgl,
                       const float* __restrict__ mfw,
                       const int* __restrict__ cat,
                       float* __restrict__ cb, float* __restrict__ ab,
                       float* __restrict__ w0)
{
#pragma clang fp contract(off)
    int wave = threadIdx.x >> 6, lane = threadIdx.x & 63;
    int o = blockIdx.x * 4 + wave;           // 0..1023
    int b = blockIdx.y;
    const float* wr = ws1 + (size_t)o * 1267;
    float s = 0.f;
    for (int j = lane; j < 840; j += 64)
        s += wr[1 + j] * invgl[b * 840 + j];
    float a0 = 0.f, a1 = 0.f, a2 = 0.f;
    for (int i = lane; i < 420; i += 64) {
        float w = wr[841 + i];
        a0 += w * mfw[b * 1260 + i * 3];
        a1 += w * mfw[b * 1260 + i * 3 + 1];
        a2 += w * mfw[b * 1260 + i * 3 + 2];
    }
    for (int off = 32; off; off >>= 1) {
        s  += __shfl_down(s, off);
        a0 += __shfl_down(a0, off);
        a1 += __shfl_down(a1, off);
        a2 += __shfl_down(a2, off);
    }
    if (lane == 0) {
        cb[b * 1024 + o] = s + wr[1261 + cat[b]];
        ab[((size_t)(b * 1024 + o)) * 3 + 0] = a0;
        ab[((size_t)(b * 1024 + o)) * 3 + 1] = a1;
        ab[((size_t)(b * 1024 + o)) * 3 + 2] = a2;
        if (b == 0) w0[o] = wr[0];
    }
}

// ============================ y1 generator (replaces gemm1) ==================
__global__ __launch_bounds__(256)
void y1_gen_kernel(const float* __restrict__ cb, const float* __restrict__ ab,
                   const float* __restrict__ w0, const float* __restrict__ coord,
                   const float* __restrict__ normv, float* __restrict__ y1t)
{
#pragma clang fp contract(off)
    int pt = blockIdx.x;                // 0..8191
    int b = pt >> 11, n = pt & 2047;
    float cx = coord[(b * 3 + 0) * NTOT + n];
    float cy = coord[(b * 3 + 1) * NTOT + n];
    float cz = coord[(b * 3 + 2) * NTOT + n];
    float nr = normv[b * NTOT + n];
    for (int it = 0; it < 4; ++it) {
        int o = it * 256 + threadIdx.x;
        size_t bo = (size_t)(b * 1024 + o);
        float v = cb[bo] + ab[bo * 3] * cx + ab[bo * 3 + 1] * cy +
                  ab[bo * 3 + 2] * cz + w0[o] * nr;
        y1t[(size_t)pt * 1024 + o] = v;
    }
}

// ============================ weight convert f32 -> bf16 ============================
__global__ void wconv_kernel(const float* __restrict__ src, unsigned short* __restrict__ dst,
                             int Msrc, int Ksrc, int Kpad)
{
    int k = blockIdx.x * 256 + threadIdx.x;
    int o = blockIdx.y;
    float v = (o < Msrc && k < Ksrc) ? src[(size_t)o * Ksrc + k] : 0.f;
    dst[(size_t)o * Kpad + k] = f2b(v);
}

// ============================ MFMA GEMM ============================
__global__ __launch_bounds__(256)
void gemm_mfma_kernel(const unsigned short* __restrict__ A,
                      const unsigned short* __restrict__ Bw,
                      float* __restrict__ C, int K, int Mreal)
{
    __shared__ __align__(16) unsigned short Al[128 * 40];
    __shared__ __align__(16) unsigned short Bl[128 * 40];
    int t = threadIdx.x;
    int r0 = blockIdx.x * 128;
    int c0 = blockIdx.y * 128;
    int w = t >> 6, l = t & 63;
    int wm = w & 1, wn = w >> 1;
    int lm = l & 15, lq = l >> 4;
    f32x4 acc[4][4] = {};
    for (int k0 = 0; k0 < K; k0 += 32) {
        for (int half = 0; half < 2; ++half) {
            int ch = t + half * 256;
            int row = ch >> 2, kc = ch & 3;
            *(uint4*)&Al[row * 40 + kc * 8] =
                *(const uint4*)&A[(size_t)(r0 + row) * K + k0 + kc * 8];
            *(uint4*)&Bl[row * 40 + kc * 8] =
                *(const uint4*)&Bw[(size_t)(c0 + row) * K + k0 + kc * 8];
        }
        __syncthreads();
        bf16x8 af[4], bfr[4];
#pragma unroll
        for (int i = 0; i < 4; ++i)
            af[i] = *(const bf16x8*)&Al[(wm * 64 + i * 16 + lm) * 40 + lq * 8];
#pragma unroll
        for (int j = 0; j < 4; ++j)
            bfr[j] = *(const bf16x8*)&Bl[(wn * 64 + j * 16 + lm) * 40 + lq * 8];
#pragma unroll
        for (int i = 0; i < 4; ++i)
#pragma unroll
            for (int j = 0; j < 4; ++j)
                acc[i][j] = __builtin_amdgcn_mfma_f32_16x16x32_bf16(af[i], bfr[j],
                                                                    acc[i][j], 0, 0, 0);
        __syncthreads();
    }
#pragma unroll
    for (int i = 0; i < 4; ++i) {
#pragma unroll
        for (int j = 0; j < 4; ++j) {
            int col = c0 + wn * 64 + j * 16 + lm;
            if (col < Mreal) {
                int rbase = r0 + wm * 64 + i * 16 + lq * 4;
#pragma unroll
                for (int r = 0; r < 4; ++r)
                    C[(size_t)(rbase + r) * Mreal + col] = acc[i][j][r];
            }
        }
    }
}

// ============================ conv BN stats ============================
__global__ void cstatsT_kernel(const float* __restrict__ Ct, float* __restrict__ st,
                               int Mreal)
{
    __shared__ float l1[256], l2[256];
    int t = threadIdx.x;
    int o = blockIdx.x * 64 + (t & 63);
    int r0 = blockIdx.y * 128 + (t >> 6) * 32;
    float s = 0.f, s2 = 0.f;
    if (o < Mreal) {
        for (int rr = 0; rr < 32; ++rr) {
            float v = Ct[(size_t)(r0 + rr) * Mreal + o];
            s += v; s2 += v * v;
        }
    }
    l1[t] = s; l2[t] = s2;
    __syncthreads();
    if (t < 64 && o < Mreal) {
        s  = l1[t] + l1[t + 64] + l1[t + 128] + l1[t + 192];
        s2 = l2[t] + l2[t + 64] + l2[t + 128] + l2[t + 192];
        atomicAdd(&st[o], s);
        atomicAdd(&st[Mreal + o], s2);
    }
}

// ============================ BN+ReLU -> bf16 ============================
__global__ void bnreluT_kernel(const float* __restrict__ Ct, const float* __restrict__ st,
                               const float* __restrict__ g, const float* __restrict__ be,
                               unsigned short* __restrict__ outb, int M, int maskM)
{
#pragma clang fp contract(off)
    size_t idx = (size_t)blockIdx.x * 256 + threadIdx.x;
    int o = (int)(idx & (size_t)maskM);
    float m = st[o] * (1.f / 8192.f);
    float var = st[M + o] * (1.f / 8192.f) - m * m;
    float sqv = sqrtf(var + 1e-5f);
    float v = g[o] * (Ct[idx] - m) / sqv + be[o];
    outb[idx] = f2b(v > 0.f ? v : 0.f);
}

// ============================ final BN+ReLU + transpose ============================
__global__ void bnrelu_outT_kernel(const float* __restrict__ Ct, const float* __restrict__ st,
                                   const float* __restrict__ g, const float* __restrict__ be,
                                   float* __restrict__ outinv)
{
#pragma clang fp contract(off)
    __shared__ float tile[64][65];
    int t = threadIdx.x;
    int r0 = blockIdx.x * 64;
    int o0 = blockIdx.y * 64;
    int b = r0 >> 11, n0 = r0 & 2047;
    int oi = t & 63;
    int o = o0 + oi;
    float m = 0.f, sqv = 1.f, gg = 0.f, bb = 0.f;
    if (o < 420) {
        m = st[o] * (1.f / 8192.f);
        float var = st[420 + o] * (1.f / 8192.f) - m * m;
        sqv = sqrtf(var + 1e-5f);
        gg = g[o]; bb = be[o];
    }
    for (int it = 0; it < 16; ++it) {
        int rr = it * 4 + (t >> 6);
        float v = 0.f;
        if (o < 420) {
            v = gg * (Ct[(size_t)(r0 + rr) * 420 + o] - m) / sqv + bb;
            v = v > 0.f ? v : 0.f;
        }
        tile[rr][oi] = v;
    }
    __syncthreads();
    for (int it = 0; it < 16; ++it) {
        int oc = it * 4 + (t >> 6);
        int oo = o0 + oc;
        if (oo < 420)
            outinv[((size_t)(b * 420 + oo)) * 2048 + n0 + (t & 63)] = tile[t & 63][oc];
    }
}

// ============================ launch ============================
extern "C" void kernel_launch(void* const* d_in, const int* in_sizes, int n_in,
                              void* d_out, int out_size, void* d_ws, size_t ws_size,
                              hipStream_t stream)
{
    (void)in_sizes; (void)n_in; (void)out_size; (void)ws_size;
    const float* xc   = (const float*)d_in[0];
    const float* normv= (const float*)d_in[1];
    const int*   cat  = (const int*)d_in[2];
    const float* wf0  = (const float*)d_in[3];
    const float* wd0  = (const float*)d_in[4];
    const float* g0   = (const float*)d_in[5];
    const float* b0   = (const float*)d_in[6];
    const float* wf1  = (const float*)d_in[7];
    const float* wd1  = (const float*)d_in[8];
    const float* g1   = (const float*)d_in[9];
    const float* b1   = (const float*)d_in[10];
    const float* wp1  = (const float*)d_in[11];
    const float* wf2  = (const float*)d_in[12];
    const float* wd2  = (const float*)d_in[13];
    const float* g2   = (const float*)d_in[14];
    const float* b2   = (const float*)d_in[15];
    const float* wf3  = (const float*)d_in[16];
    const float* wd3  = (const float*)d_in[17];
    const float* g3   = (const float*)d_in[18];
    const float* b3   = (const float*)d_in[19];
    const float* wp2  = (const float*)d_in[20];
    const float* wf4  = (const float*)d_in[21];
    const float* wd4  = (const float*)d_in[22];
    const float* g4   = (const float*)d_in[23];
    const float* b4   = (const float*)d_in[24];
    const float* wv1f = (const float*)d_in[25];
    const float* wv1d = (const float*)d_in[26];
    const float* wv2f = (const float*)d_in[27];
    const float* wv2d = (const float*)d_in[28];
    const float* w3   = (const float*)d_in[29];
    const float* ws1  = (const float*)d_in[30];
    const float* sg1  = (const float*)d_in[32];
    const float* sb1  = (const float*)d_in[33];
    const float* ws2  = (const float*)d_in[34];
    const float* sg2  = (const float*)d_in[36];
    const float* sb2  = (const float*)d_in[37];
    const float* ws3  = (const float*)d_in[38];
    const float* sg3  = (const float*)d_in[40];
    const float* sb3  = (const float*)d_in[41];

    float* ws = (float*)d_ws;
    float* out = (float*)d_out;

    int*    idx20 = (int*)(ws + WS_IDX20);
    float*  fs    = ws + WS_FS;
    float*  x0    = ws + WS_X0;
    float*  x1    = ws + WS_X1;
    float*  xm2   = ws + WS_XM2;
    float*  x2    = ws + WS_X2;
    float*  x3    = ws + WS_X3;
    int*    idx42 = (int*)(ws + WS_IDX42);
    float*  xm4   = ws + WS_XM4;
    float*  x4    = ws + WS_X4;
    int*    i1p   = (int*)(ws + WS_I1);
    int*    i2p   = (int*)(ws + WS_I2);
    float*  mfw   = ws + WS_MF;
    float*  invgl = ws + WS_INVGL;
    double* st    = (double*)(ws + WS_STATS);
    float*  cst   = ws + WS_CST;
    float*  cb    = ws + WS_CB;
    float*  ab    = ws + WS_AB;
    float*  w0    = ws + WS_W0;
    unsigned short* w2b  = (unsigned short*)(ws + WS_W2B);
    unsigned short* w3b  = (unsigned short*)(ws + WS_W3B);
    float*  y1t   = ws + WS_Y1T;
    unsigned short* y1b  = (unsigned short*)(ws + WS_Y1B);
    float*  y2t   = ws + WS_Y2T;
    unsigned short* y2b  = (unsigned short*)(ws + WS_Y2B);
    float*  y3t   = ws + WS_Y3T;

    hipMemsetAsync((void*)st, 0, 840 * sizeof(double), stream);
    hipMemsetAsync((void*)cst, 0, 3912 * sizeof(float), stream);
    hipMemsetAsync((void*)mfw, 0, 5040 * sizeof(float), stream);

    // weight conversions (independent)
    wconv_kernel<<<dim3(4, 512), 256, 0, stream>>>(ws2, w2b, 512, 1024, 1024);
    wconv_kernel<<<dim3(2, 512), 256, 0, stream>>>(ws3, w3b, 420, 512, 512);

    // KNN-20 (also the knn-4 prefix for pool stage 1)
    knn_reg_kernel<32, 20><<<dim3(512, 4), 256, 0, stream>>>(xc, 1, 1, idx20, 2048);
    surf_build_kernel<<<640, 256, 0, stream>>>(xc, idx20, fs);

    // stage 0
    stats0_kernel<<<dim3(128, 4), 256, 0, stream>>>(fs, wf0, st + ST0_OFF);
    apply0_kernel<<<dim3(128, 4), 256, 0, stream>>>(fs, wf0, wd0, g0, b0,
                                                    st + ST0_OFF, x0);

    // stage 1
    vn_stats_kernel<<<dim3(128, 4), 256, 0, stream>>>(x0, wf1, st + ST1_OFF, 42, 42, 2048);
    vn_apply_kernel<<<dim3(256, 4), 256, 0, stream>>>(x0, wf1, wd1, g1, b1, st + ST1_OFF,
                                                      8192.0, 42, 42, 2048, 6, 2, x1);

    // pool 1
    vn_pool_kernel<<<dim3(512, 4), 256, 0, stream>>>(x1, idx20, 40960LL, 80, wp1, xm2,
                                                     42, 2048, 512);
    // stage 2
    vn_stats_kernel<<<dim3(32, 4), 256, 0, stream>>>(xm2, wf2, st + ST2_OFF, 42, 84, 512);
    vn_apply_kernel<<<dim3(128, 4), 256, 0, stream>>>(xm2, wf2, wd2, g2, b2, st + ST2_OFF,
                                                      2048.0, 42, 84, 512, 7, 2, x2);
    // stage 3
    vn_stats_kernel<<<dim3(32, 4), 256, 0, stream>>>(x2, wf3, st + ST3_OFF, 84, 84, 512);
    vn_apply_kernel<<<dim3(128, 4), 256, 0, stream>>>(x2, wf3, wd3, g3, b3, st + ST3_OFF,
                                                      2048.0, 84, 84, 512, 7, 2, x3);

    // knn-4 on coord2 (cands stride 4, queries stride 16)
    knn_reg_kernel<8, 4><<<dim3(32, 4), 256, 0, stream>>>(xc, 4, 16, idx42, 128);
    vn_pool_kernel<<<dim3(128, 4), 256, 0, stream>>>(x3, idx42, 512LL, 4, wp2, xm4,
                                                     84, 512, 128);
    // stage 4
    vn_stats_kernel<<<dim3(8, 4), 256, 0, stream>>>(xm4, wf4, st + ST4_OFF, 84, 168, 128);
    vn_apply_kernel<<<dim3(64, 4), 256, 0, stream>>>(xm4, wf4, wd4, g4, b4, st + ST4_OFF,
                                                     512.0, 84, 168, 128, 8, 2, x4);

    // nearest-neighbor upsample indices
    nearest_reg_kernel<8><<<dim3(512, 4), 256, 0, stream>>>(xc, 4, i1p);
    nearest_reg_kernel<2><<<dim3(512, 4), 256, 0, stream>>>(xc, 16, i2p);

    // eqv (output 0) with fused mean partials; finalize mean (output 1)
    eqv_kernel<<<dim3(8, 1260, 4), 256, 0, stream>>>(x0, x1, x2, x3, x4, i1p, i2p,
                                                     out + OUT_EQV, mfw);
    mf_finalize_kernel<<<20, 256, 0, stream>>>(mfw, out + OUT_MF);

    // z chain + inv_gl (output 3)
    z_kernel<<<4, 256, 0, stream>>>(mfw, wv1f, wv1d, wv2f, wv2d, w3, invgl,
                                    out + OUT_INVGL);

    // invariant branch: conv1 factored (wave-per-(b,o), coalesced)
    conv1_coef_kernel<<<dim3(256, 4), 256, 0, stream>>>(ws1, invgl, mfw, cat, cb, ab, w0);
    y1_gen_kernel<<<8192, 256, 0, stream>>>(cb, ab, w0, xc, normv, y1t);
    cstatsT_kernel<<<dim3(16, 64), 256, 0, stream>>>(y1t, cst + CST1_OFF, 1024);
    bnreluT_kernel<<<32768, 256, 0, stream>>>(y1t, cst + CST1_OFF, sg1, sb1, y1b,
                                              1024, 1023);

    gemm_mfma_kernel<<<dim3(64, 4), 256, 0, stream>>>(y1b, w2b, y2t, 1024, 512);
    cstatsT_kernel<<<dim3(8, 64), 256, 0, stream>>>(y2t, cst + CST2_OFF, 512);
    bnreluT_kernel<<<16384, 256, 0, stream>>>(y2t, cst + CST2_OFF, sg2, sb2, y2b,
                                              512, 511);

    gemm_mfma_kernel<<<dim3(64, 4), 256, 0, stream>>>(y2b, w3b, y3t, 512, 420);
    cstatsT_kernel<<<dim3(7, 64), 256, 0, stream>>>(y3t, cst + CST3_OFF, 420);
    bnrelu_outT_kernel<<<dim3(128, 7), 256, 0, stream>>>(y3t, cst + CST3_OFF, sg3, sb3,
                                                         out + OUT_INV);
}

// Round 7
// 775.610 us; speedup vs baseline: 2.4567x; 1.0660x over previous
//
#include <hip/hip_runtime.h>
#include <hip/hip_bf16.h>
#include <cstdint>
#include <cstddef>

#define NTOT 2048
#define BTOT 4

typedef short bf16x8 __attribute__((ext_vector_type(8)));
typedef float f32x4 __attribute__((ext_vector_type(4)));

__device__ inline unsigned short f2b(float v) {
    __hip_bfloat16 h = __float2bfloat16(v);
    return *reinterpret_cast<unsigned short*>(&h);
}

// ---------------- workspace layout (float-element offsets) ----------------
static const size_t WS_IDX20 = 0;                       // int[163840]
static const size_t WS_FS    = 163840;                  // float[1474560]
static const size_t WS_X0    = 1638400;                 // float[2064384] (B,42,3,2048)
static const size_t WS_X1    = 3702784;                 // float[2064384]
static const size_t WS_XM2   = 5767168;                 // float[258048]
static const size_t WS_X2    = 6025216;                 // float[516096]
static const size_t WS_X3    = 6541312;                 // float[516096]
static const size_t WS_IDX42 = 7057408;                 // int[2048]
static const size_t WS_XM4   = 7059456;                 // float[129024]
static const size_t WS_X4    = 7188480;                 // float[258048]
static const size_t WS_I1    = 7446528;                 // int[8192]
static const size_t WS_I2    = 7454720;                 // int[8192]
static const size_t WS_MF    = 7462912;                 // float[5040]
static const size_t WS_INVGL = 7467952;                 // float[3360]
static const size_t WS_STATS = 7471312;                 // double[840] (1680 fl slots)
static const size_t WS_CST   = 7472992;                 // float[3912] conv bn sums
// conv1 factored coefficients + z scratch (old invT region; all dead before
// the y2t overlay (gemm2 output) is written)
static const size_t WS_CB    = 7480320;                 // float[4096]   cb[b][o]
static const size_t WS_AB    = 7484416;                 // float[12288]  ab[b][o][3]
static const size_t WS_W0    = 7496704;                 // float[1024]   ws1[:,0]
static const size_t WS_Z1    = 7497728;                 // float[2520]   z1[b][210*3]
static const size_t WS_Z2    = 7500288;                 // float[1008]   z2[b][84*3]
static const size_t WS_W2B   = 13378560;                // ushort[512*1024]
static const size_t WS_W3B   = 13640704;                // ushort[512*512]
static const size_t WS_Y1T   = 13771776;                // float[8192*1024]
static const size_t WS_Y1B   = 0;                       // ushort overlay
static const size_t WS_Y2T   = 7480320;                 // float overlay (CB/AB/Z dead)
static const size_t WS_Y2B   = 4194304;                 // ushort overlay
static const size_t WS_Y3T   = WS_Y1T;                  // float overlay

#define ST0_OFF 0
#define ST1_OFF 84
#define ST2_OFF 168
#define ST3_OFF 336
#define ST4_OFF 504
#define CST1_OFF 0
#define CST2_OFF 2048
#define CST3_OFF 3072

#define OUT_EQV   0
#define OUT_MF    10321920
#define OUT_INV   10326960
#define OUT_INVGL 13767600

// ============================ KNN v3 (cached quarter maxima) ==================
template <int SLOTS, int K>
__global__ __launch_bounds__(256)
void knn_reg_kernel(const float* __restrict__ coord, int cand_stride, int q_stride,
                    int* __restrict__ out_idx, int q_cnt)
{
#pragma clang fp contract(off)
    constexpr int Q = SLOTS / 8;
    int b = blockIdx.y;
    int wave = threadIdx.x >> 6, lane = threadIdx.x & 63;
    int q = blockIdx.x * 4 + wave;
    if (q >= q_cnt) return;
    int nq = q * q_stride;
    float qx = coord[(b * 3 + 0) * NTOT + nq];
    float qy = coord[(b * 3 + 1) * NTOT + nq];
    float qz = coord[(b * 3 + 2) * NTOT + nq];
    float xxq = qx * qx + qy * qy + qz * qz;
    float v[SLOTS];
#pragma unroll
    for (int j = 0; j < SLOTS; ++j) {
        int mo = (lane + 64 * j) * cand_stride;
        float cx = coord[(b * 3 + 0) * NTOT + mo];
        float cy = coord[(b * 3 + 1) * NTOT + mo];
        float cz = coord[(b * 3 + 2) * NTOT + mo];
        float inner = qx * cx + qy * cy + qz * cz;
        float xxc = cx * cx + cy * cy + cz * cz;
        v[j] = (2.0f * inner - xxq) - xxc;
    }
    float qv[Q]; int qj[Q];
#pragma unroll
    for (int qq = 0; qq < Q; ++qq) {
        float nv = v[qq * 8]; int nj = qq * 8;
#pragma unroll
        for (int j = 1; j < 8; ++j)
            if (v[qq * 8 + j] > nv) { nv = v[qq * 8 + j]; nj = qq * 8 + j; }
        qv[qq] = nv; qj[qq] = nj;
    }
#pragma clang loop unroll(disable)
    for (int kk = 0; kk < K; ++kk) {
        float bv = qv[0]; int bj = qj[0];
#pragma unroll
        for (int qq = 1; qq < Q; ++qq)
            if (qv[qq] > bv) { bv = qv[qq]; bj = qj[qq]; }
        int bm = lane + 64 * bj;
        for (int off = 32; off; off >>= 1) {
            float ov = __shfl_down(bv, off);
            int   om = __shfl_down(bm, off);
            if (ov > bv || (ov == bv && om < bm)) { bv = ov; bm = om; }
        }
        int m_win = __builtin_amdgcn_readfirstlane(bm);
        if (lane == 0)
            out_idx[((size_t)(b * q_cnt) + q) * K + kk] = m_win;
        int w_slot = m_win >> 6;
        bool isw = (lane == (m_win & 63));
#pragma unroll
        for (int qq = 0; qq < Q; ++qq) {
            if (qq == (w_slot >> 3)) {
#pragma unroll
                for (int j = 0; j < 8; ++j)
                    if (qq * 8 + j == w_slot)
                        v[qq * 8 + j] = isw ? -3.4e38f : v[qq * 8 + j];
                float nv = v[qq * 8]; int nj = qq * 8;
#pragma unroll
                for (int j = 1; j < 8; ++j)
                    if (v[qq * 8 + j] > nv) { nv = v[qq * 8 + j]; nj = qq * 8 + j; }
                qv[qq] = nv; qj[qq] = nj;
            }
        }
    }
}

// ============================ nearest (register argmin, wave-per-query) ======
template <int SLOTS>
__global__ __launch_bounds__(256)
void nearest_reg_kernel(const float* __restrict__ coord, int cand_stride,
                        int* __restrict__ out)
{
#pragma clang fp contract(off)
    int b = blockIdx.y;
    int wave = threadIdx.x >> 6, lane = threadIdx.x & 63;
    int n = blockIdx.x * 4 + wave;
    float qx = coord[(b * 3 + 0) * NTOT + n];
    float qy = coord[(b * 3 + 1) * NTOT + n];
    float qz = coord[(b * 3 + 2) * NTOT + n];
    float tt = qx * qx + qy * qy + qz * qz;
    float v[SLOTS];
#pragma unroll
    for (int j = 0; j < SLOTS; ++j) {
        int mo = (lane + 64 * j) * cand_stride;
        float cx = coord[(b * 3 + 0) * NTOT + mo];
        float cy = coord[(b * 3 + 1) * NTOT + mo];
        float cz = coord[(b * 3 + 2) * NTOT + mo];
        float inner = qx * cx + qy * cy + qz * cz;
        float ss = cx * cx + cy * cy + cz * cz;
        v[j] = (tt - 2.0f * inner) + ss;
    }
    float bv = v[0];
    int bj = 0;
#pragma unroll
    for (int j = 1; j < SLOTS; ++j)
        if (v[j] < bv) { bv = v[j]; bj = j; }
    int bm = lane + 64 * bj;
    for (int off = 32; off; off >>= 1) {
        float ov = __shfl_down(bv, off);
        int   om = __shfl_down(bm, off);
        if (ov < bv || (ov == bv && om < bm)) { bv = ov; bm = om; }
    }
    if (lane == 0) out[b * NTOT + n] = bm;
}

// ============================ surface feature build ============================
__global__ void surf_build_kernel(const float* __restrict__ coord,
                                  const int* __restrict__ idx20,
                                  float* __restrict__ fs)
{
#pragma clang fp contract(off)
    int t = blockIdx.x * 256 + threadIdx.x;
    if (t >= BTOT * NTOT * 20) return;
    int n = (t / 20) & (NTOT - 1);
    int b = t / (20 * NTOT);
    int m = idx20[t];
    float cx = coord[(b * 3 + 0) * NTOT + n];
    float cy = coord[(b * 3 + 1) * NTOT + n];
    float cz = coord[(b * 3 + 2) * NTOT + n];
    float nx = coord[(b * 3 + 0) * NTOT + m];
    float ny = coord[(b * 3 + 1) * NTOT + m];
    float nz = coord[(b * 3 + 2) * NTOT + m];
    float* f9 = fs + (size_t)t * 9;
    f9[0] = nx - cx; f9[1] = ny - cy; f9[2] = nz - cz;
    f9[3] = cx;      f9[4] = cy;      f9[5] = cz;
    f9[6] = ny * cz - nz * cy;
    f9[7] = nz * cx - nx * cz;
    f9[8] = nx * cy - ny * cx;
}

// ============================ stage-0 stats / apply (4 waves x 4 pts) ========
__global__ __launch_bounds__(256)
void stats0_kernel(const float* __restrict__ fs,
                   const float* __restrict__ wf0,
                   double* __restrict__ stats)
{
#pragma clang fp contract(off)
    __shared__ float fl[4][720];
    __shared__ double red[4][84];
    int wave = threadIdx.x >> 6, lane = threadIdx.x & 63;
    int b = blockIdx.y;
    int n0 = (blockIdx.x * 4 + wave) * 4;
    const float* src = fs + ((size_t)(b * NTOT + n0) * 20) * 9;
    for (int t = lane; t < 720; t += 64) fl[wave][t] = src[t];
    __syncthreads();
    int o = lane;
    if (o < 42) {
        float w0 = wf0[o * 3], w1 = wf0[o * 3 + 1], w2 = wf0[o * 3 + 2];
        double s = 0.0, s2 = 0.0;
        for (int i = 0; i < 80; ++i) {
            const float* f9 = &fl[wave][i * 9];
            float p0 = w0 * f9[0] + w1 * f9[3] + w2 * f9[6];
            float p1 = w0 * f9[1] + w1 * f9[4] + w2 * f9[7];
            float p2 = w0 * f9[2] + w1 * f9[5] + w2 * f9[8];
            float nrm = sqrtf(p0 * p0 + p1 * p1 + p2 * p2) + 1e-6f;
            s += (double)nrm; s2 += (double)nrm * (double)nrm;
        }
        red[wave][o] = s;
        red[wave][42 + o] = s2;
    }
    __syncthreads();
    int t = threadIdx.x;
    if (t < 84)
        atomicAdd(&stats[t], red[0][t] + red[1][t] + red[2][t] + red[3][t]);
}

__global__ __launch_bounds__(256)
void apply0_kernel(const float* __restrict__ fs,
                   const float* __restrict__ wf0,
                   const float* __restrict__ wd0,
                   const float* __restrict__ g0,
                   const float* __restrict__ b0,
                   const double* __restrict__ stats,
                   float* __restrict__ x0)
{
#pragma clang fp contract(off)
    __shared__ float fl[4][720];
    int wave = threadIdx.x >> 6, lane = threadIdx.x & 63;
    int b = blockIdx.y;
    int n0 = (blockIdx.x * 4 + wave) * 4;
    const float* src = fs + ((size_t)(b * NTOT + n0) * 20) * 9;
    for (int t = lane; t < 720; t += 64) fl[wave][t] = src[t];
    __syncthreads();
    int o = lane;
    if (o >= 42) return;
    double S1 = stats[o], S2 = stats[42 + o];
    double md = S1 / 163840.0;
    float m = (float)md;
    float var = (float)(S2 / 163840.0 - md * md);
    float sqv = sqrtf(var + 1e-5f);
    float gg = g0[o], bb = b0[o];
    float wa0 = wf0[o * 3], wa1 = wf0[o * 3 + 1], wa2 = wf0[o * 3 + 2];
    float wb0 = wd0[o * 3], wb1 = wd0[o * 3 + 1], wb2 = wd0[o * 3 + 2];
    for (int pp = 0; pp < 4; ++pp) {
        float r8[3][8];
        float tl[3][4];
        for (int k = 0; k < 20; ++k) {
            const float* f9 = &fl[wave][(pp * 20 + k) * 9];
            float p0 = wa0 * f9[0] + wa1 * f9[3] + wa2 * f9[6];
            float p1 = wa0 * f9[1] + wa1 * f9[4] + wa2 * f9[7];
            float p2 = wa0 * f9[2] + wa1 * f9[5] + wa2 * f9[8];
            float d0 = wb0 * f9[0] + wb1 * f9[3] + wb2 * f9[6];
            float d1 = wb0 * f9[1] + wb1 * f9[4] + wb2 * f9[7];
            float d2 = wb0 * f9[2] + wb1 * f9[5] + wb2 * f9[8];
            float nrm = sqrtf(p0 * p0 + p1 * p1 + p2 * p2) + 1e-6f;
            float nb = gg * (nrm - m) / sqv + bb;
            p0 = p0 / nrm * nb;
            p1 = p1 / nrm * nb;
            p2 = p2 / nrm * nb;
            float dot = p0 * d0 + p1 * d1 + p2 * d2;
            float r0, r1, r2;
            if (dot >= 0.f) { r0 = p0; r1 = p1; r2 = p2; }
            else {
                float tq = dot / (d0 * d0 + d1 * d1 + d2 * d2 + 1e-6f);
                r0 = p0 - tq * d0; r1 = p1 - tq * d1; r2 = p2 - tq * d2;
            }
            float o0 = 0.2f * p0 + 0.8f * r0;
            float o1 = 0.2f * p1 + 0.8f * r1;
            float o2 = 0.2f * p2 + 0.8f * r2;
            if (k < 8)       { r8[0][k] = o0;       r8[1][k] = o1;       r8[2][k] = o2; }
            else if (k < 16) { r8[0][k-8] += o0;    r8[1][k-8] += o1;    r8[2][k-8] += o2; }
            else             { tl[0][k-16] = o0;    tl[1][k-16] = o1;    tl[2][k-16] = o2; }
        }
        int n = n0 + pp;
        for (int v = 0; v < 3; ++v) {
            float res = ((r8[v][0] + r8[v][1]) + (r8[v][2] + r8[v][3])) +
                        ((r8[v][4] + r8[v][5]) + (r8[v][6] + r8[v][7]));
            res += tl[v][0]; res += tl[v][1]; res += tl[v][2]; res += tl[v][3];
            x0[((size_t)(b * 42 + o) * 3 + v) * NTOT + n] = res / 20.0f;
        }
    }
}

// ============================ generic VN stats ============================
__global__ void vn_stats_kernel(const float* __restrict__ xin,
                                const float* __restrict__ wf,
                                double* __restrict__ stats,
                                int Ci, int Co, int Npts)
{
#pragma clang fp contract(off)
    __shared__ float col[252];
    int b = blockIdx.y;
    int o = threadIdx.x;
    double s = 0.0, s2 = 0.0;
    for (int it = 0; it < 16; ++it) {
        int pt = blockIdx.x * 16 + it;
        __syncthreads();
        for (int t = threadIdx.x; t < Ci * 3; t += blockDim.x)
            col[t] = xin[(size_t)(b * 3 * Ci + t) * Npts + pt];
        __syncthreads();
        if (o < Co) {
            const float* wr = wf + o * Ci;
            float p0 = 0.f, p1 = 0.f, p2 = 0.f;
            for (int c = 0; c < Ci; ++c) {
                float w = wr[c];
                p0 += w * col[3 * c]; p1 += w * col[3 * c + 1]; p2 += w * col[3 * c + 2];
            }
            float nrm = sqrtf(p0 * p0 + p1 * p1 + p2 * p2) + 1e-6f;
            s += (double)nrm; s2 += (double)nrm * (double)nrm;
        }
    }
    if (o < Co) { atomicAdd(&stats[o], s); atomicAdd(&stats[Co + o], s2); }
}

// ============================ VN apply (OPAD thread mapping) ==================
__global__ __launch_bounds__(256)
void vn_apply_kernel(const float* __restrict__ xin,
                     const float* __restrict__ wf,
                     const float* __restrict__ wd,
                     const float* __restrict__ g,
                     const float* __restrict__ bbp,
                     const double* __restrict__ stats,
                     double count, int Ci, int Co, int Npts,
                     int oshift, int nit,
                     float* __restrict__ xout)
{
#pragma clang fp contract(off)
    __shared__ float col[520];
    int t = threadIdx.x;
    int b = blockIdx.y;
    int OPAD = 1 << oshift;
    int PTS = 256 >> oshift;
    int o = t & (OPAD - 1);
    int ps = t >> oshift;
    int Ci3 = Ci * 3;
    int stride = Ci3 + 1;
    float m = 0.f, sqv = 1.f, gg = 0.f, bb = 0.f;
    if (o < Co) {
        double S1 = stats[o], S2 = stats[Co + o];
        double md = S1 / count;
        m = (float)md;
        float var = (float)(S2 / count - md * md);
        sqv = sqrtf(var + 1e-5f);
        gg = g[o]; bb = bbp[o];
    }
    int pt0 = blockIdx.x * (PTS * nit);
    for (int it = 0; it < nit; ++it) {
        int ptbase = pt0 + it * PTS;
        __syncthreads();
        for (int i = t; i < PTS * Ci3; i += 256) {
            int pl = i / Ci3, off = i - pl * Ci3;
            col[pl * stride + off] =
                xin[(size_t)(b * 3 * Ci + off) * Npts + (ptbase + pl)];
        }
        __syncthreads();
        if (o < Co) {
            const float* cl = &col[ps * stride];
            const float* wr = wf + o * Ci;
            const float* wdr = wd + o * Ci;
            float p0 = 0.f, p1 = 0.f, p2 = 0.f, d0 = 0.f, d1 = 0.f, d2 = 0.f;
            for (int c = 0; c < Ci; ++c) {
                float c0 = cl[3 * c], c1 = cl[3 * c + 1], c2 = cl[3 * c + 2];
                float w = wr[c];
                p0 += w * c0; p1 += w * c1; p2 += w * c2;
                float w2 = wdr[c];
                d0 += w2 * c0; d1 += w2 * c1; d2 += w2 * c2;
            }
            float nrm = sqrtf(p0 * p0 + p1 * p1 + p2 * p2) + 1e-6f;
            float nb = gg * (nrm - m) / sqv + bb;
            p0 = p0 / nrm * nb;
            p1 = p1 / nrm * nb;
            p2 = p2 / nrm * nb;
            float dot = p0 * d0 + p1 * d1 + p2 * d2;
            float r0, r1, r2;
            if (dot >= 0.f) { r0 = p0; r1 = p1; r2 = p2; }
            else {
                float tq = dot / (d0 * d0 + d1 * d1 + d2 * d2 + 1e-6f);
                r0 = p0 - tq * d0; r1 = p1 - tq * d1; r2 = p2 - tq * d2;
            }
            int pt = ptbase + ps;
            xout[((size_t)(b * Co + o) * 3 + 0) * Npts + pt] = 0.2f * p0 + 0.8f * r0;
            xout[((size_t)(b * Co + o) * 3 + 1) * Npts + pt] = 0.2f * p1 + 0.8f * r1;
            xout[((size_t)(b * Co + o) * 3 + 2) * Npts + pt] = 0.2f * p2 + 0.8f * r2;
        }
    }
}

// ============================ VN max-pool-down ============================
__global__ void vn_pool_kernel(const float* __restrict__ xin,
                               const int* __restrict__ idx, long long sb, int sq,
                               const float* __restrict__ wp,
                               float* __restrict__ xout,
                               int C, int Np, int Nq)
{
#pragma clang fp contract(off)
    __shared__ float nb[4 * 84 * 3];
    int b = blockIdx.y;
    int q = blockIdx.x;
    const int* ir = idx + b * sb + (long long)q * sq;
    for (int kk = 0; kk < 4; ++kk) {
        int mm = ir[kk];
        for (int t = threadIdx.x; t < C * 3; t += blockDim.x)
            nb[kk * C * 3 + t] = xin[(size_t)(b * 3 * C + t) * Np + mm];
    }
    __syncthreads();
    int o = threadIdx.x;
    if (o >= C) return;
    const float* wr = wp + o * C;
    float best = -3.4e38f;
    int bk = 0;
    for (int kk = 0; kk < 4; ++kk) {
        const float* cl = &nb[kk * C * 3];
        float d0 = 0.f, d1 = 0.f, d2 = 0.f;
        for (int c = 0; c < C; ++c) {
            float w = wr[c];
            d0 += w * cl[3 * c]; d1 += w * cl[3 * c + 1]; d2 += w * cl[3 * c + 2];
        }
        float dot = cl[o * 3] * d0 + cl[o * 3 + 1] * d1 + cl[o * 3 + 2] * d2;
        if (dot > best) { best = dot; bk = kk; }
    }
    const float* cb = &nb[bk * C * 3];
    xout[((size_t)(b * C + o) * 3 + 0) * Nq + q] = cb[o * 3];
    xout[((size_t)(b * C + o) * 3 + 1) * Nq + q] = cb[o * 3 + 1];
    xout[((size_t)(b * C + o) * 3 + 2) * Nq + q] = cb[o * 3 + 2];
}

// ============================ eqv assembly + fused mean partial ==============
__global__ void eqv_kernel(const float* __restrict__ x0, const float* __restrict__ x1,
                           const float* __restrict__ x2, const float* __restrict__ x3,
                           const float* __restrict__ x4,
                           const int* __restrict__ i1, const int* __restrict__ i2,
                           float* __restrict__ out_eqv, float* __restrict__ mfw)
{
    __shared__ float r1[256];
    int n = blockIdx.x * 256 + threadIdx.x;
    int cv = blockIdx.y;
    int b = blockIdx.z;
    int cc = cv / 3, v = cv % 3;
    float val;
    if (cc < 42)
        val = x0[((size_t)(b * 42 + cc) * 3 + v) * NTOT + n];
    else if (cc < 84)
        val = x1[((size_t)(b * 42 + (cc - 42)) * 3 + v) * NTOT + n];
    else if (cc < 168) {
        int m = i1[b * NTOT + n];
        val = x2[((size_t)(b * 84 + (cc - 84)) * 3 + v) * 512 + m];
    } else if (cc < 252) {
        int m = i1[b * NTOT + n];
        val = x3[((size_t)(b * 84 + (cc - 168)) * 3 + v) * 512 + m];
    } else {
        int m = i2[b * NTOT + n];
        val = x4[((size_t)(b * 168 + (cc - 252)) * 3 + v) * 128 + m];
    }
    out_eqv[((size_t)(b * 1260 + cv)) * NTOT + n] = val;
    r1[threadIdx.x] = val;
    __syncthreads();
    for (int off = 128; off; off >>= 1) {
        if ((int)threadIdx.x < off) r1[threadIdx.x] += r1[threadIdx.x + off];
        __syncthreads();
    }
    if (threadIdx.x == 0) atomicAdd(&mfw[b * 1260 + cv], r1[0]);
}

// ============================ mean_feat finalize ============================
__global__ void mf_finalize_kernel(float* __restrict__ mfw, float* __restrict__ out_mf)
{
    int i = blockIdx.x * 256 + threadIdx.x;
    if (i < 5040) {
        float m = mfw[i] / 2048.0f;
        mfw[i] = m;
        out_mf[i] = m;
    }
}

// ============================ z1: wave-per-output VN layer (K=420) ===========
__global__ __launch_bounds__(256)
void z1_kernel(const float* __restrict__ mfw,
               const float* __restrict__ wv1f, const float* __restrict__ wv1d,
               float* __restrict__ z1ws)
{
#pragma clang fp contract(off)
    __shared__ float mf[1260];
    int b = blockIdx.y;
    int wave = threadIdx.x >> 6, lane = threadIdx.x & 63;
    for (int i = threadIdx.x; i < 1260; i += 256) mf[i] = mfw[b * 1260 + i];
    __syncthreads();
    int o = blockIdx.x * 4 + wave;
    if (o >= 210) return;
    const float* wr  = wv1f + (size_t)o * 420;
    const float* wdr = wv1d + (size_t)o * 420;
    float p0 = 0.f, p1 = 0.f, p2 = 0.f, d0 = 0.f, d1 = 0.f, d2 = 0.f;
    for (int c = lane; c < 420; c += 64) {
        float m0 = mf[3 * c], m1 = mf[3 * c + 1], m2 = mf[3 * c + 2];
        float w = wr[c];
        p0 += w * m0; p1 += w * m1; p2 += w * m2;
        float w2 = wdr[c];
        d0 += w2 * m0; d1 += w2 * m1; d2 += w2 * m2;
    }
    for (int off = 32; off; off >>= 1) {
        p0 += __shfl_down(p0, off); p1 += __shfl_down(p1, off);
        p2 += __shfl_down(p2, off); d0 += __shfl_down(d0, off);
        d1 += __shfl_down(d1, off); d2 += __shfl_down(d2, off);
    }
    if (lane == 0) {
        float dot = p0 * d0 + p1 * d1 + p2 * d2;
        float r0, r1, r2;
        if (dot >= 0.f) { r0 = p0; r1 = p1; r2 = p2; }
        else {
            float tq = dot / (d0 * d0 + d1 * d1 + d2 * d2 + 1e-6f);
            r0 = p0 - tq * d0; r1 = p1 - tq * d1; r2 = p2 - tq * d2;
        }
        z1ws[b * 630 + o * 3]     = 0.2f * p0 + 0.8f * r0;
        z1ws[b * 630 + o * 3 + 1] = 0.2f * p1 + 0.8f * r1;
        z1ws[b * 630 + o * 3 + 2] = 0.2f * p2 + 0.8f * r2;
    }
}

// ============================ z2: wave-per-output VN layer (K=210) ===========
__global__ __launch_bounds__(256)
void z2_kernel(const float* __restrict__ z1ws,
               const float* __restrict__ wv2f, const float* __restrict__ wv2d,
               float* __restrict__ z2ws)
{
#pragma clang fp contract(off)
    __shared__ float zl[630];
    int b = blockIdx.y;
    int wave = threadIdx.x >> 6, lane = threadIdx.x & 63;
    for (int i = threadIdx.x; i < 630; i += 256) zl[i] = z1ws[b * 630 + i];
    __syncthreads();
    int o = blockIdx.x * 4 + wave;
    if (o >= 84) return;
    const float* wr  = wv2f + (size_t)o * 210;
    const float* wdr = wv2d + (size_t)o * 210;
    float p0 = 0.f, p1 = 0.f, p2 = 0.f, d0 = 0.f, d1 = 0.f, d2 = 0.f;
    for (int c = lane; c < 210; c += 64) {
        float m0 = zl[3 * c], m1 = zl[3 * c + 1], m2 = zl[3 * c + 2];
        float w = wr[c];
        p0 += w * m0; p1 += w * m1; p2 += w * m2;
        float w2 = wdr[c];
        d0 += w2 * m0; d1 += w2 * m1; d2 += w2 * m2;
    }
    for (int off = 32; off; off >>= 1) {
        p0 += __shfl_down(p0, off); p1 += __shfl_down(p1, off);
        p2 += __shfl_down(p2, off); d0 += __shfl_down(d0, off);
        d1 += __shfl_down(d1, off); d2 += __shfl_down(d2, off);
    }
    if (lane == 0) {
        float dot = p0 * d0 + p1 * d1 + p2 * d2;
        float r0, r1, r2;
        if (dot >= 0.f) { r0 = p0; r1 = p1; r2 = p2; }
        else {
            float tq = dot / (d0 * d0 + d1 * d1 + d2 * d2 + 1e-6f);
            r0 = p0 - tq * d0; r1 = p1 - tq * d1; r2 = p2 - tq * d2;
        }
        z2ws[b * 252 + o * 3]     = 0.2f * p0 + 0.8f * r0;
        z2ws[b * 252 + o * 3 + 1] = 0.2f * p1 + 0.8f * r1;
        z2ws[b * 252 + o * 3 + 2] = 0.2f * p2 + 0.8f * r2;
    }
}

// ============================ z3 + inv_gl ============================
__global__ void z3invgl_kernel(const float* __restrict__ mfw,
                               const float* __restrict__ z2ws,
                               const float* __restrict__ w3,
                               float* __restrict__ invgl_ws,
                               float* __restrict__ out_invgl)
{
#pragma clang fp contract(off)
    __shared__ float z2[252];
    __shared__ float z3[6];
    __shared__ float mf[1260];
    int b = blockIdx.x;
    int t = threadIdx.x;
    for (int i = t; i < 252; i += 256) z2[i] = z2ws[b * 252 + i];
    for (int i = t; i < 1260; i += 256) mf[i] = mfw[b * 1260 + i];
    __syncthreads();
    if (t < 6) {
        int v = t / 2, kt = t % 2;
        float s = 0.f;
        for (int c = 0; c < 84; ++c) s += z2[c * 3 + v] * w3[kt * 84 + c];
        z3[v * 2 + kt] = s;
    }
    __syncthreads();
    for (int i = t; i < 840; i += 256) {
        int ii = i / 2, kt = i % 2;
        float s = mf[ii * 3] * z3[0 + kt] + mf[ii * 3 + 1] * z3[2 + kt] +
                  mf[ii * 3 + 2] * z3[4 + kt];
        invgl_ws[b * 840 + i] = s;
        out_invgl[b * 840 + i] = s;
    }
}

// ============================ conv1 factored coefficients (wave-per-o) =======
__global__ __launch_bounds__(256)
void conv1_coef_kernel(const float* __restrict__ ws1,
                       const float* __restrict__ invgl,
                       const float* __restrict__ mfw,
                       const int* __restrict__ cat,
                       float* __restrict__ cb, float* __restrict__ ab,
                       float* __restrict__ w0)
{
#pragma clang fp contract(off)
    int wave = threadIdx.x >> 6, lane = threadIdx.x & 63;
    int o = blockIdx.x * 4 + wave;           // 0..1023
    int b = blockIdx.y;
    const float* wr = ws1 + (size_t)o * 1267;
    float s = 0.f;
    for (int j = lane; j < 840; j += 64)
        s += wr[1 + j] * invgl[b * 840 + j];
    float a0 = 0.f, a1 = 0.f, a2 = 0.f;
    for (int i = lane; i < 420; i += 64) {
        float w = wr[841 + i];
        a0 += w * mfw[b * 1260 + i * 3];
        a1 += w * mfw[b * 1260 + i * 3 + 1];
        a2 += w * mfw[b * 1260 + i * 3 + 2];
    }
    for (int off = 32; off; off >>= 1) {
        s  += __shfl_down(s, off);
        a0 += __shfl_down(a0, off);
        a1 += __shfl_down(a1, off);
        a2 += __shfl_down(a2, off);
    }
    if (lane == 0) {
        cb[b * 1024 + o] = s + wr[1261 + cat[b]];
        ab[((size_t)(b * 1024 + o)) * 3 + 0] = a0;
        ab[((size_t)(b * 1024 + o)) * 3 + 1] = a1;
        ab[((size_t)(b * 1024 + o)) * 3 + 2] = a2;
        if (b == 0) w0[o] = wr[0];
    }
}

// ============================ y1 generator (replaces gemm1) ==================
__global__ __launch_bounds__(256)
void y1_gen_kernel(const float* __restrict__ cb, const float* __restrict__ ab,
                   const float* __restrict__ w0, const float* __restrict__ coord,
                   const float* __restrict__ normv, float* __restrict__ y1t)
{
#pragma clang fp contract(off)
    int pt = blockIdx.x;                // 0..8191
    int b = pt >> 11, n = pt & 2047;
    float cx = coord[(b * 3 + 0) * NTOT + n];
    float cy = coord[(b * 3 + 1) * NTOT + n];
    float cz = coord[(b * 3 + 2) * NTOT + n];
    float nr = normv[b * NTOT + n];
    for (int it = 0; it < 4; ++it) {
        int o = it * 256 + threadIdx.x;
        size_t bo = (size_t)(b * 1024 + o);
        float v = cb[bo] + ab[bo * 3] * cx + ab[bo * 3 + 1] * cy +
                  ab[bo * 3 + 2] * cz + w0[o] * nr;
        y1t[(size_t)pt * 1024 + o] = v;
    }
}

// ============================ weight convert f32 -> bf16 ============================
__global__ void wconv_kernel(const float* __restrict__ src, unsigned short* __restrict__ dst,
                             int Msrc, int Ksrc, int Kpad)
{
    int k = blockIdx.x * 256 + threadIdx.x;
    int o = blockIdx.y;
    float v = (o < Msrc && k < Ksrc) ? src[(size_t)o * Ksrc + k] : 0.f;
    dst[(size_t)o * Kpad + k] = f2b(v);
}

// ============================ MFMA GEMM ============================
__global__ __launch_bounds__(256)
void gemm_mfma_kernel(const unsigned short* __restrict__ A,
                      const unsigned short* __restrict__ Bw,
                      float* __restrict__ C, int K, int Mreal)
{
    __shared__ __align__(16) unsigned short Al[128 * 40];
    __shared__ __align__(16) unsigned short Bl[128 * 40];
    int t = threadIdx.x;
    int r0 = blockIdx.x * 128;
    int c0 = blockIdx.y * 128;
    int w = t >> 6, l = t & 63;
    int wm = w & 1, wn = w >> 1;
    int lm = l & 15, lq = l >> 4;
    f32x4 acc[4][4] = {};
    for (int k0 = 0; k0 < K; k0 += 32) {
        for (int half = 0; half < 2; ++half) {
            int ch = t + half * 256;
            int row = ch >> 2, kc = ch & 3;
            *(uint4*)&Al[row * 40 + kc * 8] =
                *(const uint4*)&A[(size_t)(r0 + row) * K + k0 + kc * 8];
            *(uint4*)&Bl[row * 40 + kc * 8] =
                *(const uint4*)&Bw[(size_t)(c0 + row) * K + k0 + kc * 8];
        }
        __syncthreads();
        bf16x8 af[4], bfr[4];
#pragma unroll
        for (int i = 0; i < 4; ++i)
            af[i] = *(const bf16x8*)&Al[(wm * 64 + i * 16 + lm) * 40 + lq * 8];
#pragma unroll
        for (int j = 0; j < 4; ++j)
            bfr[j] = *(const bf16x8*)&Bl[(wn * 64 + j * 16 + lm) * 40 + lq * 8];
#pragma unroll
        for (int i = 0; i < 4; ++i)
#pragma unroll
            for (int j = 0; j < 4; ++j)
                acc[i][j] = __builtin_amdgcn_mfma_f32_16x16x32_bf16(af[i], bfr[j],
                                                                    acc[i][j], 0, 0, 0);
        __syncthreads();
    }
#pragma unroll
    for (int i = 0; i < 4; ++i) {
#pragma unroll
        for (int j = 0; j < 4; ++j) {
            int col = c0 + wn * 64 + j * 16 + lm;
            if (col < Mreal) {
                int rbase = r0 + wm * 64 + i * 16 + lq * 4;
#pragma unroll
                for (int r = 0; r < 4; ++r)
                    C[(size_t)(rbase + r) * Mreal + col] = acc[i][j][r];
            }
        }
    }
}

// ============================ conv BN stats ============================
__global__ void cstatsT_kernel(const float* __restrict__ Ct, float* __restrict__ st,
                               int Mreal)
{
    __shared__ float l1[256], l2[256];
    int t = threadIdx.x;
    int o = blockIdx.x * 64 + (t & 63);
    int r0 = blockIdx.y * 128 + (t >> 6) * 32;
    float s = 0.f, s2 = 0.f;
    if (o < Mreal) {
        for (int rr = 0; rr < 32; ++rr) {
            float v = Ct[(size_t)(r0 + rr) * Mreal + o];
            s += v; s2 += v * v;
        }
    }
    l1[t] = s; l2[t] = s2;
    __syncthreads();
    if (t < 64 && o < Mreal) {
        s  = l1[t] + l1[t + 64] + l1[t + 128] + l1[t + 192];
        s2 = l2[t] + l2[t + 64] + l2[t + 128] + l2[t + 192];
        atomicAdd(&st[o], s);
        atomicAdd(&st[Mreal + o], s2);
    }
}

// ============================ BN+ReLU -> bf16 ============================
__global__ void bnreluT_kernel(const float* __restrict__ Ct, const float* __restrict__ st,
                               const float* __restrict__ g, const float* __restrict__ be,
                               unsigned short* __restrict__ outb, int M, int maskM)
{
#pragma clang fp contract(off)
    size_t idx = (size_t)blockIdx.x * 256 + threadIdx.x;
    int o = (int)(idx & (size_t)maskM);
    float m = st[o] * (1.f / 8192.f);
    float var = st[M + o] * (1.f / 8192.f) - m * m;
    float sqv = sqrtf(var + 1e-5f);
    float v = g[o] * (Ct[idx] - m) / sqv + be[o];
    outb[idx] = f2b(v > 0.f ? v : 0.f);
}

// ============================ final BN+ReLU + transpose ============================
__global__ void bnrelu_outT_kernel(const float* __restrict__ Ct, const float* __restrict__ st,
                                   const float* __restrict__ g, const float* __restrict__ be,
                                   float* __restrict__ outinv)
{
#pragma clang fp contract(off)
    __shared__ float tile[64][65];
    int t = threadIdx.x;
    int r0 = blockIdx.x * 64;
    int o0 = blockIdx.y * 64;
    int b = r0 >> 11, n0 = r0 & 2047;
    int oi = t & 63;
    int o = o0 + oi;
    float m = 0.f, sqv = 1.f, gg = 0.f, bb = 0.f;
    if (o < 420) {
        m = st[o] * (1.f / 8192.f);
        float var = st[420 + o] * (1.f / 8192.f) - m * m;
        sqv = sqrtf(var + 1e-5f);
        gg = g[o]; bb = be[o];
    }
    for (int it = 0; it < 16; ++it) {
        int rr = it * 4 + (t >> 6);
        float v = 0.f;
        if (o < 420) {
            v = gg * (Ct[(size_t)(r0 + rr) * 420 + o] - m) / sqv + bb;
            v = v > 0.f ? v : 0.f;
        }
        tile[rr][oi] = v;
    }
    __syncthreads();
    for (int it = 0; it < 16; ++it) {
        int oc = it * 4 + (t >> 6);
        int oo = o0 + oc;
        if (oo < 420)
            outinv[((size_t)(b * 420 + oo)) * 2048 + n0 + (t & 63)] = tile[t & 63][oc];
    }
}

// ============================ launch ============================
extern "C" void kernel_launch(void* const* d_in, const int* in_sizes, int n_in,
                              void* d_out, int out_size, void* d_ws, size_t ws_size,
                              hipStream_t stream)
{
    (void)in_sizes; (void)n_in; (void)out_size; (void)ws_size;
    const float* xc   = (const float*)d_in[0];
    const float* normv= (const float*)d_in[1];
    const int*   cat  = (const int*)d_in[2];
    const float* wf0  = (const float*)d_in[3];
    const float* wd0  = (const float*)d_in[4];
    const float* g0   = (const float*)d_in[5];
    const float* b0   = (const float*)d_in[6];
    const float* wf1  = (const float*)d_in[7];
    const float* wd1  = (const float*)d_in[8];
    const float* g1   = (const float*)d_in[9];
    const float* b1   = (const float*)d_in[10];
    const float* wp1  = (const float*)d_in[11];
    const float* wf2  = (const float*)d_in[12];
    const float* wd2  = (const float*)d_in[13];
    const float* g2   = (const float*)d_in[14];
    const float* b2   = (const float*)d_in[15];
    const float* wf3  = (const float*)d_in[16];
    const float* wd3  = (const float*)d_in[17];
    const float* g3   = (const float*)d_in[18];
    const float* b3   = (const float*)d_in[19];
    const float* wp2  = (const float*)d_in[20];
    const float* wf4  = (const float*)d_in[21];
    const float* wd4  = (const float*)d_in[22];
    const float* g4   = (const float*)d_in[23];
    const float* b4   = (const float*)d_in[24];
    const float* wv1f = (const float*)d_in[25];
    const float* wv1d = (const float*)d_in[26];
    const float* wv2f = (const float*)d_in[27];
    const float* wv2d = (const float*)d_in[28];
    const float* w3   = (const float*)d_in[29];
    const float* ws1  = (const float*)d_in[30];
    const float* sg1  = (const float*)d_in[32];
    const float* sb1  = (const float*)d_in[33];
    const float* ws2  = (const float*)d_in[34];
    const float* sg2  = (const float*)d_in[36];
    const float* sb2  = (const float*)d_in[37];
    const float* ws3  = (const float*)d_in[38];
    const float* sg3  = (const float*)d_in[40];
    const float* sb3  = (const float*)d_in[41];

    float* ws = (float*)d_ws;
    float* out = (float*)d_out;

    int*    idx20 = (int*)(ws + WS_IDX20);
    float*  fs    = ws + WS_FS;
    float*  x0    = ws + WS_X0;
    float*  x1    = ws + WS_X1;
    float*  xm2   = ws + WS_XM2;
    float*  x2    = ws + WS_X2;
    float*  x3    = ws + WS_X3;
    int*    idx42 = (int*)(ws + WS_IDX42);
    float*  xm4   = ws + WS_XM4;
    float*  x4    = ws + WS_X4;
    int*    i1p   = (int*)(ws + WS_I1);
    int*    i2p   = (int*)(ws + WS_I2);
    float*  mfw   = ws + WS_MF;
    float*  invgl = ws + WS_INVGL;
    double* st    = (double*)(ws + WS_STATS);
    float*  cst   = ws + WS_CST;
    float*  cb    = ws + WS_CB;
    float*  ab    = ws + WS_AB;
    float*  w0    = ws + WS_W0;
    float*  z1ws  = ws + WS_Z1;
    float*  z2ws  = ws + WS_Z2;
    unsigned short* w2b  = (unsigned short*)(ws + WS_W2B);
    unsigned short* w3b  = (unsigned short*)(ws + WS_W3B);
    float*  y1t   = ws + WS_Y1T;
    unsigned short* y1b  = (unsigned short*)(ws + WS_Y1B);
    float*  y2t   = ws + WS_Y2T;
    unsigned short* y2b  = (unsigned short*)(ws + WS_Y2B);
    float*  y3t   = ws + WS_Y3T;

    hipMemsetAsync((void*)st, 0, 840 * sizeof(double), stream);
    hipMemsetAsync((void*)cst, 0, 3912 * sizeof(float), stream);
    hipMemsetAsync((void*)mfw, 0, 5040 * sizeof(float), stream);

    // weight conversions (independent)
    wconv_kernel<<<dim3(4, 512), 256, 0, stream>>>(ws2, w2b, 512, 1024, 1024);
    wconv_kernel<<<dim3(2, 512), 256, 0, stream>>>(ws3, w3b, 420, 512, 512);

    // KNN-20 (also the knn-4 prefix for pool stage 1)
    knn_reg_kernel<32, 20><<<dim3(512, 4), 256, 0, stream>>>(xc, 1, 1, idx20, 2048);
    surf_build_kernel<<<640, 256, 0, stream>>>(xc, idx20, fs);

    // stage 0
    stats0_kernel<<<dim3(128, 4), 256, 0, stream>>>(fs, wf0, st + ST0_OFF);
    apply0_kernel<<<dim3(128, 4), 256, 0, stream>>>(fs, wf0, wd0, g0, b0,
                                                    st + ST0_OFF, x0);

    // stage 1
    vn_stats_kernel<<<dim3(128, 4), 256, 0, stream>>>(x0, wf1, st + ST1_OFF, 42, 42, 2048);
    vn_apply_kernel<<<dim3(256, 4), 256, 0, stream>>>(x0, wf1, wd1, g1, b1, st + ST1_OFF,
                                                      8192.0, 42, 42, 2048, 6, 2, x1);

    // pool 1
    vn_pool_kernel<<<dim3(512, 4), 256, 0, stream>>>(x1, idx20, 40960LL, 80, wp1, xm2,
                                                     42, 2048, 512);
    // stage 2
    vn_stats_kernel<<<dim3(32, 4), 256, 0, stream>>>(xm2, wf2, st + ST2_OFF, 42, 84, 512);
    vn_apply_kernel<<<dim3(128, 4), 256, 0, stream>>>(xm2, wf2, wd2, g2, b2, st + ST2_OFF,
                                                      2048.0, 42, 84, 512, 7, 2, x2);
    // stage 3
    vn_stats_kernel<<<dim3(32, 4), 256, 0, stream>>>(x2, wf3, st + ST3_OFF, 84, 84, 512);
    vn_apply_kernel<<<dim3(128, 4), 256, 0, stream>>>(x2, wf3, wd3, g3, b3, st + ST3_OFF,
                                                      2048.0, 84, 84, 512, 7, 2, x3);

    // knn-4 on coord2 (cands stride 4, queries stride 16)
    knn_reg_kernel<8, 4><<<dim3(32, 4), 256, 0, stream>>>(xc, 4, 16, idx42, 128);
    vn_pool_kernel<<<dim3(128, 4), 256, 0, stream>>>(x3, idx42, 512LL, 4, wp2, xm4,
                                                     84, 512, 128);
    // stage 4
    vn_stats_kernel<<<dim3(8, 4), 256, 0, stream>>>(xm4, wf4, st + ST4_OFF, 84, 168, 128);
    vn_apply_kernel<<<dim3(64, 4), 256, 0, stream>>>(xm4, wf4, wd4, g4, b4, st + ST4_OFF,
                                                     512.0, 84, 168, 128, 8, 2, x4);

    // nearest-neighbor upsample indices
    nearest_reg_kernel<8><<<dim3(512, 4), 256, 0, stream>>>(xc, 4, i1p);
    nearest_reg_kernel<2><<<dim3(512, 4), 256, 0, stream>>>(xc, 16, i2p);

    // eqv (output 0) with fused mean partials; finalize mean (output 1)
    eqv_kernel<<<dim3(8, 1260, 4), 256, 0, stream>>>(x0, x1, x2, x3, x4, i1p, i2p,
                                                     out + OUT_EQV, mfw);
    mf_finalize_kernel<<<20, 256, 0, stream>>>(mfw, out + OUT_MF);

    // z chain (wave-per-output, coalesced) + inv_gl (output 3)
    z1_kernel<<<dim3(53, 4), 256, 0, stream>>>(mfw, wv1f, wv1d, z1ws);
    z2_kernel<<<dim3(21, 4), 256, 0, stream>>>(z1ws, wv2f, wv2d, z2ws);
    z3invgl_kernel<<<4, 256, 0, stream>>>(mfw, z2ws, w3, invgl, out + OUT_INVGL);

    // invariant branch: conv1 factored (wave-per-(b,o), coalesced)
    conv1_coef_kernel<<<dim3(256, 4), 256, 0, stream>>>(ws1, invgl, mfw, cat, cb, ab, w0);
    y1_gen_kernel<<<8192, 256, 0, stream>>>(cb, ab, w0, xc, normv, y1t);
    cstatsT_kernel<<<dim3(16, 64), 256, 0, stream>>>(y1t, cst + CST1_OFF, 1024);
    bnreluT_kernel<<<32768, 256, 0, stream>>>(y1t, cst + CST1_OFF, sg1, sb1, y1b,
                                              1024, 1023);

    gemm_mfma_kernel<<<dim3(64, 4), 256, 0, stream>>>(y1b, w2b, y2t, 1024, 512);
    cstatsT_kernel<<<dim3(8, 64), 256, 0, stream>>>(y2t, cst + CST2_OFF, 512);
    bnreluT_kernel<<<16384, 256, 0, stream>>>(y2t, cst + CST2_OFF, sg2, sb2, y2b,
                                              512, 511);

    gemm_mfma_kernel<<<dim3(64, 4), 256, 0, stream>>>(y2b, w3b, y3t, 512, 420);
    cstatsT_kernel<<<dim3(7, 64), 256, 0, stream>>>(y3t, cst + CST3_OFF, 420);
    bnrelu_outT_kernel<<<dim3(128, 7), 256, 0, stream>>>(y3t, cst + CST3_OFF, sg3, sb3,
                                                         out + OUT_INV);
}

// Round 8
// 761.358 us; speedup vs baseline: 2.5027x; 1.0187x over previous
//
#include <hip/hip_runtime.h>
#include <hip/hip_bf16.h>
#include <cstdint>
#include <cstddef>

#define NTOT 2048
#define BTOT 4

typedef short bf16x8 __attribute__((ext_vector_type(8)));
typedef float f32x4 __attribute__((ext_vector_type(4)));

__device__ inline unsigned short f2b(float v) {
    __hip_bfloat16 h = __float2bfloat16(v);
    return *reinterpret_cast<unsigned short*>(&h);
}

// ---------------- workspace layout (float-element offsets) ----------------
static const size_t WS_IDX20 = 0;                       // int[163840]
static const size_t WS_FS    = 163840;                  // float[1474560]
static const size_t WS_X0    = 1638400;                 // float[2064384] (B,42,3,2048)
static const size_t WS_X1    = 3702784;                 // float[2064384]
static const size_t WS_XM2   = 5767168;                 // float[258048]
static const size_t WS_X2    = 6025216;                 // float[516096]
static const size_t WS_X3    = 6541312;                 // float[516096]
static const size_t WS_IDX42 = 7057408;                 // int[2048]
static const size_t WS_XM4   = 7059456;                 // float[129024]
static const size_t WS_X4    = 7188480;                 // float[258048]
static const size_t WS_I1    = 7446528;                 // int[8192]
static const size_t WS_I2    = 7454720;                 // int[8192]
static const size_t WS_MF    = 7462912;                 // float[5040]
static const size_t WS_INVGL = 7467952;                 // float[3360]
static const size_t WS_STATS = 7471312;                 // double[840] (1680 fl slots)
static const size_t WS_CST   = 7472992;                 // float[3912] conv bn sums
static const size_t WS_CB    = 7480320;                 // float[4096]   cb[b][o]
static const size_t WS_AB    = 7484416;                 // float[12288]  ab[b][o][3]
static const size_t WS_W0    = 7496704;                 // float[1024]   ws1[:,0]
static const size_t WS_Z1    = 7497728;                 // float[2520]   z1[b][210*3]
static const size_t WS_Z2    = 7500288;                 // float[1008]   z2[b][84*3]
static const size_t WS_W2B   = 13378560;                // ushort[512*1024]
static const size_t WS_W3B   = 13640704;                // ushort[512*512]
static const size_t WS_Y1T   = 13771776;                // float[8192*1024]
static const size_t WS_Y1B   = 0;                       // ushort overlay
static const size_t WS_Y2T   = 7480320;                 // float overlay (CB/AB/Z dead)
static const size_t WS_Y2B   = 4194304;                 // ushort overlay
static const size_t WS_Y3T   = WS_Y1T;                  // float overlay

#define ST0_OFF 0
#define ST1_OFF 84
#define ST2_OFF 168
#define ST3_OFF 336
#define ST4_OFF 504
#define CST1_OFF 0
#define CST2_OFF 2048
#define CST3_OFF 3072

#define OUT_EQV   0
#define OUT_MF    10321920
#define OUT_INV   10326960
#define OUT_INVGL 13767600

// ============================ KNN v3 (cached quarter maxima) ==================
template <int SLOTS, int K>
__global__ __launch_bounds__(256)
void knn_reg_kernel(const float* __restrict__ coord, int cand_stride, int q_stride,
                    int* __restrict__ out_idx, int q_cnt)
{
#pragma clang fp contract(off)
    constexpr int Q = SLOTS / 8;
    int b = blockIdx.y;
    int wave = threadIdx.x >> 6, lane = threadIdx.x & 63;
    int q = blockIdx.x * 4 + wave;
    if (q >= q_cnt) return;
    int nq = q * q_stride;
    float qx = coord[(b * 3 + 0) * NTOT + nq];
    float qy = coord[(b * 3 + 1) * NTOT + nq];
    float qz = coord[(b * 3 + 2) * NTOT + nq];
    float xxq = qx * qx + qy * qy + qz * qz;
    float v[SLOTS];
#pragma unroll
    for (int j = 0; j < SLOTS; ++j) {
        int mo = (lane + 64 * j) * cand_stride;
        float cx = coord[(b * 3 + 0) * NTOT + mo];
        float cy = coord[(b * 3 + 1) * NTOT + mo];
        float cz = coord[(b * 3 + 2) * NTOT + mo];
        float inner = qx * cx + qy * cy + qz * cz;
        float xxc = cx * cx + cy * cy + cz * cz;
        v[j] = (2.0f * inner - xxq) - xxc;
    }
    float qv[Q]; int qj[Q];
#pragma unroll
    for (int qq = 0; qq < Q; ++qq) {
        float nv = v[qq * 8]; int nj = qq * 8;
#pragma unroll
        for (int j = 1; j < 8; ++j)
            if (v[qq * 8 + j] > nv) { nv = v[qq * 8 + j]; nj = qq * 8 + j; }
        qv[qq] = nv; qj[qq] = nj;
    }
#pragma clang loop unroll(disable)
    for (int kk = 0; kk < K; ++kk) {
        float bv = qv[0]; int bj = qj[0];
#pragma unroll
        for (int qq = 1; qq < Q; ++qq)
            if (qv[qq] > bv) { bv = qv[qq]; bj = qj[qq]; }
        int bm = lane + 64 * bj;
        for (int off = 32; off; off >>= 1) {
            float ov = __shfl_down(bv, off);
            int   om = __shfl_down(bm, off);
            if (ov > bv || (ov == bv && om < bm)) { bv = ov; bm = om; }
        }
        int m_win = __builtin_amdgcn_readfirstlane(bm);
        if (lane == 0)
            out_idx[((size_t)(b * q_cnt) + q) * K + kk] = m_win;
        int w_slot = m_win >> 6;
        bool isw = (lane == (m_win & 63));
#pragma unroll
        for (int qq = 0; qq < Q; ++qq) {
            if (qq == (w_slot >> 3)) {
#pragma unroll
                for (int j = 0; j < 8; ++j)
                    if (qq * 8 + j == w_slot)
                        v[qq * 8 + j] = isw ? -3.4e38f : v[qq * 8 + j];
                float nv = v[qq * 8]; int nj = qq * 8;
#pragma unroll
                for (int j = 1; j < 8; ++j)
                    if (v[qq * 8 + j] > nv) { nv = v[qq * 8 + j]; nj = qq * 8 + j; }
                qv[qq] = nv; qj[qq] = nj;
            }
        }
    }
}

// ============================ nearest (register argmin, wave-per-query) ======
template <int SLOTS>
__global__ __launch_bounds__(256)
void nearest_reg_kernel(const float* __restrict__ coord, int cand_stride,
                        int* __restrict__ out)
{
#pragma clang fp contract(off)
    int b = blockIdx.y;
    int wave = threadIdx.x >> 6, lane = threadIdx.x & 63;
    int n = blockIdx.x * 4 + wave;
    float qx = coord[(b * 3 + 0) * NTOT + n];
    float qy = coord[(b * 3 + 1) * NTOT + n];
    float qz = coord[(b * 3 + 2) * NTOT + n];
    float tt = qx * qx + qy * qy + qz * qz;
    float v[SLOTS];
#pragma unroll
    for (int j = 0; j < SLOTS; ++j) {
        int mo = (lane + 64 * j) * cand_stride;
        float cx = coord[(b * 3 + 0) * NTOT + mo];
        float cy = coord[(b * 3 + 1) * NTOT + mo];
        float cz = coord[(b * 3 + 2) * NTOT + mo];
        float inner = qx * cx + qy * cy + qz * cz;
        float ss = cx * cx + cy * cy + cz * cz;
        v[j] = (tt - 2.0f * inner) + ss;
    }
    float bv = v[0];
    int bj = 0;
#pragma unroll
    for (int j = 1; j < SLOTS; ++j)
        if (v[j] < bv) { bv = v[j]; bj = j; }
    int bm = lane + 64 * bj;
    for (int off = 32; off; off >>= 1) {
        float ov = __shfl_down(bv, off);
        int   om = __shfl_down(bm, off);
        if (ov < bv || (ov == bv && om < bm)) { bv = ov; bm = om; }
    }
    if (lane == 0) out[b * NTOT + n] = bm;
}

// ============================ surface feature build ============================
__global__ void surf_build_kernel(const float* __restrict__ coord,
                                  const int* __restrict__ idx20,
                                  float* __restrict__ fs)
{
#pragma clang fp contract(off)
    int t = blockIdx.x * 256 + threadIdx.x;
    if (t >= BTOT * NTOT * 20) return;
    int n = (t / 20) & (NTOT - 1);
    int b = t / (20 * NTOT);
    int m = idx20[t];
    float cx = coord[(b * 3 + 0) * NTOT + n];
    float cy = coord[(b * 3 + 1) * NTOT + n];
    float cz = coord[(b * 3 + 2) * NTOT + n];
    float nx = coord[(b * 3 + 0) * NTOT + m];
    float ny = coord[(b * 3 + 1) * NTOT + m];
    float nz = coord[(b * 3 + 2) * NTOT + m];
    float* f9 = fs + (size_t)t * 9;
    f9[0] = nx - cx; f9[1] = ny - cy; f9[2] = nz - cz;
    f9[3] = cx;      f9[4] = cy;      f9[5] = cz;
    f9[6] = ny * cz - nz * cy;
    f9[7] = nz * cx - nx * cz;
    f9[8] = nx * cy - ny * cx;
}

// ============================ stage-0 stats (4 waves x 4 pts) ========
__global__ __launch_bounds__(256)
void stats0_kernel(const float* __restrict__ fs,
                   const float* __restrict__ wf0,
                   double* __restrict__ stats)
{
#pragma clang fp contract(off)
    __shared__ float fl[4][720];
    __shared__ double red[4][84];
    int wave = threadIdx.x >> 6, lane = threadIdx.x & 63;
    int b = blockIdx.y;
    int n0 = (blockIdx.x * 4 + wave) * 4;
    const float* src = fs + ((size_t)(b * NTOT + n0) * 20) * 9;
    for (int t = lane; t < 720; t += 64) fl[wave][t] = src[t];
    __syncthreads();
    int o = lane;
    if (o < 42) {
        float w0 = wf0[o * 3], w1 = wf0[o * 3 + 1], w2 = wf0[o * 3 + 2];
        double s = 0.0, s2 = 0.0;
        for (int i = 0; i < 80; ++i) {
            const float* f9 = &fl[wave][i * 9];
            float p0 = w0 * f9[0] + w1 * f9[3] + w2 * f9[6];
            float p1 = w0 * f9[1] + w1 * f9[4] + w2 * f9[7];
            float p2 = w0 * f9[2] + w1 * f9[5] + w2 * f9[8];
            float nrm = sqrtf(p0 * p0 + p1 * p1 + p2 * p2) + 1e-6f;
            s += (double)nrm; s2 += (double)nrm * (double)nrm;
        }
        red[wave][o] = s;
        red[wave][42 + o] = s2;
    }
    __syncthreads();
    int t = threadIdx.x;
    if (t < 84)
        atomicAdd(&stats[t], red[0][t] + red[1][t] + red[2][t] + red[3][t]);
}

// ============================ stage-0 apply (1 point per wave) ========
__global__ __launch_bounds__(256)
void apply0_kernel(const float* __restrict__ fs,
                   const float* __restrict__ wf0,
                   const float* __restrict__ wd0,
                   const float* __restrict__ g0,
                   const float* __restrict__ b0,
                   const double* __restrict__ stats,
                   float* __restrict__ x0)
{
#pragma clang fp contract(off)
    __shared__ float fl[4][180];
    int wave = threadIdx.x >> 6, lane = threadIdx.x & 63;
    int b = blockIdx.y;
    int n = blockIdx.x * 4 + wave;
    const float* src = fs + ((size_t)(b * NTOT + n) * 20) * 9;
    for (int t = lane; t < 180; t += 64) fl[wave][t] = src[t];
    __syncthreads();
    int o = lane;
    if (o >= 42) return;
    double S1 = stats[o], S2 = stats[42 + o];
    double md = S1 / 163840.0;
    float m = (float)md;
    float var = (float)(S2 / 163840.0 - md * md);
    float sqv = sqrtf(var + 1e-5f);
    float gg = g0[o], bb = b0[o];
    float wa0 = wf0[o * 3], wa1 = wf0[o * 3 + 1], wa2 = wf0[o * 3 + 2];
    float wb0 = wd0[o * 3], wb1 = wd0[o * 3 + 1], wb2 = wd0[o * 3 + 2];
    float r8[3][8];
    float tl[3][4];
    for (int k = 0; k < 20; ++k) {
        const float* f9 = &fl[wave][k * 9];
        float p0 = wa0 * f9[0] + wa1 * f9[3] + wa2 * f9[6];
        float p1 = wa0 * f9[1] + wa1 * f9[4] + wa2 * f9[7];
        float p2 = wa0 * f9[2] + wa1 * f9[5] + wa2 * f9[8];
        float d0 = wb0 * f9[0] + wb1 * f9[3] + wb2 * f9[6];
        float d1 = wb0 * f9[1] + wb1 * f9[4] + wb2 * f9[7];
        float d2 = wb0 * f9[2] + wb1 * f9[5] + wb2 * f9[8];
        float nrm = sqrtf(p0 * p0 + p1 * p1 + p2 * p2) + 1e-6f;
        float nb = gg * (nrm - m) / sqv + bb;
        p0 = p0 / nrm * nb;
        p1 = p1 / nrm * nb;
        p2 = p2 / nrm * nb;
        float dot = p0 * d0 + p1 * d1 + p2 * d2;
        float r0, r1, r2;
        if (dot >= 0.f) { r0 = p0; r1 = p1; r2 = p2; }
        else {
            float tq = dot / (d0 * d0 + d1 * d1 + d2 * d2 + 1e-6f);
            r0 = p0 - tq * d0; r1 = p1 - tq * d1; r2 = p2 - tq * d2;
        }
        float o0 = 0.2f * p0 + 0.8f * r0;
        float o1 = 0.2f * p1 + 0.8f * r1;
        float o2 = 0.2f * p2 + 0.8f * r2;
        if (k < 8)       { r8[0][k] = o0;       r8[1][k] = o1;       r8[2][k] = o2; }
        else if (k < 16) { r8[0][k-8] += o0;    r8[1][k-8] += o1;    r8[2][k-8] += o2; }
        else             { tl[0][k-16] = o0;    tl[1][k-16] = o1;    tl[2][k-16] = o2; }
    }
    for (int v = 0; v < 3; ++v) {
        float res = ((r8[v][0] + r8[v][1]) + (r8[v][2] + r8[v][3])) +
                    ((r8[v][4] + r8[v][5]) + (r8[v][6] + r8[v][7]));
        res += tl[v][0]; res += tl[v][1]; res += tl[v][2]; res += tl[v][3];
        x0[((size_t)(b * 42 + o) * 3 + v) * NTOT + n] = res / 20.0f;
    }
}

// ============================ generic VN stats ============================
__global__ void vn_stats_kernel(const float* __restrict__ xin,
                                const float* __restrict__ wf,
                                double* __restrict__ stats,
                                int Ci, int Co, int Npts)
{
#pragma clang fp contract(off)
    __shared__ float col[252];
    int b = blockIdx.y;
    int o = threadIdx.x;
    double s = 0.0, s2 = 0.0;
    for (int it = 0; it < 16; ++it) {
        int pt = blockIdx.x * 16 + it;
        __syncthreads();
        for (int t = threadIdx.x; t < Ci * 3; t += blockDim.x)
            col[t] = xin[(size_t)(b * 3 * Ci + t) * Npts + pt];
        __syncthreads();
        if (o < Co) {
            const float* wr = wf + o * Ci;
            float p0 = 0.f, p1 = 0.f, p2 = 0.f;
            for (int c = 0; c < Ci; ++c) {
                float w = wr[c];
                p0 += w * col[3 * c]; p1 += w * col[3 * c + 1]; p2 += w * col[3 * c + 2];
            }
            float nrm = sqrtf(p0 * p0 + p1 * p1 + p2 * p2) + 1e-6f;
            s += (double)nrm; s2 += (double)nrm * (double)nrm;
        }
    }
    if (o < Co) { atomicAdd(&stats[o], s); atomicAdd(&stats[Co + o], s2); }
}

// ============================ VN apply (OPAD thread mapping) ==================
__global__ __launch_bounds__(256)
void vn_apply_kernel(const float* __restrict__ xin,
                     const float* __restrict__ wf,
                     const float* __restrict__ wd,
                     const float* __restrict__ g,
                     const float* __restrict__ bbp,
                     const double* __restrict__ stats,
                     double count, int Ci, int Co, int Npts,
                     int oshift, int nit,
                     float* __restrict__ xout)
{
#pragma clang fp contract(off)
    __shared__ float col[520];
    int t = threadIdx.x;
    int b = blockIdx.y;
    int OPAD = 1 << oshift;
    int PTS = 256 >> oshift;
    int o = t & (OPAD - 1);
    int ps = t >> oshift;
    int Ci3 = Ci * 3;
    int stride = Ci3 + 1;
    float m = 0.f, sqv = 1.f, gg = 0.f, bb = 0.f;
    if (o < Co) {
        double S1 = stats[o], S2 = stats[Co + o];
        double md = S1 / count;
        m = (float)md;
        float var = (float)(S2 / count - md * md);
        sqv = sqrtf(var + 1e-5f);
        gg = g[o]; bb = bbp[o];
    }
    int pt0 = blockIdx.x * (PTS * nit);
    for (int it = 0; it < nit; ++it) {
        int ptbase = pt0 + it * PTS;
        __syncthreads();
        for (int i = t; i < PTS * Ci3; i += 256) {
            int pl = i / Ci3, off = i - pl * Ci3;
            col[pl * stride + off] =
                xin[(size_t)(b * 3 * Ci + off) * Npts + (ptbase + pl)];
        }
        __syncthreads();
        if (o < Co) {
            const float* cl = &col[ps * stride];
            const float* wr = wf + o * Ci;
            const float* wdr = wd + o * Ci;
            float p0 = 0.f, p1 = 0.f, p2 = 0.f, d0 = 0.f, d1 = 0.f, d2 = 0.f;
            for (int c = 0; c < Ci; ++c) {
                float c0 = cl[3 * c], c1 = cl[3 * c + 1], c2 = cl[3 * c + 2];
                float w = wr[c];
                p0 += w * c0; p1 += w * c1; p2 += w * c2;
                float w2 = wdr[c];
                d0 += w2 * c0; d1 += w2 * c1; d2 += w2 * c2;
            }
            float nrm = sqrtf(p0 * p0 + p1 * p1 + p2 * p2) + 1e-6f;
            float nb = gg * (nrm - m) / sqv + bb;
            p0 = p0 / nrm * nb;
            p1 = p1 / nrm * nb;
            p2 = p2 / nrm * nb;
            float dot = p0 * d0 + p1 * d1 + p2 * d2;
            float r0, r1, r2;
            if (dot >= 0.f) { r0 = p0; r1 = p1; r2 = p2; }
            else {
                float tq = dot / (d0 * d0 + d1 * d1 + d2 * d2 + 1e-6f);
                r0 = p0 - tq * d0; r1 = p1 - tq * d1; r2 = p2 - tq * d2;
            }
            int pt = ptbase + ps;
            xout[((size_t)(b * Co + o) * 3 + 0) * Npts + pt] = 0.2f * p0 + 0.8f * r0;
            xout[((size_t)(b * Co + o) * 3 + 1) * Npts + pt] = 0.2f * p1 + 0.8f * r1;
            xout[((size_t)(b * Co + o) * 3 + 2) * Npts + pt] = 0.2f * p2 + 0.8f * r2;
        }
    }
}

// ============================ VN max-pool-down ============================
__global__ void vn_pool_kernel(const float* __restrict__ xin,
                               const int* __restrict__ idx, long long sb, int sq,
                               const float* __restrict__ wp,
                               float* __restrict__ xout,
                               int C, int Np, int Nq)
{
#pragma clang fp contract(off)
    __shared__ float nb[4 * 84 * 3];
    int b = blockIdx.y;
    int q = blockIdx.x;
    const int* ir = idx + b * sb + (long long)q * sq;
    for (int kk = 0; kk < 4; ++kk) {
        int mm = ir[kk];
        for (int t = threadIdx.x; t < C * 3; t += blockDim.x)
            nb[kk * C * 3 + t] = xin[(size_t)(b * 3 * C + t) * Np + mm];
    }
    __syncthreads();
    int o = threadIdx.x;
    if (o >= C) return;
    const float* wr = wp + o * C;
    float best = -3.4e38f;
    int bk = 0;
    for (int kk = 0; kk < 4; ++kk) {
        const float* cl = &nb[kk * C * 3];
        float d0 = 0.f, d1 = 0.f, d2 = 0.f;
        for (int c = 0; c < C; ++c) {
            float w = wr[c];
            d0 += w * cl[3 * c]; d1 += w * cl[3 * c + 1]; d2 += w * cl[3 * c + 2];
        }
        float dot = cl[o * 3] * d0 + cl[o * 3 + 1] * d1 + cl[o * 3 + 2] * d2;
        if (dot > best) { best = dot; bk = kk; }
    }
    const float* cb = &nb[bk * C * 3];
    xout[((size_t)(b * C + o) * 3 + 0) * Nq + q] = cb[o * 3];
    xout[((size_t)(b * C + o) * 3 + 1) * Nq + q] = cb[o * 3 + 1];
    xout[((size_t)(b * C + o) * 3 + 2) * Nq + q] = cb[o * 3 + 2];
}

// ============================ eqv assembly + fused mean partial ==============
__global__ void eqv_kernel(const float* __restrict__ x0, const float* __restrict__ x1,
                           const float* __restrict__ x2, const float* __restrict__ x3,
                           const float* __restrict__ x4,
                           const int* __restrict__ i1, const int* __restrict__ i2,
                           float* __restrict__ out_eqv, float* __restrict__ mfw)
{
    __shared__ float r1[256];
    int n = blockIdx.x * 256 + threadIdx.x;
    int cv = blockIdx.y;
    int b = blockIdx.z;
    int cc = cv / 3, v = cv % 3;
    float val;
    if (cc < 42)
        val = x0[((size_t)(b * 42 + cc) * 3 + v) * NTOT + n];
    else if (cc < 84)
        val = x1[((size_t)(b * 42 + (cc - 42)) * 3 + v) * NTOT + n];
    else if (cc < 168) {
        int m = i1[b * NTOT + n];
        val = x2[((size_t)(b * 84 + (cc - 84)) * 3 + v) * 512 + m];
    } else if (cc < 252) {
        int m = i1[b * NTOT + n];
        val = x3[((size_t)(b * 84 + (cc - 168)) * 3 + v) * 512 + m];
    } else {
        int m = i2[b * NTOT + n];
        val = x4[((size_t)(b * 168 + (cc - 252)) * 3 + v) * 128 + m];
    }
    out_eqv[((size_t)(b * 1260 + cv)) * NTOT + n] = val;
    r1[threadIdx.x] = val;
    __syncthreads();
    for (int off = 128; off; off >>= 1) {
        if ((int)threadIdx.x < off) r1[threadIdx.x] += r1[threadIdx.x + off];
        __syncthreads();
    }
    if (threadIdx.x == 0) atomicAdd(&mfw[b * 1260 + cv], r1[0]);
}

// ============================ mean_feat finalize ============================
__global__ void mf_finalize_kernel(float* __restrict__ mfw, float* __restrict__ out_mf)
{
    int i = blockIdx.x * 256 + threadIdx.x;
    if (i < 5040) {
        float m = mfw[i] / 2048.0f;
        mfw[i] = m;
        out_mf[i] = m;
    }
}

// ============================ z1: wave-per-output VN layer (K=420) ===========
__global__ __launch_bounds__(256)
void z1_kernel(const float* __restrict__ mfw,
               const float* __restrict__ wv1f, const float* __restrict__ wv1d,
               float* __restrict__ z1ws)
{
#pragma clang fp contract(off)
    __shared__ float mf[1260];
    int b = blockIdx.y;
    int wave = threadIdx.x >> 6, lane = threadIdx.x & 63;
    for (int i = threadIdx.x; i < 1260; i += 256) mf[i] = mfw[b * 1260 + i];
    __syncthreads();
    int o = blockIdx.x * 4 + wave;
    if (o >= 210) return;
    const float* wr  = wv1f + (size_t)o * 420;
    const float* wdr = wv1d + (size_t)o * 420;
    float p0 = 0.f, p1 = 0.f, p2 = 0.f, d0 = 0.f, d1 = 0.f, d2 = 0.f;
    for (int c = lane; c < 420; c += 64) {
        float m0 = mf[3 * c], m1 = mf[3 * c + 1], m2 = mf[3 * c + 2];
        float w = wr[c];
        p0 += w * m0; p1 += w * m1; p2 += w * m2;
        float w2 = wdr[c];
        d0 += w2 * m0; d1 += w2 * m1; d2 += w2 * m2;
    }
    for (int off = 32; off; off >>= 1) {
        p0 += __shfl_down(p0, off); p1 += __shfl_down(p1, off);
        p2 += __shfl_down(p2, off); d0 += __shfl_down(d0, off);
        d1 += __shfl_down(d1, off); d2 += __shfl_down(d2, off);
    }
    if (lane == 0) {
        float dot = p0 * d0 + p1 * d1 + p2 * d2;
        float r0, r1, r2;
        if (dot >= 0.f) { r0 = p0; r1 = p1; r2 = p2; }
        else {
            float tq = dot / (d0 * d0 + d1 * d1 + d2 * d2 + 1e-6f);
            r0 = p0 - tq * d0; r1 = p1 - tq * d1; r2 = p2 - tq * d2;
        }
        z1ws[b * 630 + o * 3]     = 0.2f * p0 + 0.8f * r0;
        z1ws[b * 630 + o * 3 + 1] = 0.2f * p1 + 0.8f * r1;
        z1ws[b * 630 + o * 3 + 2] = 0.2f * p2 + 0.8f * r2;
    }
}

// ============================ z2: wave-per-output VN layer (K=210) ===========
__global__ __launch_bounds__(256)
void z2_kernel(const float* __restrict__ z1ws,
               const float* __restrict__ wv2f, const float* __restrict__ wv2d,
               float* __restrict__ z2ws)
{
#pragma clang fp contract(off)
    __shared__ float zl[630];
    int b = blockIdx.y;
    int wave = threadIdx.x >> 6, lane = threadIdx.x & 63;
    for (int i = threadIdx.x; i < 630; i += 256) zl[i] = z1ws[b * 630 + i];
    __syncthreads();
    int o = blockIdx.x * 4 + wave;
    if (o >= 84) return;
    const float* wr  = wv2f + (size_t)o * 210;
    const float* wdr = wv2d + (size_t)o * 210;
    float p0 = 0.f, p1 = 0.f, p2 = 0.f, d0 = 0.f, d1 = 0.f, d2 = 0.f;
    for (int c = lane; c < 210; c += 64) {
        float m0 = zl[3 * c], m1 = zl[3 * c + 1], m2 = zl[3 * c + 2];
        float w = wr[c];
        p0 += w * m0; p1 += w * m1; p2 += w * m2;
        float w2 = wdr[c];
        d0 += w2 * m0; d1 += w2 * m1; d2 += w2 * m2;
    }
    for (int off = 32; off; off >>= 1) {
        p0 += __shfl_down(p0, off); p1 += __shfl_down(p1, off);
        p2 += __shfl_down(p2, off); d0 += __shfl_down(d0, off);
        d1 += __shfl_down(d1, off); d2 += __shfl_down(d2, off);
    }
    if (lane == 0) {
        float dot = p0 * d0 + p1 * d1 + p2 * d2;
        float r0, r1, r2;
        if (dot >= 0.f) { r0 = p0; r1 = p1; r2 = p2; }
        else {
            float tq = dot / (d0 * d0 + d1 * d1 + d2 * d2 + 1e-6f);
            r0 = p0 - tq * d0; r1 = p1 - tq * d1; r2 = p2 - tq * d2;
        }
        z2ws[b * 252 + o * 3]     = 0.2f * p0 + 0.8f * r0;
        z2ws[b * 252 + o * 3 + 1] = 0.2f * p1 + 0.8f * r1;
        z2ws[b * 252 + o * 3 + 2] = 0.2f * p2 + 0.8f * r2;
    }
}

// ============================ z3 + inv_gl ============================
__global__ void z3invgl_kernel(const float* __restrict__ mfw,
                               const float* __restrict__ z2ws,
                               const float* __restrict__ w3,
                               float* __restrict__ invgl_ws,
                               float* __restrict__ out_invgl)
{
#pragma clang fp contract(off)
    __shared__ float z2[252];
    __shared__ float z3[6];
    __shared__ float mf[1260];
    int b = blockIdx.x;
    int t = threadIdx.x;
    for (int i = t; i < 252; i += 256) z2[i] = z2ws[b * 252 + i];
    for (int i = t; i < 1260; i += 256) mf[i] = mfw[b * 1260 + i];
    __syncthreads();
    if (t < 6) {
        int v = t / 2, kt = t % 2;
        float s = 0.f;
        for (int c = 0; c < 84; ++c) s += z2[c * 3 + v] * w3[kt * 84 + c];
        z3[v * 2 + kt] = s;
    }
    __syncthreads();
    for (int i = t; i < 840; i += 256) {
        int ii = i / 2, kt = i % 2;
        float s = mf[ii * 3] * z3[0 + kt] + mf[ii * 3 + 1] * z3[2 + kt] +
                  mf[ii * 3 + 2] * z3[4 + kt];
        invgl_ws[b * 840 + i] = s;
        out_invgl[b * 840 + i] = s;
    }
}

// ============================ conv1 factored coefficients (wave-per-o) =======
__global__ __launch_bounds__(256)
void conv1_coef_kernel(const float* __restrict__ ws1,
                       const float* __restrict__ invgl,
                       const float* __restrict__ mfw,
                       const int* __restrict__ cat,
                       float* __restrict__ cb, float* __restrict__ ab,
                       float* __restrict__ w0)
{
#pragma clang fp contract(off)
    int wave = threadIdx.x >> 6, lane = threadIdx.x & 63;
    int o = blockIdx.x * 4 + wave;           // 0..1023
    int b = blockIdx.y;
    const float* wr = ws1 + (size_t)o * 1267;
    float s = 0.f;
    for (int j = lane; j < 840; j += 64)
        s += wr[1 + j] * invgl[b * 840 + j];
    float a0 = 0.f, a1 = 0.f, a2 = 0.f;
    for (int i = lane; i < 420; i += 64) {
        float w = wr[841 + i];
        a0 += w * mfw[b * 1260 + i * 3];
        a1 += w * mfw[b * 1260 + i * 3 + 1];
        a2 += w * mfw[b * 1260 + i * 3 + 2];
    }
    for (int off = 32; off; off >>= 1) {
        s  += __shfl_down(s, off);
        a0 += __shfl_down(a0, off);
        a1 += __shfl_down(a1, off);
        a2 += __shfl_down(a2, off);
    }
    if (lane == 0) {
        cb[b * 1024 + o] = s + wr[1261 + cat[b]];
        ab[((size_t)(b * 1024 + o)) * 3 + 0] = a0;
        ab[((size_t)(b * 1024 + o)) * 3 + 1] = a1;
        ab[((size_t)(b * 1024 + o)) * 3 + 2] = a2;
        if (b == 0) w0[o] = wr[0];
    }
}

// ============================ y1 generator (replaces gemm1) ==================
__global__ __launch_bounds__(256)
void y1_gen_kernel(const float* __restrict__ cb, const float* __restrict__ ab,
                   const float* __restrict__ w0, const float* __restrict__ coord,
                   const float* __restrict__ normv, float* __restrict__ y1t)
{
#pragma clang fp contract(off)
    int pt = blockIdx.x;                // 0..8191
    int b = pt >> 11, n = pt & 2047;
    float cx = coord[(b * 3 + 0) * NTOT + n];
    float cy = coord[(b * 3 + 1) * NTOT + n];
    float cz = coord[(b * 3 + 2) * NTOT + n];
    float nr = normv[b * NTOT + n];
    for (int it = 0; it < 4; ++it) {
        int o = it * 256 + threadIdx.x;
        size_t bo = (size_t)(b * 1024 + o);
        float v = cb[bo] + ab[bo * 3] * cx + ab[bo * 3 + 1] * cy +
                  ab[bo * 3 + 2] * cz + w0[o] * nr;
        y1t[(size_t)pt * 1024 + o] = v;
    }
}

// ============================ weight convert f32 -> bf16 ============================
__global__ void wconv_kernel(const float* __restrict__ src, unsigned short* __restrict__ dst,
                             int Msrc, int Ksrc, int Kpad)
{
    int k = blockIdx.x * 256 + threadIdx.x;
    int o = blockIdx.y;
    float v = (o < Msrc && k < Ksrc) ? src[(size_t)o * Ksrc + k] : 0.f;
    dst[(size_t)o * Kpad + k] = f2b(v);
}

// ============================ MFMA GEMM ============================
__global__ __launch_bounds__(256)
void gemm_mfma_kernel(const unsigned short* __restrict__ A,
                      const unsigned short* __restrict__ Bw,
                      float* __restrict__ C, int K, int Mreal)
{
    __shared__ __align__(16) unsigned short Al[128 * 40];
    __shared__ __align__(16) unsigned short Bl[128 * 40];
    int t = threadIdx.x;
    int r0 = blockIdx.x * 128;
    int c0 = blockIdx.y * 128;
    int w = t >> 6, l = t & 63;
    int wm = w & 1, wn = w >> 1;
    int lm = l & 15, lq = l >> 4;
    f32x4 acc[4][4] = {};
    for (int k0 = 0; k0 < K; k0 += 32) {
        for (int half = 0; half < 2; ++half) {
            int ch = t + half * 256;
            int row = ch >> 2, kc = ch & 3;
            *(uint4*)&Al[row * 40 + kc * 8] =
                *(const uint4*)&A[(size_t)(r0 + row) * K + k0 + kc * 8];
            *(uint4*)&Bl[row * 40 + kc * 8] =
                *(const uint4*)&Bw[(size_t)(c0 + row) * K + k0 + kc * 8];
        }
        __syncthreads();
        bf16x8 af[4], bfr[4];
#pragma unroll
        for (int i = 0; i < 4; ++i)
            af[i] = *(const bf16x8*)&Al[(wm * 64 + i * 16 + lm) * 40 + lq * 8];
#pragma unroll
        for (int j = 0; j < 4; ++j)
            bfr[j] = *(const bf16x8*)&Bl[(wn * 64 + j * 16 + lm) * 40 + lq * 8];
#pragma unroll
        for (int i = 0; i < 4; ++i)
#pragma unroll
            for (int j = 0; j < 4; ++j)
                acc[i][j] = __builtin_amdgcn_mfma_f32_16x16x32_bf16(af[i], bfr[j],
                                                                    acc[i][j], 0, 0, 0);
        __syncthreads();
    }
#pragma unroll
    for (int i = 0; i < 4; ++i) {
#pragma unroll
        for (int j = 0; j < 4; ++j) {
            int col = c0 + wn * 64 + j * 16 + lm;
            if (col < Mreal) {
                int rbase = r0 + wm * 64 + i * 16 + lq * 4;
#pragma unroll
                for (int r = 0; r < 4; ++r)
                    C[(size_t)(rbase + r) * Mreal + col] = acc[i][j][r];
            }
        }
    }
}

// ============================ conv BN stats ============================
__global__ void cstatsT_kernel(const float* __restrict__ Ct, float* __restrict__ st,
                               int Mreal)
{
    __shared__ float l1[256], l2[256];
    int t = threadIdx.x;
    int o = blockIdx.x * 64 + (t & 63);
    int r0 = blockIdx.y * 128 + (t >> 6) * 32;
    float s = 0.f, s2 = 0.f;
    if (o < Mreal) {
        for (int rr = 0; rr < 32; ++rr) {
            float v = Ct[(size_t)(r0 + rr) * Mreal + o];
            s += v; s2 += v * v;
        }
    }
    l1[t] = s; l2[t] = s2;
    __syncthreads();
    if (t < 64 && o < Mreal) {
        s  = l1[t] + l1[t + 64] + l1[t + 128] + l1[t + 192];
        s2 = l2[t] + l2[t + 64] + l2[t + 128] + l2[t + 192];
        atomicAdd(&st[o], s);
        atomicAdd(&st[Mreal + o], s2);
    }
}

// ============================ BN+ReLU -> bf16 ============================
__global__ void bnreluT_kernel(const float* __restrict__ Ct, const float* __restrict__ st,
                               const float* __restrict__ g, const float* __restrict__ be,
                               unsigned short* __restrict__ outb, int M, int maskM)
{
#pragma clang fp contract(off)
    size_t idx = (size_t)blockIdx.x * 256 + threadIdx.x;
    int o = (int)(idx & (size_t)maskM);
    float m = st[o] * (1.f / 8192.f);
    float var = st[M + o] * (1.f / 8192.f) - m * m;
    float sqv = sqrtf(var + 1e-5f);
    float v = g[o] * (Ct[idx] - m) / sqv + be[o];
    outb[idx] = f2b(v > 0.f ? v : 0.f);
}

// ============================ final BN+ReLU + transpose ============================
__global__ void bnrelu_outT_kernel(const float* __restrict__ Ct, const float* __restrict__ st,
                                   const float* __restrict__ g, const float* __restrict__ be,
                                   float* __restrict__ outinv)
{
#pragma clang fp contract(off)
    __shared__ float tile[64][65];
    int t = threadIdx.x;
    int r0 = blockIdx.x * 64;
    int o0 = blockIdx.y * 64;
    int b = r0 >> 11, n0 = r0 & 2047;
    int oi = t & 63;
    int o = o0 + oi;
    float m = 0.f, sqv = 1.f, gg = 0.f, bb = 0.f;
    if (o < 420) {
        m = st[o] * (1.f / 8192.f);
        float var = st[420 + o] * (1.f / 8192.f) - m * m;
        sqv = sqrtf(var + 1e-5f);
        gg = g[o]; bb = be[o];
    }
    for (int it = 0; it < 16; ++it) {
        int rr = it * 4 + (t >> 6);
        float v = 0.f;
        if (o < 420) {
            v = gg * (Ct[(size_t)(r0 + rr) * 420 + o] - m) / sqv + bb;
            v = v > 0.f ? v : 0.f;
        }
        tile[rr][oi] = v;
    }
    __syncthreads();
    for (int it = 0; it < 16; ++it) {
        int oc = it * 4 + (t >> 6);
        int oo = o0 + oc;
        if (oo < 420)
            outinv[((size_t)(b * 420 + oo)) * 2048 + n0 + (t & 63)] = tile[t & 63][oc];
    }
}

// ============================ launch ============================
extern "C" void kernel_launch(void* const* d_in, const int* in_sizes, int n_in,
                              void* d_out, int out_size, void* d_ws, size_t ws_size,
                              hipStream_t stream)
{
    (void)in_sizes; (void)n_in; (void)out_size; (void)ws_size;
    const float* xc   = (const float*)d_in[0];
    const float* normv= (const float*)d_in[1];
    const int*   cat  = (const int*)d_in[2];
    const float* wf0  = (const float*)d_in[3];
    const float* wd0  = (const float*)d_in[4];
    const float* g0   = (const float*)d_in[5];
    const float* b0   = (const float*)d_in[6];
    const float* wf1  = (const float*)d_in[7];
    const float* wd1  = (const float*)d_in[8];
    const float* g1   = (const float*)d_in[9];
    const float* b1   = (const float*)d_in[10];
    const float* wp1  = (const float*)d_in[11];
    const float* wf2  = (const float*)d_in[12];
    const float* wd2  = (const float*)d_in[13];
    const float* g2   = (const float*)d_in[14];
    const float* b2   = (const float*)d_in[15];
    const float* wf3  = (const float*)d_in[16];
    const float* wd3  = (const float*)d_in[17];
    const float* g3   = (const float*)d_in[18];
    const float* b3   = (const float*)d_in[19];
    const float* wp2  = (const float*)d_in[20];
    const float* wf4  = (const float*)d_in[21];
    const float* wd4  = (const float*)d_in[22];
    const float* g4   = (const float*)d_in[23];
    const float* b4   = (const float*)d_in[24];
    const float* wv1f = (const float*)d_in[25];
    const float* wv1d = (const float*)d_in[26];
    const float* wv2f = (const float*)d_in[27];
    const float* wv2d = (const float*)d_in[28];
    const float* w3   = (const float*)d_in[29];
    const float* ws1  = (const float*)d_in[30];
    const float* sg1  = (const float*)d_in[32];
    const float* sb1  = (const float*)d_in[33];
    const float* ws2  = (const float*)d_in[34];
    const float* sg2  = (const float*)d_in[36];
    const float* sb2  = (const float*)d_in[37];
    const float* ws3  = (const float*)d_in[38];
    const float* sg3  = (const float*)d_in[40];
    const float* sb3  = (const float*)d_in[41];

    float* ws = (float*)d_ws;
    float* out = (float*)d_out;

    int*    idx20 = (int*)(ws + WS_IDX20);
    float*  fs    = ws + WS_FS;
    float*  x0    = ws + WS_X0;
    float*  x1    = ws + WS_X1;
    float*  xm2   = ws + WS_XM2;
    float*  x2    = ws + WS_X2;
    float*  x3    = ws + WS_X3;
    int*    idx42 = (int*)(ws + WS_IDX42);
    float*  xm4   = ws + WS_XM4;
    float*  x4    = ws + WS_X4;
    int*    i1p   = (int*)(ws + WS_I1);
    int*    i2p   = (int*)(ws + WS_I2);
    float*  mfw   = ws + WS_MF;
    float*  invgl = ws + WS_INVGL;
    double* st    = (double*)(ws + WS_STATS);
    float*  cst   = ws + WS_CST;
    float*  cb    = ws + WS_CB;
    float*  ab    = ws + WS_AB;
    float*  w0    = ws + WS_W0;
    float*  z1ws  = ws + WS_Z1;
    float*  z2ws  = ws + WS_Z2;
    unsigned short* w2b  = (unsigned short*)(ws + WS_W2B);
    unsigned short* w3b  = (unsigned short*)(ws + WS_W3B);
    float*  y1t   = ws + WS_Y1T;
    unsigned short* y1b  = (unsigned short*)(ws + WS_Y1B);
    float*  y2t   = ws + WS_Y2T;
    unsigned short* y2b  = (unsigned short*)(ws + WS_Y2B);
    float*  y3t   = ws + WS_Y3T;

    hipMemsetAsync((void*)st, 0, 840 * sizeof(double), stream);
    hipMemsetAsync((void*)cst, 0, 3912 * sizeof(float), stream);
    hipMemsetAsync((void*)mfw, 0, 5040 * sizeof(float), stream);

    // weight conversions (independent)
    wconv_kernel<<<dim3(4, 512), 256, 0, stream>>>(ws2, w2b, 512, 1024, 1024);
    wconv_kernel<<<dim3(2, 512), 256, 0, stream>>>(ws3, w3b, 420, 512, 512);

    // KNN-20 (also the knn-4 prefix for pool stage 1)
    knn_reg_kernel<32, 20><<<dim3(512, 4), 256, 0, stream>>>(xc, 1, 1, idx20, 2048);
    surf_build_kernel<<<640, 256, 0, stream>>>(xc, idx20, fs);

    // stage 0
    stats0_kernel<<<dim3(128, 4), 256, 0, stream>>>(fs, wf0, st + ST0_OFF);
    apply0_kernel<<<dim3(512, 4), 256, 0, stream>>>(fs, wf0, wd0, g0, b0,
                                                    st + ST0_OFF, x0);

    // stage 1
    vn_stats_kernel<<<dim3(128, 4), 256, 0, stream>>>(x0, wf1, st + ST1_OFF, 42, 42, 2048);
    vn_apply_kernel<<<dim3(512, 4), 256, 0, stream>>>(x0, wf1, wd1, g1, b1, st + ST1_OFF,
                                                      8192.0, 42, 42, 2048, 6, 1, x1);

    // pool 1
    vn_pool_kernel<<<dim3(512, 4), 256, 0, stream>>>(x1, idx20, 40960LL, 80, wp1, xm2,
                                                     42, 2048, 512);
    // stage 2
    vn_stats_kernel<<<dim3(32, 4), 256, 0, stream>>>(xm2, wf2, st + ST2_OFF, 42, 84, 512);
    vn_apply_kernel<<<dim3(256, 4), 256, 0, stream>>>(xm2, wf2, wd2, g2, b2, st + ST2_OFF,
                                                      2048.0, 42, 84, 512, 7, 1, x2);
    // stage 3
    vn_stats_kernel<<<dim3(32, 4), 256, 0, stream>>>(x2, wf3, st + ST3_OFF, 84, 84, 512);
    vn_apply_kernel<<<dim3(256, 4), 256, 0, stream>>>(x2, wf3, wd3, g3, b3, st + ST3_OFF,
                                                      2048.0, 84, 84, 512, 7, 1, x3);

    // knn-4 on coord2 (cands stride 4, queries stride 16)
    knn_reg_kernel<8, 4><<<dim3(32, 4), 256, 0, stream>>>(xc, 4, 16, idx42, 128);
    vn_pool_kernel<<<dim3(128, 4), 256, 0, stream>>>(x3, idx42, 512LL, 4, wp2, xm4,
                                                     84, 512, 128);
    // stage 4
    vn_stats_kernel<<<dim3(8, 4), 256, 0, stream>>>(xm4, wf4, st + ST4_OFF, 84, 168, 128);
    vn_apply_kernel<<<dim3(128, 4), 256, 0, stream>>>(xm4, wf4, wd4, g4, b4, st + ST4_OFF,
                                                      512.0, 84, 168, 128, 8, 1, x4);

    // nearest-neighbor upsample indices
    nearest_reg_kernel<8><<<dim3(512, 4), 256, 0, stream>>>(xc, 4, i1p);
    nearest_reg_kernel<2><<<dim3(512, 4), 256, 0, stream>>>(xc, 16, i2p);

    // eqv (output 0) with fused mean partials; finalize mean (output 1)
    eqv_kernel<<<dim3(8, 1260, 4), 256, 0, stream>>>(x0, x1, x2, x3, x4, i1p, i2p,
                                                     out + OUT_EQV, mfw);
    mf_finalize_kernel<<<20, 256, 0, stream>>>(mfw, out + OUT_MF);

    // z chain (wave-per-output, coalesced) + inv_gl (output 3)
    z1_kernel<<<dim3(53, 4), 256, 0, stream>>>(mfw, wv1f, wv1d, z1ws);
    z2_kernel<<<dim3(21, 4), 256, 0, stream>>>(z1ws, wv2f, wv2d, z2ws);
    z3invgl_kernel<<<4, 256, 0, stream>>>(mfw, z2ws, w3, invgl, out + OUT_INVGL);

    // invariant branch: conv1 factored (wave-per-(b,o), coalesced)
    conv1_coef_kernel<<<dim3(256, 4), 256, 0, stream>>>(ws1, invgl, mfw, cat, cb, ab, w0);
    y1_gen_kernel<<<8192, 256, 0, stream>>>(cb, ab, w0, xc, normv, y1t);
    cstatsT_kernel<<<dim3(16, 64), 256, 0, stream>>>(y1t, cst + CST1_OFF, 1024);
    bnreluT_kernel<<<32768, 256, 0, stream>>>(y1t, cst + CST1_OFF, sg1, sb1, y1b,
                                              1024, 1023);

    gemm_mfma_kernel<<<dim3(64, 4), 256, 0, stream>>>(y1b, w2b, y2t, 1024, 512);
    cstatsT_kernel<<<dim3(8, 64), 256, 0, stream>>>(y2t, cst + CST2_OFF, 512);
    bnreluT_kernel<<<16384, 256, 0, stream>>>(y2t, cst + CST2_OFF, sg2, sb2, y2b,
                                              512, 511);

    gemm_mfma_kernel<<<dim3(64, 4), 256, 0, stream>>>(y2b, w3b, y3t, 512, 420);
    cstatsT_kernel<<<dim3(7, 64), 256, 0, stream>>>(y3t, cst + CST3_OFF, 420);
    bnrelu_outT_kernel<<<dim3(128, 7), 256, 0, stream>>>(y3t, cst + CST3_OFF, sg3, sb3,
                                                         out + OUT_INV);
}